// Round 9
// baseline (508.362 us; speedup 1.0000x reference)
//
#include <hip/hip_runtime.h>
#include <math.h>

// Problem constants (ConformerEncoderLayer, T=512 B=16 C=512 H=8 d=64 DFF=2048 K=31)
#define T_SEQ 512
#define B_SZ  16
#define C_DIM 512
#define NH    8
#define HD    64
#define DFF_  2048
#define NROWS (T_SEQ * B_SZ)   // 8192 rows of (t*B+b)
#define EPS_BN 1.2840254166877414f  // exp(0.25)

typedef unsigned short u16;
typedef __attribute__((ext_vector_type(8))) short bf16x8;
typedef __attribute__((ext_vector_type(4))) float f32x4;

__device__ __forceinline__ float sigmoidf_(float x) { return 1.f / (1.f + __expf(-x)); }
__device__ __forceinline__ float dswishf_(float x)  { return x * sigmoidf_(x - 1.f); }
__device__ __forceinline__ float clampd_(float x)   { return fminf(fmaxf(x, -1e4f), 1e4f); }
__device__ __forceinline__ u16 f2bf_(float x) {
    unsigned u = __float_as_uint(x);
    return (u16)((u + 0x7fffu + ((u >> 16) & 1u)) >> 16);
}
__device__ __forceinline__ float bf2f_(u16 u) {
    return __uint_as_float(((unsigned)u) << 16);
}

// ---------------------------------------------------------------------------
// bf16 MFMA GEMM, double-buffered LDS, reg-staged (R0-proven staging).
// R3-proven: 512-thread / 8-wave blocks on a 128x128 tile (wave = 64x32 out,
// acc[4][2]). Used for the wide GEMMs (M>=1024). N,M mult of 128; K mult of 32.
// ---------------------------------------------------------------------------
template <int ACT, bool HAS_RES, bool O32, bool O16>
__global__ __launch_bounds__(512) void gemm_mfma(
    const u16* __restrict__ A, const u16* __restrict__ W,
    const float* __restrict__ bias, const float* __restrict__ res,
    float* __restrict__ out32, u16* __restrict__ out16, int N, int K, int M)
{
    __shared__ __align__(16) u16 As[2][128 * 32];
    __shared__ __align__(16) u16 Bs[2][128 * 32];
    const int tid  = threadIdx.x;
    const int wv   = tid >> 6;
    const int lane = tid & 63;
    const int wm   = wv >> 2, wn = wv & 3;   // 2 x 4 waves, 64x32 out each
    const int m0 = blockIdx.x * 128;
    const int n0 = blockIdx.y * 128;

    const int sc_ = tid & 3;
    const int sr_ = tid >> 2;                // 0..127
    const u16* gA = A + (size_t)(n0 + sr_) * K + sc_ * 8;
    const u16* gB = W + (size_t)(m0 + sr_) * K + sc_ * 8;
    const int ls = sr_ * 32 + sc_ * 8;

    f32x4 acc[4][2];
#pragma unroll
    for (int i = 0; i < 4; ++i)
#pragma unroll
        for (int j = 0; j < 2; ++j) acc[i][j] = (f32x4)0.f;

    const int frow = (lane & 15);
    const int fk   = (lane >> 4) * 8;

    uint4 ra = *(const uint4*)(gA);
    uint4 rb = *(const uint4*)(gB);
    *(uint4*)&As[0][ls] = ra;
    *(uint4*)&Bs[0][ls] = rb;
    __syncthreads();

    int buf = 0;
    for (int k0 = 0; k0 < K; k0 += 32) {
        const bool last = (k0 + 32 >= K);
        if (!last) {
            ra = *(const uint4*)(gA + k0 + 32);
            rb = *(const uint4*)(gB + k0 + 32);
        }
        bf16x8 af[4], bf[2];
#pragma unroll
        for (int i = 0; i < 4; ++i)
            af[i] = *(const bf16x8*)&As[buf][(wm * 64 + i * 16 + frow) * 32 + fk];
#pragma unroll
        for (int j = 0; j < 2; ++j)
            bf[j] = *(const bf16x8*)&Bs[buf][(wn * 32 + j * 16 + frow) * 32 + fk];
#pragma unroll
        for (int i = 0; i < 4; ++i)
#pragma unroll
            for (int j = 0; j < 2; ++j)
                acc[i][j] = __builtin_amdgcn_mfma_f32_16x16x32_bf16(af[i], bf[j], acc[i][j], 0, 0, 0);
        if (!last) {
            const int nb = buf ^ 1;
            *(uint4*)&As[nb][ls] = ra;
            *(uint4*)&Bs[nb][ls] = rb;
            __syncthreads();
            buf = nb;
        }
    }

    const int quad = lane >> 4;
#pragma unroll
    for (int i = 0; i < 4; ++i) {
        const int row = n0 + wm * 64 + i * 16 + quad * 4;
#pragma unroll
        for (int j = 0; j < 2; ++j) {
            const int col = m0 + wn * 32 + j * 16 + (lane & 15);
            const float bv = bias ? bias[col] : 0.f;
#pragma unroll
            for (int r = 0; r < 4; ++r) {
                float v = acc[i][j][r] + bv;
                if (ACT == 1) v = dswishf_(v);
                if (HAS_RES) v += res[(size_t)(row + r) * M + col];
                v = clampd_(v);
                if (O32) out32[(size_t)(row + r) * M + col] = v;
                if (O16) out16[(size_t)(row + r) * M + col] = f2bf_(v);
            }
        }
    }
}

// ---------------------------------------------------------------------------
// R9: 64x64-tile GEMM for the M=512 outputs (ffm2/out-proj/pw2/ffn2). These
// ran 256 blocks = 1 block/CU = 2 waves/SIMD with the 128-tile — the least
// latency hiding in the graph. 64x64 tile, 256 threads / 4 waves (wave =
// 32x32, acc[2][2]), 16 KB LDS -> grid (M/64, N/64) = 1024 blocks = 4
// blocks/CU = 4 waves/SIMD (2x TLP). Block linearization is m-fastest so 8
// consecutive blocks share one A-slice (L2-friendly). Same reg-staged dbuf.
// ---------------------------------------------------------------------------
template <int ACT, bool HAS_RES, bool O32, bool O16>
__global__ __launch_bounds__(256) void gemm_small(
    const u16* __restrict__ A, const u16* __restrict__ W,
    const float* __restrict__ bias, const float* __restrict__ res,
    float* __restrict__ out32, u16* __restrict__ out16, int N, int K, int M)
{
    __shared__ __align__(16) u16 As[2][64 * 32];
    __shared__ __align__(16) u16 Bs[2][64 * 32];
    const int tid  = threadIdx.x;
    const int wv   = tid >> 6;
    const int lane = tid & 63;
    const int wm   = wv >> 1, wn = wv & 1;   // 2 x 2 waves, 32x32 out each
    const int m0 = blockIdx.x * 64;
    const int n0 = blockIdx.y * 64;

    const int sc_ = tid & 3;
    const int sr_ = tid >> 2;                // 0..63
    const u16* gA = A + (size_t)(n0 + sr_) * K + sc_ * 8;
    const u16* gB = W + (size_t)(m0 + sr_) * K + sc_ * 8;
    const int ls = sr_ * 32 + sc_ * 8;

    f32x4 acc[2][2];
#pragma unroll
    for (int i = 0; i < 2; ++i)
#pragma unroll
        for (int j = 0; j < 2; ++j) acc[i][j] = (f32x4)0.f;

    const int frow = (lane & 15);
    const int fk   = (lane >> 4) * 8;

    uint4 ra = *(const uint4*)(gA);
    uint4 rb = *(const uint4*)(gB);
    *(uint4*)&As[0][ls] = ra;
    *(uint4*)&Bs[0][ls] = rb;
    __syncthreads();

    int buf = 0;
    for (int k0 = 0; k0 < K; k0 += 32) {
        const bool last = (k0 + 32 >= K);
        if (!last) {
            ra = *(const uint4*)(gA + k0 + 32);
            rb = *(const uint4*)(gB + k0 + 32);
        }
        bf16x8 af[2], bf[2];
#pragma unroll
        for (int i = 0; i < 2; ++i)
            af[i] = *(const bf16x8*)&As[buf][(wm * 32 + i * 16 + frow) * 32 + fk];
#pragma unroll
        for (int j = 0; j < 2; ++j)
            bf[j] = *(const bf16x8*)&Bs[buf][(wn * 32 + j * 16 + frow) * 32 + fk];
#pragma unroll
        for (int i = 0; i < 2; ++i)
#pragma unroll
            for (int j = 0; j < 2; ++j)
                acc[i][j] = __builtin_amdgcn_mfma_f32_16x16x32_bf16(af[i], bf[j], acc[i][j], 0, 0, 0);
        if (!last) {
            const int nb = buf ^ 1;
            *(uint4*)&As[nb][ls] = ra;
            *(uint4*)&Bs[nb][ls] = rb;
            __syncthreads();
            buf = nb;
        }
    }

    const int quad = lane >> 4;
#pragma unroll
    for (int i = 0; i < 2; ++i) {
        const int row = n0 + wm * 32 + i * 16 + quad * 4;
#pragma unroll
        for (int j = 0; j < 2; ++j) {
            const int col = m0 + wn * 32 + j * 16 + (lane & 15);
            const float bv = bias ? bias[col] : 0.f;
#pragma unroll
            for (int r = 0; r < 4; ++r) {
                float v = acc[i][j][r] + bv;
                if (ACT == 1) v = dswishf_(v);
                if (HAS_RES) v += res[(size_t)(row + r) * M + col];
                v = clampd_(v);
                if (O32) out32[(size_t)(row + r) * M + col] = v;
                if (O16) out16[(size_t)(row + r) * M + col] = f2bf_(v);
            }
        }
    }
}

// ---------------------------------------------------------------------------
// dbuf GEMM with fused epilogues (reg-staged, 512-thread / 8-wave).
// EPI=0 (qkv): writes qu/qv/k/v bf16 in [b*8+h][t][d], q*0.125 + u/v bias.
//   (R7 lesson: V must NOT be written transposed here — 2B/lane scatter at
//    1KB stride killed coalescing. vt_k's LDS-tiled transpose is cheaper.)
// EPI=1 (pos): writes p_b[h][j][d] bf16.
// ---------------------------------------------------------------------------
template <int EPI>
__global__ __launch_bounds__(512) void gemm_fused(
    const u16* __restrict__ A, const u16* __restrict__ W,
    const float* __restrict__ bias, const float* __restrict__ ub, const float* __restrict__ vb,
    u16* __restrict__ o_qu, u16* __restrict__ o_qv, u16* __restrict__ o_k,
    u16* __restrict__ o_v, u16* __restrict__ o_p, int N, int K, int M)
{
    __shared__ __align__(16) u16 As[2][128 * 32];
    __shared__ __align__(16) u16 Bs[2][128 * 32];
    const int tid  = threadIdx.x;
    const int wv   = tid >> 6;
    const int lane = tid & 63;
    const int wm   = wv >> 2, wn = wv & 3;
    const int m0 = blockIdx.x * 128;
    const int n0 = blockIdx.y * 128;

    const int sc_ = tid & 3;
    const int sr_ = tid >> 2;
    const u16* gA = A + (size_t)(n0 + sr_) * K + sc_ * 8;
    const u16* gB = W + (size_t)(m0 + sr_) * K + sc_ * 8;
    const int ls = sr_ * 32 + sc_ * 8;

    f32x4 acc[4][2];
#pragma unroll
    for (int i = 0; i < 4; ++i)
#pragma unroll
        for (int j = 0; j < 2; ++j) acc[i][j] = (f32x4)0.f;

    const int frow = (lane & 15);
    const int fk   = (lane >> 4) * 8;

    uint4 ra = *(const uint4*)(gA);
    uint4 rb = *(const uint4*)(gB);
    *(uint4*)&As[0][ls] = ra;
    *(uint4*)&Bs[0][ls] = rb;
    __syncthreads();

    int buf = 0;
    for (int k0 = 0; k0 < K; k0 += 32) {
        const bool last = (k0 + 32 >= K);
        if (!last) {
            ra = *(const uint4*)(gA + k0 + 32);
            rb = *(const uint4*)(gB + k0 + 32);
        }
        bf16x8 af[4], bf[2];
#pragma unroll
        for (int i = 0; i < 4; ++i)
            af[i] = *(const bf16x8*)&As[buf][(wm * 64 + i * 16 + frow) * 32 + fk];
#pragma unroll
        for (int j = 0; j < 2; ++j)
            bf[j] = *(const bf16x8*)&Bs[buf][(wn * 32 + j * 16 + frow) * 32 + fk];
#pragma unroll
        for (int i = 0; i < 4; ++i)
#pragma unroll
            for (int j = 0; j < 2; ++j)
                acc[i][j] = __builtin_amdgcn_mfma_f32_16x16x32_bf16(af[i], bf[j], acc[i][j], 0, 0, 0);
        if (!last) {
            const int nb = buf ^ 1;
            *(uint4*)&As[nb][ls] = ra;
            *(uint4*)&Bs[nb][ls] = rb;
            __syncthreads();
            buf = nb;
        }
    }

    const int quad = lane >> 4;
#pragma unroll
    for (int i = 0; i < 4; ++i) {
        const int rowb = n0 + wm * 64 + i * 16 + quad * 4;
#pragma unroll
        for (int j = 0; j < 2; ++j) {
            const int col = m0 + wn * 32 + j * 16 + (lane & 15);
            if (EPI == 0) {
                const float bv = bias[col];
                const int c = col & 511, h = c >> 6, d = c & 63;
#pragma unroll
                for (int r = 0; r < 4; ++r) {
                    const int row = rowb + r;
                    const float v = clampd_(acc[i][j][r] + bv);
                    const int t = row >> 4, b = row & 15;
                    const size_t dst = ((size_t)(b * 8 + h) * 512 + t) * 64 + d;
                    if (col < 512) {
                        o_qu[dst] = f2bf_(v * 0.125f + ub[c]);
                        o_qv[dst] = f2bf_(v * 0.125f + vb[c]);
                    } else if (col < 1024) {
                        o_k[dst] = f2bf_(v);
                    } else {
                        o_v[dst] = f2bf_(v);
                    }
                }
            } else {
                const int h = col >> 6, d = col & 63;
#pragma unroll
                for (int r = 0; r < 4; ++r)
                    o_p[(size_t)h * 65536 + (size_t)(rowb + r) * 64 + d] = f2bf_(acc[i][j][r]);
            }
        }
    }
}

// ---------------------------------------------------------------------------
// pw1 GEMM with fused GLU (R6-proven). Writes a*sigmoid(g) bf16 to glu_o.
// ---------------------------------------------------------------------------
__global__ __launch_bounds__(512) void gemm_glu_k(
    const u16* __restrict__ A, const u16* __restrict__ W,
    const float* __restrict__ bias, u16* __restrict__ out)
{
    __shared__ __align__(16) u16 As[2][128 * 32];
    __shared__ __align__(16) u16 Ba[2][128 * 32];
    __shared__ __align__(16) u16 Bg[2][128 * 32];
    const int tid  = threadIdx.x;
    const int wv   = tid >> 6;
    const int lane = tid & 63;
    const int wm   = wv >> 2, wn = wv & 3;
    const int m0 = blockIdx.x * 128;
    const int n0 = blockIdx.y * 128;
    const int K = 512;

    const int sc_ = tid & 3;
    const int sr_ = tid >> 2;
    const u16* gA  = A + (size_t)(n0 + sr_) * K + sc_ * 8;
    const u16* gBa = W + (size_t)(m0 + sr_) * K + sc_ * 8;
    const u16* gBg = W + (size_t)(m0 + 512 + sr_) * K + sc_ * 8;
    const int ls = sr_ * 32 + sc_ * 8;

    f32x4 aa[4][2], ag[4][2];
#pragma unroll
    for (int i = 0; i < 4; ++i)
#pragma unroll
        for (int j = 0; j < 2; ++j) { aa[i][j] = (f32x4)0.f; ag[i][j] = (f32x4)0.f; }

    const int frow = (lane & 15);
    const int fk   = (lane >> 4) * 8;

    uint4 ra  = *(const uint4*)(gA);
    uint4 rba = *(const uint4*)(gBa);
    uint4 rbg = *(const uint4*)(gBg);
    *(uint4*)&As[0][ls] = ra;
    *(uint4*)&Ba[0][ls] = rba;
    *(uint4*)&Bg[0][ls] = rbg;
    __syncthreads();

    int buf = 0;
    for (int k0 = 0; k0 < K; k0 += 32) {
        const bool last = (k0 + 32 >= K);
        if (!last) {
            ra  = *(const uint4*)(gA + k0 + 32);
            rba = *(const uint4*)(gBa + k0 + 32);
            rbg = *(const uint4*)(gBg + k0 + 32);
        }
        bf16x8 af[4], bfa[2], bfg[2];
#pragma unroll
        for (int i = 0; i < 4; ++i)
            af[i] = *(const bf16x8*)&As[buf][(wm * 64 + i * 16 + frow) * 32 + fk];
#pragma unroll
        for (int j = 0; j < 2; ++j) {
            bfa[j] = *(const bf16x8*)&Ba[buf][(wn * 32 + j * 16 + frow) * 32 + fk];
            bfg[j] = *(const bf16x8*)&Bg[buf][(wn * 32 + j * 16 + frow) * 32 + fk];
        }
#pragma unroll
        for (int i = 0; i < 4; ++i)
#pragma unroll
            for (int j = 0; j < 2; ++j) {
                aa[i][j] = __builtin_amdgcn_mfma_f32_16x16x32_bf16(af[i], bfa[j], aa[i][j], 0, 0, 0);
                ag[i][j] = __builtin_amdgcn_mfma_f32_16x16x32_bf16(af[i], bfg[j], ag[i][j], 0, 0, 0);
            }
        if (!last) {
            const int nb = buf ^ 1;
            *(uint4*)&As[nb][ls] = ra;
            *(uint4*)&Ba[nb][ls] = rba;
            *(uint4*)&Bg[nb][ls] = rbg;
            __syncthreads();
            buf = nb;
        }
    }

    const int quad = lane >> 4;
#pragma unroll
    for (int i = 0; i < 4; ++i) {
        const int row = n0 + wm * 64 + i * 16 + quad * 4;
#pragma unroll
        for (int j = 0; j < 2; ++j) {
            const int col = m0 + wn * 32 + j * 16 + (lane & 15);
            const float ba = bias[col];
            const float bg = bias[col + 512];
#pragma unroll
            for (int r = 0; r < 4; ++r) {
                const float a = clampd_(aa[i][j][r] + ba);
                const float g = clampd_(ag[i][j][r] + bg);
                out[(size_t)(row + r) * 512 + col] = f2bf_(a * sigmoidf_(g));
            }
        }
    }
}

// ---------------------------------------------------------------------------
// f32 -> bf16 converters / prep (merged single launch, R6-proven)
// ---------------------------------------------------------------------------
__device__ __forceinline__ void store_bf4_(u16* out, float4 v) {
    const unsigned lo = (unsigned)f2bf_(v.x) | ((unsigned)f2bf_(v.y) << 16);
    const unsigned hi = (unsigned)f2bf_(v.z) | ((unsigned)f2bf_(v.w) << 16);
    *(uint2*)out = make_uint2(lo, hi);
}

struct WPtrs { const float* p[9]; };
__global__ __launch_bounds__(256) void prep_k(
    WPtrs wp, const float* __restrict__ src, const float* __restrict__ pos,
    const float* __restrict__ cdw,
    u16* __restrict__ wb, u16* __restrict__ src_b, u16* __restrict__ pos_b,
    float* __restrict__ wTd)
{
    const int e = (blockIdx.x * 256 + threadIdx.x) * 4;
    if (e < 6291456) {
        static const int off[10] = {0, 1048576, 2097152, 3145728, 4194304,
                                    4980736, 5242880, 5505024, 6029312, 6291456};
        int r = 0;
#pragma unroll
        for (int k = 1; k < 9; ++k) r += (e >= off[k]);
        store_bf4_(wb + e, *(const float4*)(wp.p[r] + (e - off[r])));
    } else if (e < 6291456 + 4194304) {
        const int e2 = e - 6291456;
        store_bf4_(src_b + e2, *(const float4*)(src + e2));
    } else if (e < 6291456 + 4194304 + 524288) {
        const int e2 = e - (6291456 + 4194304);
        float4 v = make_float4(0.f, 0.f, 0.f, 0.f);
        if (e2 < 1023 * 512) v = *(const float4*)(pos + e2);
        store_bf4_(pos_b + e2, v);
    } else {
        const int e2 = e - (6291456 + 4194304 + 524288);
        if (e2 < 15872) {
#pragma unroll
            for (int q = 0; q < 4; ++q) {
                const int i2 = e2 + q;
                const int j = i2 >> 9, c = i2 & 511;
                wTd[i2] = cdw[c * 31 + j];
            }
        }
    }
}

// v_b[gbh][s][d] -> vt_b[gbh][d][s]  (64x64 LDS tile transpose; R7 lesson:
// this is cheaper than scattering the transpose into the GEMM epilogue)
__global__ __launch_bounds__(256) void vt_k(const u16* __restrict__ in, u16* __restrict__ out)
{
    __shared__ u16 tile[64][65];
    const int s0 = blockIdx.x * 64;
    const int gbh = blockIdx.y;
    const u16* src = in + (size_t)gbh * 512 * 64;
    u16* dst = out + (size_t)gbh * 64 * 512;
    const int tid = threadIdx.x;
#pragma unroll
    for (int q = 0; q < 2; ++q) {
        const int lin = tid * 2 + q;             // 0..511 uint4s
        const int srow = lin >> 3, c8 = (lin & 7) * 8;
        const uint4 v = *(const uint4*)(src + (size_t)(s0 + srow) * 64 + c8);
        const u16* vu = (const u16*)&v;
#pragma unroll
        for (int e = 0; e < 8; ++e) tile[srow][c8 + e] = vu[e];
    }
    __syncthreads();
#pragma unroll
    for (int q = 0; q < 2; ++q) {
        const int lin = tid * 2 + q;
        const int d = lin >> 3, sc8 = (lin & 7) * 8;
        u16 o[8];
#pragma unroll
        for (int e = 0; e < 8; ++e) o[e] = tile[sc8 + e][d];
        *(uint4*)(dst + (size_t)d * 512 + s0 + sc8) = *(uint4*)o;
    }
}

// ---------------------------------------------------------------------------
// Fused flash rel-pos attention (R6-proven body, dynamic s-loop — R8's full
// unroll spilled: WRITE 8->20 MB, reverted).
// grid (t64-tiles=8, gbh=128), 4 waves/block, each wave owns 16 t-rows.
// Wave-private LDS slices, no barriers; padded strides (88/72 u16) keep LDS
// ops <= 2-way. l tracked via ones-column MFMA.
// ---------------------------------------------------------------------------
#define C2S 88   // padded C2 row stride (u16)
#define PS  72   // padded P row stride (u16)
__global__ __launch_bounds__(256, 4) void flash_attn(
    const u16* __restrict__ qu_b, const u16* __restrict__ qv_b,
    const u16* __restrict__ k_b, const u16* __restrict__ vt_b,
    const u16* __restrict__ p_b, u16* __restrict__ aob)
{
    __shared__ __align__(16) u16 C2ld[4][16 * C2S];
    __shared__ __align__(16) u16 Pld[4][16 * PS];
    const int tid = threadIdx.x;
    const int wv = tid >> 6;
    const int lane = tid & 63;
    const int quad = lane >> 4, ln = lane & 15;
    const int gbh = blockIdx.y;
    const int b = gbh >> 3, h = gbh & 7;
    const int t0 = blockIdx.x * 64 + wv * 16;     // wave's first t-row

    const u16* qu = qu_b + (size_t)gbh * 512 * 64;
    const u16* qv = qv_b + (size_t)gbh * 512 * 64;
    const u16* kb = k_b + (size_t)gbh * 512 * 64;
    const u16* vt = vt_b + (size_t)gbh * 64 * 512;
    const u16* pp = p_b + (size_t)h * 1024 * 64;

    // A-fragments (row = t0+ln, k = ks*32 + quad*8), constant across s-tiles
    bf16x8 aqu[2], aqv[2];
#pragma unroll
    for (int ks = 0; ks < 2; ++ks) {
        aqu[ks] = *(const bf16x8*)(qu + (size_t)(t0 + ln) * 64 + ks * 32 + quad * 8);
        aqv[ks] = *(const bf16x8*)(qv + (size_t)(t0 + ln) * 64 + ks * 32 + quad * 8);
    }

    const short ob = (short)0x3F80;               // bf16 1.0
    const bf16x8 vone = {ob, ob, ob, ob, ob, ob, ob, ob};

    f32x4 O[4];
#pragma unroll
    for (int nb = 0; nb < 4; ++nb) O[nb] = (f32x4)0.f;
    f32x4 Lacc = (f32x4)0.f;                      // per-row softmax denom
    float m[4];
#pragma unroll
    for (int r = 0; r < 4; ++r) m[r] = -1e30f;

    u16* c2w = &C2ld[wv][0];
    u16* pw  = &Pld[wv][0];

    for (int s0 = 0; s0 < 512; s0 += 64) {
        // ---- S = qu . k^T (16 x 64) ----
        f32x4 S[4];
#pragma unroll
        for (int nb = 0; nb < 4; ++nb) S[nb] = (f32x4)0.f;
        __builtin_amdgcn_s_setprio(1);
#pragma unroll
        for (int ks = 0; ks < 2; ++ks)
#pragma unroll
            for (int nb = 0; nb < 4; ++nb) {
                const bf16x8 bk = *(const bf16x8*)(kb + (size_t)(s0 + nb * 16 + ln) * 64 + ks * 32 + quad * 8);
                S[nb] = __builtin_amdgcn_mfma_f32_16x16x32_bf16(aqu[ks], bk, S[nb], 0, 0, 0);
            }
        __builtin_amdgcn_s_setprio(0);
        // ---- C2 window = qv . p[jlo..jlo+80)^T (16 x 80) ----
        const int jlo = 496 - t0 + s0;
        f32x4 C2[5];
#pragma unroll
        for (int nb = 0; nb < 5; ++nb) C2[nb] = (f32x4)0.f;
        __builtin_amdgcn_s_setprio(1);
#pragma unroll
        for (int ks = 0; ks < 2; ++ks)
#pragma unroll
            for (int nb = 0; nb < 5; ++nb) {
                const bf16x8 bp = *(const bf16x8*)(pp + (size_t)(jlo + nb * 16 + ln) * 64 + ks * 32 + quad * 8);
                C2[nb] = __builtin_amdgcn_mfma_f32_16x16x32_bf16(aqv[ks], bp, C2[nb], 0, 0, 0);
            }
        __builtin_amdgcn_s_setprio(0);
#pragma unroll
        for (int nb = 0; nb < 5; ++nb)
#pragma unroll
            for (int r = 0; r < 4; ++r)
                c2w[(quad * 4 + r) * C2S + nb * 16 + ln] = f2bf_(C2[nb][r]);

        // ---- S += shifted bd; clamp; row-max ----
        float sv[4][4];
        float rmax[4] = {-1e30f, -1e30f, -1e30f, -1e30f};
#pragma unroll
        for (int nb = 0; nb < 4; ++nb)
#pragma unroll
            for (int r = 0; r < 4; ++r) {
                const int tloc = quad * 4 + r;
                const int col = nb * 16 + ln + 15 - tloc;   // [0,78]
                const float bd = bf2f_(c2w[tloc * C2S + col]);
                const float s = clampd_(S[nb][r] + bd);
                sv[nb][r] = s;
                rmax[r] = fmaxf(rmax[r], s);
            }
#pragma unroll
        for (int off = 1; off < 16; off <<= 1)
#pragma unroll
            for (int r = 0; r < 4; ++r)
                rmax[r] = fmaxf(rmax[r], __shfl_xor(rmax[r], off, 64));

        // ---- online softmax update (no rsum: l tracked via ones-column) ----
        float alpha[4];
#pragma unroll
        for (int r = 0; r < 4; ++r) {
            const float mn = fmaxf(m[r], rmax[r]);
            alpha[r] = __expf(m[r] - mn);
            m[r] = mn;
        }
#pragma unroll
        for (int nb = 0; nb < 4; ++nb)
#pragma unroll
            for (int r = 0; r < 4; ++r) {
                const float p = __expf(sv[nb][r] - m[r]);
                pw[(quad * 4 + r) * PS + nb * 16 + ln] = f2bf_(p);
            }
#pragma unroll
        for (int nb = 0; nb < 4; ++nb)
#pragma unroll
            for (int r = 0; r < 4; ++r) O[nb][r] *= alpha[r];
#pragma unroll
        for (int r = 0; r < 4; ++r) Lacc[r] *= alpha[r];

        // ---- O += P . V ; Lacc += P . 1  (P A-frags from LDS) ----
        __builtin_amdgcn_s_setprio(1);
#pragma unroll
        for (int ks = 0; ks < 2; ++ks) {
            const bf16x8 ap = *(const bf16x8*)&pw[ln * PS + ks * 32 + quad * 8];
#pragma unroll
            for (int nb = 0; nb < 4; ++nb) {
                const bf16x8 bv = *(const bf16x8*)(vt + (size_t)(nb * 16 + ln) * 512 + s0 + ks * 32 + quad * 8);
                O[nb] = __builtin_amdgcn_mfma_f32_16x16x32_bf16(ap, bv, O[nb], 0, 0, 0);
            }
            Lacc = __builtin_amdgcn_mfma_f32_16x16x32_bf16(ap, vone, Lacc, 0, 0, 0);
        }
        __builtin_amdgcn_s_setprio(0);
    }

    // ---- epilogue: normalize and write ao (t,b,c) ----
    float inv[4];
#pragma unroll
    for (int r = 0; r < 4; ++r) inv[r] = 1.f / Lacc[r];
#pragma unroll
    for (int nb = 0; nb < 4; ++nb)
#pragma unroll
        for (int r = 0; r < 4; ++r) {
            const int t = t0 + quad * 4 + r;
            const int d = nb * 16 + ln;
            aob[((size_t)t * B_SZ + b) * 512 + h * 64 + d] = f2bf_(O[nb][r] * inv[r]);
        }
}

// ---------------------------------------------------------------------------
// Conv-module pieces (bf16 chain)
// ---------------------------------------------------------------------------
__global__ __launch_bounds__(256) void dwconv_k(
    const u16* __restrict__ g, const float* __restrict__ wT,
    const float* __restrict__ bb, u16* __restrict__ out)
{
    const int idx = blockIdx.x * 256 + threadIdx.x;
    const int c = idx & 511;
    const int b = (idx >> 9) & 15;
    const int t0 = (idx >> 13) * 8;
    float wr[31];
#pragma unroll
    for (int j = 0; j < 31; ++j) wr[j] = wT[j * 512 + c];
    float win[38];
#pragma unroll
    for (int jj = 0; jj < 38; ++jj) {
        const int tt = t0 - 30 + jj;
        win[jj] = (tt >= 0) ? bf2f_(g[((size_t)tt * B_SZ + b) * 512 + c]) : 0.f;
    }
    const float bias = bb[c];
#pragma unroll
    for (int o = 0; o < 8; ++o) {
        float acc = bias;
#pragma unroll
        for (int j = 0; j < 31; ++j) acc += win[o + j] * wr[j];
        out[((size_t)(t0 + o) * B_SZ + b) * 512 + c] = f2bf_(dswishf_(acc));
    }
}

__global__ __launch_bounds__(256) void norm_k(float* __restrict__ x)
{
    const int row = blockIdx.x * 4 + (threadIdx.x >> 6);
    const int lane = threadIdx.x & 63;
    float* r = x + (size_t)row * 512;
    float v[8];
    float ss = 0.f;
#pragma unroll
    for (int j = 0; j < 8; ++j) { v[j] = r[lane + (j << 6)]; ss += v[j] * v[j]; }
#pragma unroll
    for (int o = 32; o > 0; o >>= 1) ss += __shfl_xor(ss, o, 64);
    const float scale = rsqrtf(ss * (1.f / 512.f) + EPS_BN);
#pragma unroll
    for (int j = 0; j < 8; ++j) r[lane + (j << 6)] = v[j] * scale;
}

// ---------------------------------------------------------------------------
extern "C" void kernel_launch(void* const* d_in, const int* in_sizes, int n_in,
                              void* d_out, int out_size, void* d_ws, size_t ws_size,
                              hipStream_t stream)
{
    const float* src   = (const float*)d_in[0];
    const float* pos   = (const float*)d_in[1];
    const float* fm_w1 = (const float*)d_in[2];
    const float* fm_b1 = (const float*)d_in[3];
    const float* fm_w2 = (const float*)d_in[4];
    const float* fm_b2 = (const float*)d_in[5];
    const float* f_w1  = (const float*)d_in[6];
    const float* f_b1  = (const float*)d_in[7];
    const float* f_w2  = (const float*)d_in[8];
    const float* f_b2  = (const float*)d_in[9];
    const float* ipw   = (const float*)d_in[10];
    const float* ipb   = (const float*)d_in[11];
    const float* opw   = (const float*)d_in[12];
    const float* opb   = (const float*)d_in[13];
    const float* lpw   = (const float*)d_in[14];
    const float* pbu   = (const float*)d_in[15];
    const float* pbv   = (const float*)d_in[16];
    const float* cpw1  = (const float*)d_in[17];
    const float* cpb1  = (const float*)d_in[18];
    const float* cdw   = (const float*)d_in[19];
    const float* cdb   = (const float*)d_in[20];
    const float* cpw2  = (const float*)d_in[21];
    const float* cpb2  = (const float*)d_in[22];

    float* x = (float*)d_out;              // running activation (8192 x 512) f32

    // ---- workspace layout ----
    char* base = (char*)d_ws;
    u16*   wb    = (u16*)base;   base += 6291456ull * 2;   // 9 weights bf16
    u16*   src_b = (u16*)base;   base += 4194304ull * 2;
    u16*   pos_b = (u16*)base;   base += 524288ull * 2;    // 1024x512 padded
    u16*   xb    = (u16*)base;   base += 4194304ull * 2;
    u16*   hb    = (u16*)base;   base += 16777216ull * 2;  // FFN hidden / dwconv out
    u16*   aob   = (u16*)base;   base += 4194304ull * 2;
    u16*   qu_b  = (u16*)base;   base += 4194304ull * 2;
    u16*   qv_b  = (u16*)base;   base += 4194304ull * 2;
    u16*   k_b   = (u16*)base;   base += 4194304ull * 2;
    u16*   v_b   = (u16*)base;   base += 4194304ull * 2;
    u16*   vt_b  = (u16*)base;   base += 4194304ull * 2;
    u16*   p_b   = (u16*)base;   base += 524288ull * 2;    // [8][1024][64]
    float* wTd   = (float*)base; base += 15872ull * 4;
    u16*   glu_o = (u16*)base;   base += 4194304ull * 2;   // conv glu out (8192x512)

    u16* fm_w1b = wb;
    u16* fm_w2b = wb + 1048576;
    u16* f_w1b  = wb + 2097152;
    u16* f_w2b  = wb + 3145728;
    u16* ipwb   = wb + 4194304;
    u16* opwb   = wb + 4980736;
    u16* lpwb   = wb + 5242880;
    u16* cpw1b  = wb + 5505024;
    u16* cpw2b  = wb + 6029312;

    const dim3 blk(256);
    const dim3 blkg(512);

    // 0) all f32 -> bf16 conversions + dw weight transpose, single launch
    WPtrs wp = {{fm_w1, fm_w2, f_w1, f_w2, ipw, opw, lpw, cpw1, cpw2}};
    prep_k<<<dim3(10768), blk, 0, stream>>>(wp, src, pos, cdw, wb, src_b, pos_b, wTd);

    // 1) macaron FFN: x = src + W2 @ dswish(W1 @ src)
    gemm_mfma<1, false, false, true><<<dim3(16, 64), blkg, 0, stream>>>(
        src_b, fm_w1b, fm_b1, nullptr, nullptr, hb, NROWS, 512, DFF_);
    gemm_small<0, true, true, true><<<dim3(8, 128), blk, 0, stream>>>(
        hb, fm_w2b, fm_b2, src, x, xb, NROWS, DFF_, 512);

    // 2) qkv / pos projections with fused repack epilogues; V transpose
    gemm_fused<0><<<dim3(12, 64), blkg, 0, stream>>>(
        xb, ipwb, ipb, pbu, pbv, qu_b, qv_b, k_b, v_b, nullptr, NROWS, 512, 1536);
    gemm_fused<1><<<dim3(4, 8), blkg, 0, stream>>>(
        pos_b, lpwb, nullptr, nullptr, nullptr,
        nullptr, nullptr, nullptr, nullptr, p_b, 1024, 512, 512);
    vt_k<<<dim3(8, 128), blk, 0, stream>>>(v_b, vt_b);

    // 3) fused flash rel-pos attention (single launch, full batch)
    flash_attn<<<dim3(8, 128), blk, 0, stream>>>(qu_b, qv_b, k_b, vt_b, p_b, aob);

    // 4) out projection (residual into x)
    gemm_small<0, true, true, true><<<dim3(8, 128), blk, 0, stream>>>(
        aob, opwb, opb, x, x, xb, NROWS, 512, 512);

    // 5) conv module: pw1+GLU fused -> dwconv(+dswish) -> pw2 (residual)
    gemm_glu_k<<<dim3(4, 64), blkg, 0, stream>>>(xb, cpw1b, cpb1, glu_o);
    dwconv_k<<<dim3(2048), blk, 0, stream>>>(glu_o, wTd, cdb, hb);
    gemm_small<0, true, true, true><<<dim3(8, 128), blk, 0, stream>>>(
        hb, cpw2b, cpb2, x, x, xb, NROWS, 512, 512);

    // 6) second FFN
    gemm_mfma<1, false, false, true><<<dim3(16, 64), blkg, 0, stream>>>(
        xb, f_w1b, f_b1, nullptr, nullptr, hb, NROWS, 512, DFF_);
    gemm_small<0, true, true, false><<<dim3(8, 128), blk, 0, stream>>>(
        hb, f_w2b, f_b2, x, x, nullptr, NROWS, DFF_, 512);

    // 7) BasicNorm
    norm_k<<<dim3(NROWS / 4), blk, 0, stream>>>(x);
}

// Round 10
// 483.731 us; speedup vs baseline: 1.0509x; 1.0509x over previous
//
#include <hip/hip_runtime.h>
#include <math.h>

// Problem constants (ConformerEncoderLayer, T=512 B=16 C=512 H=8 d=64 DFF=2048 K=31)
#define T_SEQ 512
#define B_SZ  16
#define C_DIM 512
#define NH    8
#define HD    64
#define DFF_  2048
#define NROWS (T_SEQ * B_SZ)   // 8192 rows of (t*B+b)
#define EPS_BN 1.2840254166877414f  // exp(0.25)

typedef unsigned short u16;
typedef __attribute__((ext_vector_type(8))) short bf16x8;
typedef __attribute__((ext_vector_type(4))) float f32x4;

__device__ __forceinline__ float sigmoidf_(float x) { return 1.f / (1.f + __expf(-x)); }
__device__ __forceinline__ float dswishf_(float x)  { return x * sigmoidf_(x - 1.f); }
__device__ __forceinline__ float clampd_(float x)   { return fminf(fmaxf(x, -1e4f), 1e4f); }
__device__ __forceinline__ u16 f2bf_(float x) {
    unsigned u = __float_as_uint(x);
    return (u16)((u + 0x7fffu + ((u >> 16) & 1u)) >> 16);
}
__device__ __forceinline__ float bf2f_(u16 u) {
    return __uint_as_float(((unsigned)u) << 16);
}

// ---------------------------------------------------------------------------
// bf16 MFMA GEMM, double-buffered LDS, reg-staged (R0-proven staging).
// R3-proven: 512-thread / 8-wave blocks on a 128x128 tile (wave = 64x32 out,
// acc[4][2]). R9 lesson: 64x64 tiles (more TLP, 2x panel traffic) REGRESS —
// this 128x128 config is the balance point for every GEMM here.
// N,M mult of 128; K mult of 32.
// ---------------------------------------------------------------------------
template <int ACT, bool HAS_RES, bool O32, bool O16>
__global__ __launch_bounds__(512) void gemm_mfma(
    const u16* __restrict__ A, const u16* __restrict__ W,
    const float* __restrict__ bias, const float* __restrict__ res,
    float* __restrict__ out32, u16* __restrict__ out16, int N, int K, int M)
{
    __shared__ __align__(16) u16 As[2][128 * 32];
    __shared__ __align__(16) u16 Bs[2][128 * 32];
    const int tid  = threadIdx.x;
    const int wv   = tid >> 6;
    const int lane = tid & 63;
    const int wm   = wv >> 2, wn = wv & 3;   // 2 x 4 waves, 64x32 out each
    const int m0 = blockIdx.x * 128;
    const int n0 = blockIdx.y * 128;

    const int sc_ = tid & 3;
    const int sr_ = tid >> 2;                // 0..127
    const u16* gA = A + (size_t)(n0 + sr_) * K + sc_ * 8;
    const u16* gB = W + (size_t)(m0 + sr_) * K + sc_ * 8;
    const int ls = sr_ * 32 + sc_ * 8;

    f32x4 acc[4][2];
#pragma unroll
    for (int i = 0; i < 4; ++i)
#pragma unroll
        for (int j = 0; j < 2; ++j) acc[i][j] = (f32x4)0.f;

    const int frow = (lane & 15);
    const int fk   = (lane >> 4) * 8;

    uint4 ra = *(const uint4*)(gA);
    uint4 rb = *(const uint4*)(gB);
    *(uint4*)&As[0][ls] = ra;
    *(uint4*)&Bs[0][ls] = rb;
    __syncthreads();

    int buf = 0;
    for (int k0 = 0; k0 < K; k0 += 32) {
        const bool last = (k0 + 32 >= K);
        if (!last) {
            ra = *(const uint4*)(gA + k0 + 32);
            rb = *(const uint4*)(gB + k0 + 32);
        }
        bf16x8 af[4], bf[2];
#pragma unroll
        for (int i = 0; i < 4; ++i)
            af[i] = *(const bf16x8*)&As[buf][(wm * 64 + i * 16 + frow) * 32 + fk];
#pragma unroll
        for (int j = 0; j < 2; ++j)
            bf[j] = *(const bf16x8*)&Bs[buf][(wn * 32 + j * 16 + frow) * 32 + fk];
#pragma unroll
        for (int i = 0; i < 4; ++i)
#pragma unroll
            for (int j = 0; j < 2; ++j)
                acc[i][j] = __builtin_amdgcn_mfma_f32_16x16x32_bf16(af[i], bf[j], acc[i][j], 0, 0, 0);
        if (!last) {
            const int nb = buf ^ 1;
            *(uint4*)&As[nb][ls] = ra;
            *(uint4*)&Bs[nb][ls] = rb;
            __syncthreads();
            buf = nb;
        }
    }

    const int quad = lane >> 4;
#pragma unroll
    for (int i = 0; i < 4; ++i) {
        const int row = n0 + wm * 64 + i * 16 + quad * 4;
#pragma unroll
        for (int j = 0; j < 2; ++j) {
            const int col = m0 + wn * 32 + j * 16 + (lane & 15);
            const float bv = bias ? bias[col] : 0.f;
#pragma unroll
            for (int r = 0; r < 4; ++r) {
                float v = acc[i][j][r] + bv;
                if (ACT == 1) v = dswishf_(v);
                if (HAS_RES) v += res[(size_t)(row + r) * M + col];
                v = clampd_(v);
                if (O32) out32[(size_t)(row + r) * M + col] = v;
                if (O16) out16[(size_t)(row + r) * M + col] = f2bf_(v);
            }
        }
    }
}

// ---------------------------------------------------------------------------
// R10: merged qkv + pos projection GEMM (both K=512, same dbuf body).
// Grid (12, 72): y<64 -> qkv block (N=8192 x M=1536, fused repack epilogue);
// y>=64 -> pos block (N=1024 x M=512; x>=4 early-exits, 64 idle blocks).
// The 32-block pos GEMM previously ran ALONE (~10us, 97% of GPU idle) plus a
// launch gap; merged, it fills CU slack during the 768-block qkv GEMM.
// Branch is block-uniform (no divergence).
// EPI qkv: writes qu/qv/k/v bf16 in [b*8+h][t][d], q*0.125 + u/v bias.
//   (R7 lesson: V must NOT be written transposed here — 2B/lane scatter at
//    1KB stride killed coalescing. vt_k's LDS-tiled transpose is cheaper.)
// EPI pos: writes p_b[h][j][d] bf16.
// ---------------------------------------------------------------------------
__global__ __launch_bounds__(512) void gemm_qkvpos(
    const u16* __restrict__ Aq, const u16* __restrict__ Wq,
    const u16* __restrict__ Ap, const u16* __restrict__ Wp,
    const float* __restrict__ bias, const float* __restrict__ ub, const float* __restrict__ vb,
    u16* __restrict__ o_qu, u16* __restrict__ o_qv, u16* __restrict__ o_k,
    u16* __restrict__ o_v, u16* __restrict__ o_p)
{
    __shared__ __align__(16) u16 As[2][128 * 32];
    __shared__ __align__(16) u16 Bs[2][128 * 32];
    const bool isPos = (blockIdx.y >= 64);
    if (isPos && blockIdx.x >= 4) return;
    const u16* A = isPos ? Ap : Aq;
    const u16* W = isPos ? Wp : Wq;
    const int K = 512;
    const int tid  = threadIdx.x;
    const int wv   = tid >> 6;
    const int lane = tid & 63;
    const int wm   = wv >> 2, wn = wv & 3;
    const int m0 = blockIdx.x * 128;
    const int n0 = (isPos ? ((int)blockIdx.y - 64) : (int)blockIdx.y) * 128;

    const int sc_ = tid & 3;
    const int sr_ = tid >> 2;
    const u16* gA = A + (size_t)(n0 + sr_) * K + sc_ * 8;
    const u16* gB = W + (size_t)(m0 + sr_) * K + sc_ * 8;
    const int ls = sr_ * 32 + sc_ * 8;

    f32x4 acc[4][2];
#pragma unroll
    for (int i = 0; i < 4; ++i)
#pragma unroll
        for (int j = 0; j < 2; ++j) acc[i][j] = (f32x4)0.f;

    const int frow = (lane & 15);
    const int fk   = (lane >> 4) * 8;

    uint4 ra = *(const uint4*)(gA);
    uint4 rb = *(const uint4*)(gB);
    *(uint4*)&As[0][ls] = ra;
    *(uint4*)&Bs[0][ls] = rb;
    __syncthreads();

    int buf = 0;
    for (int k0 = 0; k0 < K; k0 += 32) {
        const bool last = (k0 + 32 >= K);
        if (!last) {
            ra = *(const uint4*)(gA + k0 + 32);
            rb = *(const uint4*)(gB + k0 + 32);
        }
        bf16x8 af[4], bf[2];
#pragma unroll
        for (int i = 0; i < 4; ++i)
            af[i] = *(const bf16x8*)&As[buf][(wm * 64 + i * 16 + frow) * 32 + fk];
#pragma unroll
        for (int j = 0; j < 2; ++j)
            bf[j] = *(const bf16x8*)&Bs[buf][(wn * 32 + j * 16 + frow) * 32 + fk];
#pragma unroll
        for (int i = 0; i < 4; ++i)
#pragma unroll
            for (int j = 0; j < 2; ++j)
                acc[i][j] = __builtin_amdgcn_mfma_f32_16x16x32_bf16(af[i], bf[j], acc[i][j], 0, 0, 0);
        if (!last) {
            const int nb = buf ^ 1;
            *(uint4*)&As[nb][ls] = ra;
            *(uint4*)&Bs[nb][ls] = rb;
            __syncthreads();
            buf = nb;
        }
    }

    const int quad = lane >> 4;
#pragma unroll
    for (int i = 0; i < 4; ++i) {
        const int rowb = n0 + wm * 64 + i * 16 + quad * 4;
#pragma unroll
        for (int j = 0; j < 2; ++j) {
            const int col = m0 + wn * 32 + j * 16 + (lane & 15);
            if (!isPos) {
                const float bv = bias[col];
                const int c = col & 511, h = c >> 6, d = c & 63;
#pragma unroll
                for (int r = 0; r < 4; ++r) {
                    const int row = rowb + r;
                    const float v = clampd_(acc[i][j][r] + bv);
                    const int t = row >> 4, b = row & 15;
                    const size_t dst = ((size_t)(b * 8 + h) * 512 + t) * 64 + d;
                    if (col < 512) {
                        o_qu[dst] = f2bf_(v * 0.125f + ub[c]);
                        o_qv[dst] = f2bf_(v * 0.125f + vb[c]);
                    } else if (col < 1024) {
                        o_k[dst] = f2bf_(v);
                    } else {
                        o_v[dst] = f2bf_(v);
                    }
                }
            } else {
                const int h = col >> 6, d = col & 63;
#pragma unroll
                for (int r = 0; r < 4; ++r)
                    o_p[(size_t)h * 65536 + (size_t)(rowb + r) * 64 + d] = f2bf_(acc[i][j][r]);
            }
        }
    }
}

// ---------------------------------------------------------------------------
// pw1 GEMM with fused GLU (R6-proven). Writes a*sigmoid(g) bf16 to glu_o.
// ---------------------------------------------------------------------------
__global__ __launch_bounds__(512) void gemm_glu_k(
    const u16* __restrict__ A, const u16* __restrict__ W,
    const float* __restrict__ bias, u16* __restrict__ out)
{
    __shared__ __align__(16) u16 As[2][128 * 32];
    __shared__ __align__(16) u16 Ba[2][128 * 32];
    __shared__ __align__(16) u16 Bg[2][128 * 32];
    const int tid  = threadIdx.x;
    const int wv   = tid >> 6;
    const int lane = tid & 63;
    const int wm   = wv >> 2, wn = wv & 3;
    const int m0 = blockIdx.x * 128;
    const int n0 = blockIdx.y * 128;
    const int K = 512;

    const int sc_ = tid & 3;
    const int sr_ = tid >> 2;
    const u16* gA  = A + (size_t)(n0 + sr_) * K + sc_ * 8;
    const u16* gBa = W + (size_t)(m0 + sr_) * K + sc_ * 8;
    const u16* gBg = W + (size_t)(m0 + 512 + sr_) * K + sc_ * 8;
    const int ls = sr_ * 32 + sc_ * 8;

    f32x4 aa[4][2], ag[4][2];
#pragma unroll
    for (int i = 0; i < 4; ++i)
#pragma unroll
        for (int j = 0; j < 2; ++j) { aa[i][j] = (f32x4)0.f; ag[i][j] = (f32x4)0.f; }

    const int frow = (lane & 15);
    const int fk   = (lane >> 4) * 8;

    uint4 ra  = *(const uint4*)(gA);
    uint4 rba = *(const uint4*)(gBa);
    uint4 rbg = *(const uint4*)(gBg);
    *(uint4*)&As[0][ls] = ra;
    *(uint4*)&Ba[0][ls] = rba;
    *(uint4*)&Bg[0][ls] = rbg;
    __syncthreads();

    int buf = 0;
    for (int k0 = 0; k0 < K; k0 += 32) {
        const bool last = (k0 + 32 >= K);
        if (!last) {
            ra  = *(const uint4*)(gA + k0 + 32);
            rba = *(const uint4*)(gBa + k0 + 32);
            rbg = *(const uint4*)(gBg + k0 + 32);
        }
        bf16x8 af[4], bfa[2], bfg[2];
#pragma unroll
        for (int i = 0; i < 4; ++i)
            af[i] = *(const bf16x8*)&As[buf][(wm * 64 + i * 16 + frow) * 32 + fk];
#pragma unroll
        for (int j = 0; j < 2; ++j) {
            bfa[j] = *(const bf16x8*)&Ba[buf][(wn * 32 + j * 16 + frow) * 32 + fk];
            bfg[j] = *(const bf16x8*)&Bg[buf][(wn * 32 + j * 16 + frow) * 32 + fk];
        }
#pragma unroll
        for (int i = 0; i < 4; ++i)
#pragma unroll
            for (int j = 0; j < 2; ++j) {
                aa[i][j] = __builtin_amdgcn_mfma_f32_16x16x32_bf16(af[i], bfa[j], aa[i][j], 0, 0, 0);
                ag[i][j] = __builtin_amdgcn_mfma_f32_16x16x32_bf16(af[i], bfg[j], ag[i][j], 0, 0, 0);
            }
        if (!last) {
            const int nb = buf ^ 1;
            *(uint4*)&As[nb][ls] = ra;
            *(uint4*)&Ba[nb][ls] = rba;
            *(uint4*)&Bg[nb][ls] = rbg;
            __syncthreads();
            buf = nb;
        }
    }

    const int quad = lane >> 4;
#pragma unroll
    for (int i = 0; i < 4; ++i) {
        const int row = n0 + wm * 64 + i * 16 + quad * 4;
#pragma unroll
        for (int j = 0; j < 2; ++j) {
            const int col = m0 + wn * 32 + j * 16 + (lane & 15);
            const float ba = bias[col];
            const float bg = bias[col + 512];
#pragma unroll
            for (int r = 0; r < 4; ++r) {
                const float a = clampd_(aa[i][j][r] + ba);
                const float g = clampd_(ag[i][j][r] + bg);
                out[(size_t)(row + r) * 512 + col] = f2bf_(a * sigmoidf_(g));
            }
        }
    }
}

// ---------------------------------------------------------------------------
// f32 -> bf16 converters / prep (merged single launch, R6-proven)
// ---------------------------------------------------------------------------
__device__ __forceinline__ void store_bf4_(u16* out, float4 v) {
    const unsigned lo = (unsigned)f2bf_(v.x) | ((unsigned)f2bf_(v.y) << 16);
    const unsigned hi = (unsigned)f2bf_(v.z) | ((unsigned)f2bf_(v.w) << 16);
    *(uint2*)out = make_uint2(lo, hi);
}

struct WPtrs { const float* p[9]; };
__global__ __launch_bounds__(256) void prep_k(
    WPtrs wp, const float* __restrict__ src, const float* __restrict__ pos,
    const float* __restrict__ cdw,
    u16* __restrict__ wb, u16* __restrict__ src_b, u16* __restrict__ pos_b,
    float* __restrict__ wTd)
{
    const int e = (blockIdx.x * 256 + threadIdx.x) * 4;
    if (e < 6291456) {
        static const int off[10] = {0, 1048576, 2097152, 3145728, 4194304,
                                    4980736, 5242880, 5505024, 6029312, 6291456};
        int r = 0;
#pragma unroll
        for (int k = 1; k < 9; ++k) r += (e >= off[k]);
        store_bf4_(wb + e, *(const float4*)(wp.p[r] + (e - off[r])));
    } else if (e < 6291456 + 4194304) {
        const int e2 = e - 6291456;
        store_bf4_(src_b + e2, *(const float4*)(src + e2));
    } else if (e < 6291456 + 4194304 + 524288) {
        const int e2 = e - (6291456 + 4194304);
        float4 v = make_float4(0.f, 0.f, 0.f, 0.f);
        if (e2 < 1023 * 512) v = *(const float4*)(pos + e2);
        store_bf4_(pos_b + e2, v);
    } else {
        const int e2 = e - (6291456 + 4194304 + 524288);
        if (e2 < 15872) {
#pragma unroll
            for (int q = 0; q < 4; ++q) {
                const int i2 = e2 + q;
                const int j = i2 >> 9, c = i2 & 511;
                wTd[i2] = cdw[c * 31 + j];
            }
        }
    }
}

// v_b[gbh][s][d] -> vt_b[gbh][d][s]  (64x64 LDS tile transpose; R7 lesson:
// this is cheaper than scattering the transpose into the GEMM epilogue)
__global__ __launch_bounds__(256) void vt_k(const u16* __restrict__ in, u16* __restrict__ out)
{
    __shared__ u16 tile[64][65];
    const int s0 = blockIdx.x * 64;
    const int gbh = blockIdx.y;
    const u16* src = in + (size_t)gbh * 512 * 64;
    u16* dst = out + (size_t)gbh * 64 * 512;
    const int tid = threadIdx.x;
#pragma unroll
    for (int q = 0; q < 2; ++q) {
        const int lin = tid * 2 + q;             // 0..511 uint4s
        const int srow = lin >> 3, c8 = (lin & 7) * 8;
        const uint4 v = *(const uint4*)(src + (size_t)(s0 + srow) * 64 + c8);
        const u16* vu = (const u16*)&v;
#pragma unroll
        for (int e = 0; e < 8; ++e) tile[srow][c8 + e] = vu[e];
    }
    __syncthreads();
#pragma unroll
    for (int q = 0; q < 2; ++q) {
        const int lin = tid * 2 + q;
        const int d = lin >> 3, sc8 = (lin & 7) * 8;
        u16 o[8];
#pragma unroll
        for (int e = 0; e < 8; ++e) o[e] = tile[sc8 + e][d];
        *(uint4*)(dst + (size_t)d * 512 + s0 + sc8) = *(uint4*)o;
    }
}

// ---------------------------------------------------------------------------
// Fused flash rel-pos attention (R6-proven body, dynamic s-loop).
// Plateau note: 6 structural attacks (split-S x2, manual prefetch, bpermute
// gather, full unroll) all regressed or were neutral — this body is the
// proven local optimum (~104 us, latency-bound, register-capped occupancy).
// grid (t64-tiles=8, gbh=128), 4 waves/block, each wave owns 16 t-rows.
// Wave-private LDS slices, no barriers; padded strides (88/72 u16) keep LDS
// ops <= 2-way. l tracked via ones-column MFMA.
// ---------------------------------------------------------------------------
#define C2S 88   // padded C2 row stride (u16)
#define PS  72   // padded P row stride (u16)
__global__ __launch_bounds__(256, 4) void flash_attn(
    const u16* __restrict__ qu_b, const u16* __restrict__ qv_b,
    const u16* __restrict__ k_b, const u16* __restrict__ vt_b,
    const u16* __restrict__ p_b, u16* __restrict__ aob)
{
    __shared__ __align__(16) u16 C2ld[4][16 * C2S];
    __shared__ __align__(16) u16 Pld[4][16 * PS];
    const int tid = threadIdx.x;
    const int wv = tid >> 6;
    const int lane = tid & 63;
    const int quad = lane >> 4, ln = lane & 15;
    const int gbh = blockIdx.y;
    const int b = gbh >> 3, h = gbh & 7;
    const int t0 = blockIdx.x * 64 + wv * 16;     // wave's first t-row

    const u16* qu = qu_b + (size_t)gbh * 512 * 64;
    const u16* qv = qv_b + (size_t)gbh * 512 * 64;
    const u16* kb = k_b + (size_t)gbh * 512 * 64;
    const u16* vt = vt_b + (size_t)gbh * 64 * 512;
    const u16* pp = p_b + (size_t)h * 1024 * 64;

    // A-fragments (row = t0+ln, k = ks*32 + quad*8), constant across s-tiles
    bf16x8 aqu[2], aqv[2];
#pragma unroll
    for (int ks = 0; ks < 2; ++ks) {
        aqu[ks] = *(const bf16x8*)(qu + (size_t)(t0 + ln) * 64 + ks * 32 + quad * 8);
        aqv[ks] = *(const bf16x8*)(qv + (size_t)(t0 + ln) * 64 + ks * 32 + quad * 8);
    }

    const short ob = (short)0x3F80;               // bf16 1.0
    const bf16x8 vone = {ob, ob, ob, ob, ob, ob, ob, ob};

    f32x4 O[4];
#pragma unroll
    for (int nb = 0; nb < 4; ++nb) O[nb] = (f32x4)0.f;
    f32x4 Lacc = (f32x4)0.f;                      // per-row softmax denom
    float m[4];
#pragma unroll
    for (int r = 0; r < 4; ++r) m[r] = -1e30f;

    u16* c2w = &C2ld[wv][0];
    u16* pw  = &Pld[wv][0];

    for (int s0 = 0; s0 < 512; s0 += 64) {
        // ---- S = qu . k^T (16 x 64) ----
        f32x4 S[4];
#pragma unroll
        for (int nb = 0; nb < 4; ++nb) S[nb] = (f32x4)0.f;
        __builtin_amdgcn_s_setprio(1);
#pragma unroll
        for (int ks = 0; ks < 2; ++ks)
#pragma unroll
            for (int nb = 0; nb < 4; ++nb) {
                const bf16x8 bk = *(const bf16x8*)(kb + (size_t)(s0 + nb * 16 + ln) * 64 + ks * 32 + quad * 8);
                S[nb] = __builtin_amdgcn_mfma_f32_16x16x32_bf16(aqu[ks], bk, S[nb], 0, 0, 0);
            }
        __builtin_amdgcn_s_setprio(0);
        // ---- C2 window = qv . p[jlo..jlo+80)^T (16 x 80) ----
        const int jlo = 496 - t0 + s0;
        f32x4 C2[5];
#pragma unroll
        for (int nb = 0; nb < 5; ++nb) C2[nb] = (f32x4)0.f;
        __builtin_amdgcn_s_setprio(1);
#pragma unroll
        for (int ks = 0; ks < 2; ++ks)
#pragma unroll
            for (int nb = 0; nb < 5; ++nb) {
                const bf16x8 bp = *(const bf16x8*)(pp + (size_t)(jlo + nb * 16 + ln) * 64 + ks * 32 + quad * 8);
                C2[nb] = __builtin_amdgcn_mfma_f32_16x16x32_bf16(aqv[ks], bp, C2[nb], 0, 0, 0);
            }
        __builtin_amdgcn_s_setprio(0);
#pragma unroll
        for (int nb = 0; nb < 5; ++nb)
#pragma unroll
            for (int r = 0; r < 4; ++r)
                c2w[(quad * 4 + r) * C2S + nb * 16 + ln] = f2bf_(C2[nb][r]);

        // ---- S += shifted bd; clamp; row-max ----
        float sv[4][4];
        float rmax[4] = {-1e30f, -1e30f, -1e30f, -1e30f};
#pragma unroll
        for (int nb = 0; nb < 4; ++nb)
#pragma unroll
            for (int r = 0; r < 4; ++r) {
                const int tloc = quad * 4 + r;
                const int col = nb * 16 + ln + 15 - tloc;   // [0,78]
                const float bd = bf2f_(c2w[tloc * C2S + col]);
                const float s = clampd_(S[nb][r] + bd);
                sv[nb][r] = s;
                rmax[r] = fmaxf(rmax[r], s);
            }
#pragma unroll
        for (int off = 1; off < 16; off <<= 1)
#pragma unroll
            for (int r = 0; r < 4; ++r)
                rmax[r] = fmaxf(rmax[r], __shfl_xor(rmax[r], off, 64));

        // ---- online softmax update (no rsum: l tracked via ones-column) ----
        float alpha[4];
#pragma unroll
        for (int r = 0; r < 4; ++r) {
            const float mn = fmaxf(m[r], rmax[r]);
            alpha[r] = __expf(m[r] - mn);
            m[r] = mn;
        }
#pragma unroll
        for (int nb = 0; nb < 4; ++nb)
#pragma unroll
            for (int r = 0; r < 4; ++r) {
                const float p = __expf(sv[nb][r] - m[r]);
                pw[(quad * 4 + r) * PS + nb * 16 + ln] = f2bf_(p);
            }
#pragma unroll
        for (int nb = 0; nb < 4; ++nb)
#pragma unroll
            for (int r = 0; r < 4; ++r) O[nb][r] *= alpha[r];
#pragma unroll
        for (int r = 0; r < 4; ++r) Lacc[r] *= alpha[r];

        // ---- O += P . V ; Lacc += P . 1  (P A-frags from LDS) ----
        __builtin_amdgcn_s_setprio(1);
#pragma unroll
        for (int ks = 0; ks < 2; ++ks) {
            const bf16x8 ap = *(const bf16x8*)&pw[ln * PS + ks * 32 + quad * 8];
#pragma unroll
            for (int nb = 0; nb < 4; ++nb) {
                const bf16x8 bv = *(const bf16x8*)(vt + (size_t)(nb * 16 + ln) * 512 + s0 + ks * 32 + quad * 8);
                O[nb] = __builtin_amdgcn_mfma_f32_16x16x32_bf16(ap, bv, O[nb], 0, 0, 0);
            }
            Lacc = __builtin_amdgcn_mfma_f32_16x16x32_bf16(ap, vone, Lacc, 0, 0, 0);
        }
        __builtin_amdgcn_s_setprio(0);
    }

    // ---- epilogue: normalize and write ao (t,b,c) ----
    float inv[4];
#pragma unroll
    for (int r = 0; r < 4; ++r) inv[r] = 1.f / Lacc[r];
#pragma unroll
    for (int nb = 0; nb < 4; ++nb)
#pragma unroll
        for (int r = 0; r < 4; ++r) {
            const int t = t0 + quad * 4 + r;
            const int d = nb * 16 + ln;
            aob[((size_t)t * B_SZ + b) * 512 + h * 64 + d] = f2bf_(O[nb][r] * inv[r]);
        }
}

// ---------------------------------------------------------------------------
// Conv-module pieces (bf16 chain)
// ---------------------------------------------------------------------------
__global__ __launch_bounds__(256) void dwconv_k(
    const u16* __restrict__ g, const float* __restrict__ wT,
    const float* __restrict__ bb, u16* __restrict__ out)
{
    const int idx = blockIdx.x * 256 + threadIdx.x;
    const int c = idx & 511;
    const int b = (idx >> 9) & 15;
    const int t0 = (idx >> 13) * 8;
    float wr[31];
#pragma unroll
    for (int j = 0; j < 31; ++j) wr[j] = wT[j * 512 + c];
    float win[38];
#pragma unroll
    for (int jj = 0; jj < 38; ++jj) {
        const int tt = t0 - 30 + jj;
        win[jj] = (tt >= 0) ? bf2f_(g[((size_t)tt * B_SZ + b) * 512 + c]) : 0.f;
    }
    const float bias = bb[c];
#pragma unroll
    for (int o = 0; o < 8; ++o) {
        float acc = bias;
#pragma unroll
        for (int j = 0; j < 31; ++j) acc += win[o + j] * wr[j];
        out[((size_t)(t0 + o) * B_SZ + b) * 512 + c] = f2bf_(dswishf_(acc));
    }
}

__global__ __launch_bounds__(256) void norm_k(float* __restrict__ x)
{
    const int row = blockIdx.x * 4 + (threadIdx.x >> 6);
    const int lane = threadIdx.x & 63;
    float* r = x + (size_t)row * 512;
    float v[8];
    float ss = 0.f;
#pragma unroll
    for (int j = 0; j < 8; ++j) { v[j] = r[lane + (j << 6)]; ss += v[j] * v[j]; }
#pragma unroll
    for (int o = 32; o > 0; o >>= 1) ss += __shfl_xor(ss, o, 64);
    const float scale = rsqrtf(ss * (1.f / 512.f) + EPS_BN);
#pragma unroll
    for (int j = 0; j < 8; ++j) r[lane + (j << 6)] = v[j] * scale;
}

// ---------------------------------------------------------------------------
extern "C" void kernel_launch(void* const* d_in, const int* in_sizes, int n_in,
                              void* d_out, int out_size, void* d_ws, size_t ws_size,
                              hipStream_t stream)
{
    const float* src   = (const float*)d_in[0];
    const float* pos   = (const float*)d_in[1];
    const float* fm_w1 = (const float*)d_in[2];
    const float* fm_b1 = (const float*)d_in[3];
    const float* fm_w2 = (const float*)d_in[4];
    const float* fm_b2 = (const float*)d_in[5];
    const float* f_w1  = (const float*)d_in[6];
    const float* f_b1  = (const float*)d_in[7];
    const float* f_w2  = (const float*)d_in[8];
    const float* f_b2  = (const float*)d_in[9];
    const float* ipw   = (const float*)d_in[10];
    const float* ipb   = (const float*)d_in[11];
    const float* opw   = (const float*)d_in[12];
    const float* opb   = (const float*)d_in[13];
    const float* lpw   = (const float*)d_in[14];
    const float* pbu   = (const float*)d_in[15];
    const float* pbv   = (const float*)d_in[16];
    const float* cpw1  = (const float*)d_in[17];
    const float* cpb1  = (const float*)d_in[18];
    const float* cdw   = (const float*)d_in[19];
    const float* cdb   = (const float*)d_in[20];
    const float* cpw2  = (const float*)d_in[21];
    const float* cpb2  = (const float*)d_in[22];

    float* x = (float*)d_out;              // running activation (8192 x 512) f32

    // ---- workspace layout ----
    char* base = (char*)d_ws;
    u16*   wb    = (u16*)base;   base += 6291456ull * 2;   // 9 weights bf16
    u16*   src_b = (u16*)base;   base += 4194304ull * 2;
    u16*   pos_b = (u16*)base;   base += 524288ull * 2;    // 1024x512 padded
    u16*   xb    = (u16*)base;   base += 4194304ull * 2;
    u16*   hb    = (u16*)base;   base += 16777216ull * 2;  // FFN hidden / dwconv out
    u16*   aob   = (u16*)base;   base += 4194304ull * 2;
    u16*   qu_b  = (u16*)base;   base += 4194304ull * 2;
    u16*   qv_b  = (u16*)base;   base += 4194304ull * 2;
    u16*   k_b   = (u16*)base;   base += 4194304ull * 2;
    u16*   v_b   = (u16*)base;   base += 4194304ull * 2;
    u16*   vt_b  = (u16*)base;   base += 4194304ull * 2;
    u16*   p_b   = (u16*)base;   base += 524288ull * 2;    // [8][1024][64]
    float* wTd   = (float*)base; base += 15872ull * 4;
    u16*   glu_o = (u16*)base;   base += 4194304ull * 2;   // conv glu out (8192x512)

    u16* fm_w1b = wb;
    u16* fm_w2b = wb + 1048576;
    u16* f_w1b  = wb + 2097152;
    u16* f_w2b  = wb + 3145728;
    u16* ipwb   = wb + 4194304;
    u16* opwb   = wb + 4980736;
    u16* lpwb   = wb + 5242880;
    u16* cpw1b  = wb + 5505024;
    u16* cpw2b  = wb + 6029312;

    const dim3 blk(256);
    const dim3 blkg(512);

    // 0) all f32 -> bf16 conversions + dw weight transpose, single launch
    WPtrs wp = {{fm_w1, fm_w2, f_w1, f_w2, ipw, opw, lpw, cpw1, cpw2}};
    prep_k<<<dim3(10768), blk, 0, stream>>>(wp, src, pos, cdw, wb, src_b, pos_b, wTd);

    // 1) macaron FFN: x = src + W2 @ dswish(W1 @ src)
    gemm_mfma<1, false, false, true><<<dim3(16, 64), blkg, 0, stream>>>(
        src_b, fm_w1b, fm_b1, nullptr, nullptr, hb, NROWS, 512, DFF_);
    gemm_mfma<0, true, true, true><<<dim3(4, 64), blkg, 0, stream>>>(
        hb, fm_w2b, fm_b2, src, x, xb, NROWS, DFF_, 512);

    // 2) qkv + pos projections in ONE launch (pos fills CU slack); V transpose
    gemm_qkvpos<<<dim3(12, 72), blkg, 0, stream>>>(
        xb, ipwb, pos_b, lpwb, ipb, pbu, pbv, qu_b, qv_b, k_b, v_b, p_b);
    vt_k<<<dim3(8, 128), blk, 0, stream>>>(v_b, vt_b);

    // 3) fused flash rel-pos attention (single launch, full batch)
    flash_attn<<<dim3(8, 128), blk, 0, stream>>>(qu_b, qv_b, k_b, vt_b, p_b, aob);

    // 4) out projection (residual into x)
    gemm_mfma<0, true, true, true><<<dim3(4, 64), blkg, 0, stream>>>(
        aob, opwb, opb, x, x, xb, NROWS, 512, 512);

    // 5) conv module: pw1+GLU fused -> dwconv(+dswish) -> pw2 (residual)
    gemm_glu_k<<<dim3(4, 64), blkg, 0, stream>>>(xb, cpw1b, cpb1, glu_o);
    dwconv_k<<<dim3(2048), blk, 0, stream>>>(glu_o, wTd, cdb, hb);
    gemm_mfma<0, true, true, true><<<dim3(4, 64), blkg, 0, stream>>>(
        hb, cpw2b, cpb2, x, x, xb, NROWS, 512, 512);

    // 6) second FFN
    gemm_mfma<1, false, false, true><<<dim3(16, 64), blkg, 0, stream>>>(
        xb, f_w1b, f_b1, nullptr, nullptr, hb, NROWS, 512, DFF_);
    gemm_mfma<0, true, true, false><<<dim3(4, 64), blkg, 0, stream>>>(
        hb, f_w2b, f_b2, x, x, nullptr, NROWS, DFF_, 512);

    // 7) BasicNorm
    norm_k<<<dim3(NROWS / 4), blk, 0, stream>>>(x);
}

// Round 11
// 480.067 us; speedup vs baseline: 1.0589x; 1.0076x over previous
//
#include <hip/hip_runtime.h>
#include <math.h>

// Problem constants (ConformerEncoderLayer, T=512 B=16 C=512 H=8 d=64 DFF=2048 K=31)
#define T_SEQ 512
#define B_SZ  16
#define C_DIM 512
#define NH    8
#define HD    64
#define DFF_  2048
#define NROWS (T_SEQ * B_SZ)   // 8192 rows of (t*B+b)
#define EPS_BN 1.2840254166877414f  // exp(0.25)

typedef unsigned short u16;
typedef __attribute__((ext_vector_type(8))) short bf16x8;
typedef __attribute__((ext_vector_type(4))) float f32x4;

__device__ __forceinline__ float sigmoidf_(float x) { return 1.f / (1.f + __expf(-x)); }
__device__ __forceinline__ float dswishf_(float x)  { return x * sigmoidf_(x - 1.f); }
__device__ __forceinline__ float clampd_(float x)   { return fminf(fmaxf(x, -1e4f), 1e4f); }
__device__ __forceinline__ u16 f2bf_(float x) {
    unsigned u = __float_as_uint(x);
    return (u16)((u + 0x7fffu + ((u >> 16) & 1u)) >> 16);
}
__device__ __forceinline__ float bf2f_(u16 u) {
    return __uint_as_float(((unsigned)u) << 16);
}

// ---------------------------------------------------------------------------
// bf16 MFMA GEMM, double-buffered LDS, reg-staged (R0-proven staging).
// R3-proven: 512-thread / 8-wave blocks on a 128x128 tile (wave = 64x32 out,
// acc[4][2]). R9 lesson: 64x64 tiles (more TLP, 2x panel traffic) REGRESS —
// this 128x128 config is the balance point for every GEMM here.
// N,M mult of 128; K mult of 32.
// ---------------------------------------------------------------------------
template <int ACT, bool HAS_RES, bool O32, bool O16>
__global__ __launch_bounds__(512) void gemm_mfma(
    const u16* __restrict__ A, const u16* __restrict__ W,
    const float* __restrict__ bias, const float* __restrict__ res,
    float* __restrict__ out32, u16* __restrict__ out16, int N, int K, int M)
{
    __shared__ __align__(16) u16 As[2][128 * 32];
    __shared__ __align__(16) u16 Bs[2][128 * 32];
    const int tid  = threadIdx.x;
    const int wv   = tid >> 6;
    const int lane = tid & 63;
    const int wm   = wv >> 2, wn = wv & 3;   // 2 x 4 waves, 64x32 out each
    const int m0 = blockIdx.x * 128;
    const int n0 = blockIdx.y * 128;

    const int sc_ = tid & 3;
    const int sr_ = tid >> 2;                // 0..127
    const u16* gA = A + (size_t)(n0 + sr_) * K + sc_ * 8;
    const u16* gB = W + (size_t)(m0 + sr_) * K + sc_ * 8;
    const int ls = sr_ * 32 + sc_ * 8;

    f32x4 acc[4][2];
#pragma unroll
    for (int i = 0; i < 4; ++i)
#pragma unroll
        for (int j = 0; j < 2; ++j) acc[i][j] = (f32x4)0.f;

    const int frow = (lane & 15);
    const int fk   = (lane >> 4) * 8;

    uint4 ra = *(const uint4*)(gA);
    uint4 rb = *(const uint4*)(gB);
    *(uint4*)&As[0][ls] = ra;
    *(uint4*)&Bs[0][ls] = rb;
    __syncthreads();

    int buf = 0;
    for (int k0 = 0; k0 < K; k0 += 32) {
        const bool last = (k0 + 32 >= K);
        if (!last) {
            ra = *(const uint4*)(gA + k0 + 32);
            rb = *(const uint4*)(gB + k0 + 32);
        }
        bf16x8 af[4], bf[2];
#pragma unroll
        for (int i = 0; i < 4; ++i)
            af[i] = *(const bf16x8*)&As[buf][(wm * 64 + i * 16 + frow) * 32 + fk];
#pragma unroll
        for (int j = 0; j < 2; ++j)
            bf[j] = *(const bf16x8*)&Bs[buf][(wn * 32 + j * 16 + frow) * 32 + fk];
#pragma unroll
        for (int i = 0; i < 4; ++i)
#pragma unroll
            for (int j = 0; j < 2; ++j)
                acc[i][j] = __builtin_amdgcn_mfma_f32_16x16x32_bf16(af[i], bf[j], acc[i][j], 0, 0, 0);
        if (!last) {
            const int nb = buf ^ 1;
            *(uint4*)&As[nb][ls] = ra;
            *(uint4*)&Bs[nb][ls] = rb;
            __syncthreads();
            buf = nb;
        }
    }

    const int quad = lane >> 4;
#pragma unroll
    for (int i = 0; i < 4; ++i) {
        const int row = n0 + wm * 64 + i * 16 + quad * 4;
#pragma unroll
        for (int j = 0; j < 2; ++j) {
            const int col = m0 + wn * 32 + j * 16 + (lane & 15);
            const float bv = bias ? bias[col] : 0.f;
#pragma unroll
            for (int r = 0; r < 4; ++r) {
                float v = acc[i][j][r] + bv;
                if (ACT == 1) v = dswishf_(v);
                if (HAS_RES) v += res[(size_t)(row + r) * M + col];
                v = clampd_(v);
                if (O32) out32[(size_t)(row + r) * M + col] = v;
                if (O16) out16[(size_t)(row + r) * M + col] = f2bf_(v);
            }
        }
    }
}

// ---------------------------------------------------------------------------
// Merged qkv + pos projection GEMM (both K=512, same dbuf body; R10, neutral
// but kept: one fewer launch). Grid (12, 72): y<64 -> qkv block; y>=64 ->
// pos block (x>=4 early-exits). Branch is block-uniform.
// EPI qkv: writes qu/qv/k/v bf16 in [b*8+h][t][d], q*0.125 + u/v bias.
//   (R7 lesson: V must NOT be written transposed here — 2B/lane scatter at
//    1KB stride killed coalescing. vt_k's LDS-tiled transpose is cheaper.)
// EPI pos: writes p_b[h][j][d] bf16.
// ---------------------------------------------------------------------------
__global__ __launch_bounds__(512) void gemm_qkvpos(
    const u16* __restrict__ Aq, const u16* __restrict__ Wq,
    const u16* __restrict__ Ap, const u16* __restrict__ Wp,
    const float* __restrict__ bias, const float* __restrict__ ub, const float* __restrict__ vb,
    u16* __restrict__ o_qu, u16* __restrict__ o_qv, u16* __restrict__ o_k,
    u16* __restrict__ o_v, u16* __restrict__ o_p)
{
    __shared__ __align__(16) u16 As[2][128 * 32];
    __shared__ __align__(16) u16 Bs[2][128 * 32];
    const bool isPos = (blockIdx.y >= 64);
    if (isPos && blockIdx.x >= 4) return;
    const u16* A = isPos ? Ap : Aq;
    const u16* W = isPos ? Wp : Wq;
    const int K = 512;
    const int tid  = threadIdx.x;
    const int wv   = tid >> 6;
    const int lane = tid & 63;
    const int wm   = wv >> 2, wn = wv & 3;
    const int m0 = blockIdx.x * 128;
    const int n0 = (isPos ? ((int)blockIdx.y - 64) : (int)blockIdx.y) * 128;

    const int sc_ = tid & 3;
    const int sr_ = tid >> 2;
    const u16* gA = A + (size_t)(n0 + sr_) * K + sc_ * 8;
    const u16* gB = W + (size_t)(m0 + sr_) * K + sc_ * 8;
    const int ls = sr_ * 32 + sc_ * 8;

    f32x4 acc[4][2];
#pragma unroll
    for (int i = 0; i < 4; ++i)
#pragma unroll
        for (int j = 0; j < 2; ++j) acc[i][j] = (f32x4)0.f;

    const int frow = (lane & 15);
    const int fk   = (lane >> 4) * 8;

    uint4 ra = *(const uint4*)(gA);
    uint4 rb = *(const uint4*)(gB);
    *(uint4*)&As[0][ls] = ra;
    *(uint4*)&Bs[0][ls] = rb;
    __syncthreads();

    int buf = 0;
    for (int k0 = 0; k0 < K; k0 += 32) {
        const bool last = (k0 + 32 >= K);
        if (!last) {
            ra = *(const uint4*)(gA + k0 + 32);
            rb = *(const uint4*)(gB + k0 + 32);
        }
        bf16x8 af[4], bf[2];
#pragma unroll
        for (int i = 0; i < 4; ++i)
            af[i] = *(const bf16x8*)&As[buf][(wm * 64 + i * 16 + frow) * 32 + fk];
#pragma unroll
        for (int j = 0; j < 2; ++j)
            bf[j] = *(const bf16x8*)&Bs[buf][(wn * 32 + j * 16 + frow) * 32 + fk];
#pragma unroll
        for (int i = 0; i < 4; ++i)
#pragma unroll
            for (int j = 0; j < 2; ++j)
                acc[i][j] = __builtin_amdgcn_mfma_f32_16x16x32_bf16(af[i], bf[j], acc[i][j], 0, 0, 0);
        if (!last) {
            const int nb = buf ^ 1;
            *(uint4*)&As[nb][ls] = ra;
            *(uint4*)&Bs[nb][ls] = rb;
            __syncthreads();
            buf = nb;
        }
    }

    const int quad = lane >> 4;
#pragma unroll
    for (int i = 0; i < 4; ++i) {
        const int rowb = n0 + wm * 64 + i * 16 + quad * 4;
#pragma unroll
        for (int j = 0; j < 2; ++j) {
            const int col = m0 + wn * 32 + j * 16 + (lane & 15);
            if (!isPos) {
                const float bv = bias[col];
                const int c = col & 511, h = c >> 6, d = c & 63;
#pragma unroll
                for (int r = 0; r < 4; ++r) {
                    const int row = rowb + r;
                    const float v = clampd_(acc[i][j][r] + bv);
                    const int t = row >> 4, b = row & 15;
                    const size_t dst = ((size_t)(b * 8 + h) * 512 + t) * 64 + d;
                    if (col < 512) {
                        o_qu[dst] = f2bf_(v * 0.125f + ub[c]);
                        o_qv[dst] = f2bf_(v * 0.125f + vb[c]);
                    } else if (col < 1024) {
                        o_k[dst] = f2bf_(v);
                    } else {
                        o_v[dst] = f2bf_(v);
                    }
                }
            } else {
                const int h = col >> 6, d = col & 63;
#pragma unroll
                for (int r = 0; r < 4; ++r)
                    o_p[(size_t)h * 65536 + (size_t)(rowb + r) * 64 + d] = f2bf_(acc[i][j][r]);
            }
        }
    }
}

// ---------------------------------------------------------------------------
// pw1 GEMM with fused GLU (R6-proven). Writes a*sigmoid(g) bf16 to glu_o.
// ---------------------------------------------------------------------------
__global__ __launch_bounds__(512) void gemm_glu_k(
    const u16* __restrict__ A, const u16* __restrict__ W,
    const float* __restrict__ bias, u16* __restrict__ out)
{
    __shared__ __align__(16) u16 As[2][128 * 32];
    __shared__ __align__(16) u16 Ba[2][128 * 32];
    __shared__ __align__(16) u16 Bg[2][128 * 32];
    const int tid  = threadIdx.x;
    const int wv   = tid >> 6;
    const int lane = tid & 63;
    const int wm   = wv >> 2, wn = wv & 3;
    const int m0 = blockIdx.x * 128;
    const int n0 = blockIdx.y * 128;
    const int K = 512;

    const int sc_ = tid & 3;
    const int sr_ = tid >> 2;
    const u16* gA  = A + (size_t)(n0 + sr_) * K + sc_ * 8;
    const u16* gBa = W + (size_t)(m0 + sr_) * K + sc_ * 8;
    const u16* gBg = W + (size_t)(m0 + 512 + sr_) * K + sc_ * 8;
    const int ls = sr_ * 32 + sc_ * 8;

    f32x4 aa[4][2], ag[4][2];
#pragma unroll
    for (int i = 0; i < 4; ++i)
#pragma unroll
        for (int j = 0; j < 2; ++j) { aa[i][j] = (f32x4)0.f; ag[i][j] = (f32x4)0.f; }

    const int frow = (lane & 15);
    const int fk   = (lane >> 4) * 8;

    uint4 ra  = *(const uint4*)(gA);
    uint4 rba = *(const uint4*)(gBa);
    uint4 rbg = *(const uint4*)(gBg);
    *(uint4*)&As[0][ls] = ra;
    *(uint4*)&Ba[0][ls] = rba;
    *(uint4*)&Bg[0][ls] = rbg;
    __syncthreads();

    int buf = 0;
    for (int k0 = 0; k0 < K; k0 += 32) {
        const bool last = (k0 + 32 >= K);
        if (!last) {
            ra  = *(const uint4*)(gA + k0 + 32);
            rba = *(const uint4*)(gBa + k0 + 32);
            rbg = *(const uint4*)(gBg + k0 + 32);
        }
        bf16x8 af[4], bfa[2], bfg[2];
#pragma unroll
        for (int i = 0; i < 4; ++i)
            af[i] = *(const bf16x8*)&As[buf][(wm * 64 + i * 16 + frow) * 32 + fk];
#pragma unroll
        for (int j = 0; j < 2; ++j) {
            bfa[j] = *(const bf16x8*)&Ba[buf][(wn * 32 + j * 16 + frow) * 32 + fk];
            bfg[j] = *(const bf16x8*)&Bg[buf][(wn * 32 + j * 16 + frow) * 32 + fk];
        }
#pragma unroll
        for (int i = 0; i < 4; ++i)
#pragma unroll
            for (int j = 0; j < 2; ++j) {
                aa[i][j] = __builtin_amdgcn_mfma_f32_16x16x32_bf16(af[i], bfa[j], aa[i][j], 0, 0, 0);
                ag[i][j] = __builtin_amdgcn_mfma_f32_16x16x32_bf16(af[i], bfg[j], ag[i][j], 0, 0, 0);
            }
        if (!last) {
            const int nb = buf ^ 1;
            *(uint4*)&As[nb][ls] = ra;
            *(uint4*)&Ba[nb][ls] = rba;
            *(uint4*)&Bg[nb][ls] = rbg;
            __syncthreads();
            buf = nb;
        }
    }

    const int quad = lane >> 4;
#pragma unroll
    for (int i = 0; i < 4; ++i) {
        const int row = n0 + wm * 64 + i * 16 + quad * 4;
#pragma unroll
        for (int j = 0; j < 2; ++j) {
            const int col = m0 + wn * 32 + j * 16 + (lane & 15);
            const float ba = bias[col];
            const float bg = bias[col + 512];
#pragma unroll
            for (int r = 0; r < 4; ++r) {
                const float a = clampd_(aa[i][j][r] + ba);
                const float g = clampd_(ag[i][j][r] + bg);
                out[(size_t)(row + r) * 512 + col] = f2bf_(a * sigmoidf_(g));
            }
        }
    }
}

// ---------------------------------------------------------------------------
// f32 -> bf16 converters / prep (merged single launch, R6-proven)
// ---------------------------------------------------------------------------
__device__ __forceinline__ void store_bf4_(u16* out, float4 v) {
    const unsigned lo = (unsigned)f2bf_(v.x) | ((unsigned)f2bf_(v.y) << 16);
    const unsigned hi = (unsigned)f2bf_(v.z) | ((unsigned)f2bf_(v.w) << 16);
    *(uint2*)out = make_uint2(lo, hi);
}

struct WPtrs { const float* p[9]; };
__global__ __launch_bounds__(256) void prep_k(
    WPtrs wp, const float* __restrict__ src, const float* __restrict__ pos,
    const float* __restrict__ cdw,
    u16* __restrict__ wb, u16* __restrict__ src_b, u16* __restrict__ pos_b,
    float* __restrict__ wTd)
{
    const int e = (blockIdx.x * 256 + threadIdx.x) * 4;
    if (e < 6291456) {
        static const int off[10] = {0, 1048576, 2097152, 3145728, 4194304,
                                    4980736, 5242880, 5505024, 6029312, 6291456};
        int r = 0;
#pragma unroll
        for (int k = 1; k < 9; ++k) r += (e >= off[k]);
        store_bf4_(wb + e, *(const float4*)(wp.p[r] + (e - off[r])));
    } else if (e < 6291456 + 4194304) {
        const int e2 = e - 6291456;
        store_bf4_(src_b + e2, *(const float4*)(src + e2));
    } else if (e < 6291456 + 4194304 + 524288) {
        const int e2 = e - (6291456 + 4194304);
        float4 v = make_float4(0.f, 0.f, 0.f, 0.f);
        if (e2 < 1023 * 512) v = *(const float4*)(pos + e2);
        store_bf4_(pos_b + e2, v);
    } else {
        const int e2 = e - (6291456 + 4194304 + 524288);
        if (e2 < 15872) {
#pragma unroll
            for (int q = 0; q < 4; ++q) {
                const int i2 = e2 + q;
                const int j = i2 >> 9, c = i2 & 511;
                wTd[i2] = cdw[c * 31 + j];
            }
        }
    }
}

// v_b[gbh][s][d] -> vt_b[gbh][d][s]  (64x64 LDS tile transpose; R7 lesson:
// this is cheaper than scattering the transpose into the GEMM epilogue)
__global__ __launch_bounds__(256) void vt_k(const u16* __restrict__ in, u16* __restrict__ out)
{
    __shared__ u16 tile[64][65];
    const int s0 = blockIdx.x * 64;
    const int gbh = blockIdx.y;
    const u16* src = in + (size_t)gbh * 512 * 64;
    u16* dst = out + (size_t)gbh * 64 * 512;
    const int tid = threadIdx.x;
#pragma unroll
    for (int q = 0; q < 2; ++q) {
        const int lin = tid * 2 + q;             // 0..511 uint4s
        const int srow = lin >> 3, c8 = (lin & 7) * 8;
        const uint4 v = *(const uint4*)(src + (size_t)(s0 + srow) * 64 + c8);
        const u16* vu = (const u16*)&v;
#pragma unroll
        for (int e = 0; e < 8; ++e) tile[srow][c8 + e] = vu[e];
    }
    __syncthreads();
#pragma unroll
    for (int q = 0; q < 2; ++q) {
        const int lin = tid * 2 + q;
        const int d = lin >> 3, sc8 = (lin & 7) * 8;
        u16 o[8];
#pragma unroll
        for (int e = 0; e < 8; ++e) o[e] = tile[sc8 + e][d];
        *(uint4*)(dst + (size_t)d * 512 + s0 + sc8) = *(uint4*)o;
    }
}

// ---------------------------------------------------------------------------
// Fused flash rel-pos attention (R6-proven body, dynamic s-loop).
// Plateau note: 6 structural attacks (split-S x2, manual prefetch, bpermute
// gather, full unroll) all regressed or were neutral — this body is the
// proven local optimum (~104 us, latency-bound, register-capped occupancy).
// R11: defer-max (T13, THR=8) — skip the O/Lacc rescale when all rows' tile
// max grew by <= 8 (wave-uniform via __any; rescaling is always correct, so
// only the all-quads-within-threshold case skips). P bounded by e^8, fine in
// bf16; Lacc f32. Shortens the per-tile serial softmax chain.
// grid (t64-tiles=8, gbh=128), 4 waves/block, each wave owns 16 t-rows.
// Wave-private LDS slices, no barriers; padded strides (88/72 u16) keep LDS
// ops <= 2-way. l tracked via ones-column MFMA.
// ---------------------------------------------------------------------------
#define C2S 88   // padded C2 row stride (u16)
#define PS  72   // padded P row stride (u16)
__global__ __launch_bounds__(256, 4) void flash_attn(
    const u16* __restrict__ qu_b, const u16* __restrict__ qv_b,
    const u16* __restrict__ k_b, const u16* __restrict__ vt_b,
    const u16* __restrict__ p_b, u16* __restrict__ aob)
{
    __shared__ __align__(16) u16 C2ld[4][16 * C2S];
    __shared__ __align__(16) u16 Pld[4][16 * PS];
    const int tid = threadIdx.x;
    const int wv = tid >> 6;
    const int lane = tid & 63;
    const int quad = lane >> 4, ln = lane & 15;
    const int gbh = blockIdx.y;
    const int b = gbh >> 3, h = gbh & 7;
    const int t0 = blockIdx.x * 64 + wv * 16;     // wave's first t-row

    const u16* qu = qu_b + (size_t)gbh * 512 * 64;
    const u16* qv = qv_b + (size_t)gbh * 512 * 64;
    const u16* kb = k_b + (size_t)gbh * 512 * 64;
    const u16* vt = vt_b + (size_t)gbh * 64 * 512;
    const u16* pp = p_b + (size_t)h * 1024 * 64;

    // A-fragments (row = t0+ln, k = ks*32 + quad*8), constant across s-tiles
    bf16x8 aqu[2], aqv[2];
#pragma unroll
    for (int ks = 0; ks < 2; ++ks) {
        aqu[ks] = *(const bf16x8*)(qu + (size_t)(t0 + ln) * 64 + ks * 32 + quad * 8);
        aqv[ks] = *(const bf16x8*)(qv + (size_t)(t0 + ln) * 64 + ks * 32 + quad * 8);
    }

    const short ob = (short)0x3F80;               // bf16 1.0
    const bf16x8 vone = {ob, ob, ob, ob, ob, ob, ob, ob};

    f32x4 O[4];
#pragma unroll
    for (int nb = 0; nb < 4; ++nb) O[nb] = (f32x4)0.f;
    f32x4 Lacc = (f32x4)0.f;                      // per-row softmax denom
    float m[4];
#pragma unroll
    for (int r = 0; r < 4; ++r) m[r] = -1e30f;

    u16* c2w = &C2ld[wv][0];
    u16* pw  = &Pld[wv][0];

    for (int s0 = 0; s0 < 512; s0 += 64) {
        // ---- S = qu . k^T (16 x 64) ----
        f32x4 S[4];
#pragma unroll
        for (int nb = 0; nb < 4; ++nb) S[nb] = (f32x4)0.f;
        __builtin_amdgcn_s_setprio(1);
#pragma unroll
        for (int ks = 0; ks < 2; ++ks)
#pragma unroll
            for (int nb = 0; nb < 4; ++nb) {
                const bf16x8 bk = *(const bf16x8*)(kb + (size_t)(s0 + nb * 16 + ln) * 64 + ks * 32 + quad * 8);
                S[nb] = __builtin_amdgcn_mfma_f32_16x16x32_bf16(aqu[ks], bk, S[nb], 0, 0, 0);
            }
        __builtin_amdgcn_s_setprio(0);
        // ---- C2 window = qv . p[jlo..jlo+80)^T (16 x 80) ----
        const int jlo = 496 - t0 + s0;
        f32x4 C2[5];
#pragma unroll
        for (int nb = 0; nb < 5; ++nb) C2[nb] = (f32x4)0.f;
        __builtin_amdgcn_s_setprio(1);
#pragma unroll
        for (int ks = 0; ks < 2; ++ks)
#pragma unroll
            for (int nb = 0; nb < 5; ++nb) {
                const bf16x8 bp = *(const bf16x8*)(pp + (size_t)(jlo + nb * 16 + ln) * 64 + ks * 32 + quad * 8);
                C2[nb] = __builtin_amdgcn_mfma_f32_16x16x32_bf16(aqv[ks], bp, C2[nb], 0, 0, 0);
            }
        __builtin_amdgcn_s_setprio(0);
#pragma unroll
        for (int nb = 0; nb < 5; ++nb)
#pragma unroll
            for (int r = 0; r < 4; ++r)
                c2w[(quad * 4 + r) * C2S + nb * 16 + ln] = f2bf_(C2[nb][r]);

        // ---- S += shifted bd; clamp; row-max ----
        float sv[4][4];
        float rmax[4] = {-1e30f, -1e30f, -1e30f, -1e30f};
#pragma unroll
        for (int nb = 0; nb < 4; ++nb)
#pragma unroll
            for (int r = 0; r < 4; ++r) {
                const int tloc = quad * 4 + r;
                const int col = nb * 16 + ln + 15 - tloc;   // [0,78]
                const float bd = bf2f_(c2w[tloc * C2S + col]);
                const float s = clampd_(S[nb][r] + bd);
                sv[nb][r] = s;
                rmax[r] = fmaxf(rmax[r], s);
            }
#pragma unroll
        for (int off = 1; off < 16; off <<= 1)
#pragma unroll
            for (int r = 0; r < 4; ++r)
                rmax[r] = fmaxf(rmax[r], __shfl_xor(rmax[r], off, 64));

        // ---- online softmax update with defer-max (T13, THR=8) ----
        bool need = false;
#pragma unroll
        for (int r = 0; r < 4; ++r) need = need || (rmax[r] > m[r] + 8.f);
        if (__any((int)need)) {
            float alpha[4];
#pragma unroll
            for (int r = 0; r < 4; ++r) {
                const float mn = fmaxf(m[r], rmax[r]);
                alpha[r] = __expf(m[r] - mn);
                m[r] = mn;
            }
#pragma unroll
            for (int nb = 0; nb < 4; ++nb)
#pragma unroll
                for (int r = 0; r < 4; ++r) O[nb][r] *= alpha[r];
#pragma unroll
            for (int r = 0; r < 4; ++r) Lacc[r] *= alpha[r];
        }
#pragma unroll
        for (int nb = 0; nb < 4; ++nb)
#pragma unroll
            for (int r = 0; r < 4; ++r) {
                const float p = __expf(sv[nb][r] - m[r]);
                pw[(quad * 4 + r) * PS + nb * 16 + ln] = f2bf_(p);
            }

        // ---- O += P . V ; Lacc += P . 1  (P A-frags from LDS) ----
        __builtin_amdgcn_s_setprio(1);
#pragma unroll
        for (int ks = 0; ks < 2; ++ks) {
            const bf16x8 ap = *(const bf16x8*)&pw[ln * PS + ks * 32 + quad * 8];
#pragma unroll
            for (int nb = 0; nb < 4; ++nb) {
                const bf16x8 bv = *(const bf16x8*)(vt + (size_t)(nb * 16 + ln) * 512 + s0 + ks * 32 + quad * 8);
                O[nb] = __builtin_amdgcn_mfma_f32_16x16x32_bf16(ap, bv, O[nb], 0, 0, 0);
            }
            Lacc = __builtin_amdgcn_mfma_f32_16x16x32_bf16(ap, vone, Lacc, 0, 0, 0);
        }
        __builtin_amdgcn_s_setprio(0);
    }

    // ---- epilogue: normalize and write ao (t,b,c) ----
    float inv[4];
#pragma unroll
    for (int r = 0; r < 4; ++r) inv[r] = 1.f / Lacc[r];
#pragma unroll
    for (int nb = 0; nb < 4; ++nb)
#pragma unroll
        for (int r = 0; r < 4; ++r) {
            const int t = t0 + quad * 4 + r;
            const int d = nb * 16 + ln;
            aob[((size_t)t * B_SZ + b) * 512 + h * 64 + d] = f2bf_(O[nb][r] * inv[r]);
        }
}

// ---------------------------------------------------------------------------
// Conv-module pieces (bf16 chain)
// ---------------------------------------------------------------------------
__global__ __launch_bounds__(256) void dwconv_k(
    const u16* __restrict__ g, const float* __restrict__ wT,
    const float* __restrict__ bb, u16* __restrict__ out)
{
    const int idx = blockIdx.x * 256 + threadIdx.x;
    const int c = idx & 511;
    const int b = (idx >> 9) & 15;
    const int t0 = (idx >> 13) * 8;
    float wr[31];
#pragma unroll
    for (int j = 0; j < 31; ++j) wr[j] = wT[j * 512 + c];
    float win[38];
#pragma unroll
    for (int jj = 0; jj < 38; ++jj) {
        const int tt = t0 - 30 + jj;
        win[jj] = (tt >= 0) ? bf2f_(g[((size_t)tt * B_SZ + b) * 512 + c]) : 0.f;
    }
    const float bias = bb[c];
#pragma unroll
    for (int o = 0; o < 8; ++o) {
        float acc = bias;
#pragma unroll
        for (int j = 0; j < 31; ++j) acc += win[o + j] * wr[j];
        out[((size_t)(t0 + o) * B_SZ + b) * 512 + c] = f2bf_(dswishf_(acc));
    }
}

__global__ __launch_bounds__(256) void norm_k(float* __restrict__ x)
{
    const int row = blockIdx.x * 4 + (threadIdx.x >> 6);
    const int lane = threadIdx.x & 63;
    float* r = x + (size_t)row * 512;
    float v[8];
    float ss = 0.f;
#pragma unroll
    for (int j = 0; j < 8; ++j) { v[j] = r[lane + (j << 6)]; ss += v[j] * v[j]; }
#pragma unroll
    for (int o = 32; o > 0; o >>= 1) ss += __shfl_xor(ss, o, 64);
    const float scale = rsqrtf(ss * (1.f / 512.f) + EPS_BN);
#pragma unroll
    for (int j = 0; j < 8; ++j) r[lane + (j << 6)] = v[j] * scale;
}

// ---------------------------------------------------------------------------
extern "C" void kernel_launch(void* const* d_in, const int* in_sizes, int n_in,
                              void* d_out, int out_size, void* d_ws, size_t ws_size,
                              hipStream_t stream)
{
    const float* src   = (const float*)d_in[0];
    const float* pos   = (const float*)d_in[1];
    const float* fm_w1 = (const float*)d_in[2];
    const float* fm_b1 = (const float*)d_in[3];
    const float* fm_w2 = (const float*)d_in[4];
    const float* fm_b2 = (const float*)d_in[5];
    const float* f_w1  = (const float*)d_in[6];
    const float* f_b1  = (const float*)d_in[7];
    const float* f_w2  = (const float*)d_in[8];
    const float* f_b2  = (const float*)d_in[9];
    const float* ipw   = (const float*)d_in[10];
    const float* ipb   = (const float*)d_in[11];
    const float* opw   = (const float*)d_in[12];
    const float* opb   = (const float*)d_in[13];
    const float* lpw   = (const float*)d_in[14];
    const float* pbu   = (const float*)d_in[15];
    const float* pbv   = (const float*)d_in[16];
    const float* cpw1  = (const float*)d_in[17];
    const float* cpb1  = (const float*)d_in[18];
    const float* cdw   = (const float*)d_in[19];
    const float* cdb   = (const float*)d_in[20];
    const float* cpw2  = (const float*)d_in[21];
    const float* cpb2  = (const float*)d_in[22];

    float* x = (float*)d_out;              // running activation (8192 x 512) f32

    // ---- workspace layout ----
    char* base = (char*)d_ws;
    u16*   wb    = (u16*)base;   base += 6291456ull * 2;   // 9 weights bf16
    u16*   src_b = (u16*)base;   base += 4194304ull * 2;
    u16*   pos_b = (u16*)base;   base += 524288ull * 2;    // 1024x512 padded
    u16*   xb    = (u16*)base;   base += 4194304ull * 2;
    u16*   hb    = (u16*)base;   base += 16777216ull * 2;  // FFN hidden / dwconv out
    u16*   aob   = (u16*)base;   base += 4194304ull * 2;
    u16*   qu_b  = (u16*)base;   base += 4194304ull * 2;
    u16*   qv_b  = (u16*)base;   base += 4194304ull * 2;
    u16*   k_b   = (u16*)base;   base += 4194304ull * 2;
    u16*   v_b   = (u16*)base;   base += 4194304ull * 2;
    u16*   vt_b  = (u16*)base;   base += 4194304ull * 2;
    u16*   p_b   = (u16*)base;   base += 524288ull * 2;    // [8][1024][64]
    float* wTd   = (float*)base; base += 15872ull * 4;
    u16*   glu_o = (u16*)base;   base += 4194304ull * 2;   // conv glu out (8192x512)

    u16* fm_w1b = wb;
    u16* fm_w2b = wb + 1048576;
    u16* f_w1b  = wb + 2097152;
    u16* f_w2b  = wb + 3145728;
    u16* ipwb   = wb + 4194304;
    u16* opwb   = wb + 4980736;
    u16* lpwb   = wb + 5242880;
    u16* cpw1b  = wb + 5505024;
    u16* cpw2b  = wb + 6029312;

    const dim3 blk(256);
    const dim3 blkg(512);

    // 0) all f32 -> bf16 conversions + dw weight transpose, single launch
    WPtrs wp = {{fm_w1, fm_w2, f_w1, f_w2, ipw, opw, lpw, cpw1, cpw2}};
    prep_k<<<dim3(10768), blk, 0, stream>>>(wp, src, pos, cdw, wb, src_b, pos_b, wTd);

    // 1) macaron FFN: x = src + W2 @ dswish(W1 @ src)
    gemm_mfma<1, false, false, true><<<dim3(16, 64), blkg, 0, stream>>>(
        src_b, fm_w1b, fm_b1, nullptr, nullptr, hb, NROWS, 512, DFF_);
    gemm_mfma<0, true, true, true><<<dim3(4, 64), blkg, 0, stream>>>(
        hb, fm_w2b, fm_b2, src, x, xb, NROWS, DFF_, 512);

    // 2) qkv + pos projections in ONE launch (pos fills CU slack); V transpose
    gemm_qkvpos<<<dim3(12, 72), blkg, 0, stream>>>(
        xb, ipwb, pos_b, lpwb, ipb, pbu, pbv, qu_b, qv_b, k_b, v_b, p_b);
    vt_k<<<dim3(8, 128), blk, 0, stream>>>(v_b, vt_b);

    // 3) fused flash rel-pos attention (single launch, full batch)
    flash_attn<<<dim3(8, 128), blk, 0, stream>>>(qu_b, qv_b, k_b, vt_b, p_b, aob);

    // 4) out projection (residual into x)
    gemm_mfma<0, true, true, true><<<dim3(4, 64), blkg, 0, stream>>>(
        aob, opwb, opb, x, x, xb, NROWS, 512, 512);

    // 5) conv module: pw1+GLU fused -> dwconv(+dswish) -> pw2 (residual)
    gemm_glu_k<<<dim3(4, 64), blkg, 0, stream>>>(xb, cpw1b, cpb1, glu_o);
    dwconv_k<<<dim3(2048), blk, 0, stream>>>(glu_o, wTd, cdb, hb);
    gemm_mfma<0, true, true, true><<<dim3(4, 64), blkg, 0, stream>>>(
        hb, cpw2b, cpb2, x, x, xb, NROWS, 512, 512);

    // 6) second FFN
    gemm_mfma<1, false, false, true><<<dim3(16, 64), blkg, 0, stream>>>(
        xb, f_w1b, f_b1, nullptr, nullptr, hb, NROWS, 512, DFF_);
    gemm_mfma<0, true, true, false><<<dim3(4, 64), blkg, 0, stream>>>(
        hb, f_w2b, f_b2, x, x, nullptr, NROWS, DFF_, 512);

    // 7) BasicNorm
    norm_k<<<dim3(NROWS / 4), blk, 0, stream>>>(x);
}

// Round 12
// 471.426 us; speedup vs baseline: 1.0784x; 1.0183x over previous
//
#include <hip/hip_runtime.h>
#include <math.h>

// Problem constants (ConformerEncoderLayer, T=512 B=16 C=512 H=8 d=64 DFF=2048 K=31)
#define T_SEQ 512
#define B_SZ  16
#define C_DIM 512
#define NH    8
#define HD    64
#define DFF_  2048
#define NROWS (T_SEQ * B_SZ)   // 8192 rows of (t*B+b)
#define EPS_BN 1.2840254166877414f  // exp(0.25)

typedef unsigned short u16;
typedef __attribute__((ext_vector_type(8))) short bf16x8;
typedef __attribute__((ext_vector_type(4))) float f32x4;

__device__ __forceinline__ float sigmoidf_(float x) { return 1.f / (1.f + __expf(-x)); }
__device__ __forceinline__ float dswishf_(float x)  { return x * sigmoidf_(x - 1.f); }
__device__ __forceinline__ float clampd_(float x)   { return fminf(fmaxf(x, -1e4f), 1e4f); }
__device__ __forceinline__ u16 f2bf_(float x) {
    unsigned u = __float_as_uint(x);
    return (u16)((u + 0x7fffu + ((u >> 16) & 1u)) >> 16);
}
__device__ __forceinline__ float bf2f_(u16 u) {
    return __uint_as_float(((unsigned)u) << 16);
}

// ---------------------------------------------------------------------------
// bf16 MFMA GEMM, double-buffered LDS, reg-staged (R0-proven staging).
// R3-proven: 512-thread / 8-wave blocks on a 128x128 tile (wave = 64x32 out,
// acc[4][2]). R9 lesson: 64x64 tiles (more TLP, 2x panel traffic) REGRESS.
// N,M mult of 128; K mult of 32.
// ---------------------------------------------------------------------------
template <int ACT, bool HAS_RES, bool O32, bool O16>
__global__ __launch_bounds__(512) void gemm_mfma(
    const u16* __restrict__ A, const u16* __restrict__ W,
    const float* __restrict__ bias, const float* __restrict__ res,
    float* __restrict__ out32, u16* __restrict__ out16, int N, int K, int M)
{
    __shared__ __align__(16) u16 As[2][128 * 32];
    __shared__ __align__(16) u16 Bs[2][128 * 32];
    const int tid  = threadIdx.x;
    const int wv   = tid >> 6;
    const int lane = tid & 63;
    const int wm   = wv >> 2, wn = wv & 3;   // 2 x 4 waves, 64x32 out each
    const int m0 = blockIdx.x * 128;
    const int n0 = blockIdx.y * 128;

    const int sc_ = tid & 3;
    const int sr_ = tid >> 2;                // 0..127
    const u16* gA = A + (size_t)(n0 + sr_) * K + sc_ * 8;
    const u16* gB = W + (size_t)(m0 + sr_) * K + sc_ * 8;
    const int ls = sr_ * 32 + sc_ * 8;

    f32x4 acc[4][2];
#pragma unroll
    for (int i = 0; i < 4; ++i)
#pragma unroll
        for (int j = 0; j < 2; ++j) acc[i][j] = (f32x4)0.f;

    const int frow = (lane & 15);
    const int fk   = (lane >> 4) * 8;

    uint4 ra = *(const uint4*)(gA);
    uint4 rb = *(const uint4*)(gB);
    *(uint4*)&As[0][ls] = ra;
    *(uint4*)&Bs[0][ls] = rb;
    __syncthreads();

    int buf = 0;
    for (int k0 = 0; k0 < K; k0 += 32) {
        const bool last = (k0 + 32 >= K);
        if (!last) {
            ra = *(const uint4*)(gA + k0 + 32);
            rb = *(const uint4*)(gB + k0 + 32);
        }
        bf16x8 af[4], bf[2];
#pragma unroll
        for (int i = 0; i < 4; ++i)
            af[i] = *(const bf16x8*)&As[buf][(wm * 64 + i * 16 + frow) * 32 + fk];
#pragma unroll
        for (int j = 0; j < 2; ++j)
            bf[j] = *(const bf16x8*)&Bs[buf][(wn * 32 + j * 16 + frow) * 32 + fk];
#pragma unroll
        for (int i = 0; i < 4; ++i)
#pragma unroll
            for (int j = 0; j < 2; ++j)
                acc[i][j] = __builtin_amdgcn_mfma_f32_16x16x32_bf16(af[i], bf[j], acc[i][j], 0, 0, 0);
        if (!last) {
            const int nb = buf ^ 1;
            *(uint4*)&As[nb][ls] = ra;
            *(uint4*)&Bs[nb][ls] = rb;
            __syncthreads();
            buf = nb;
        }
    }

    const int quad = lane >> 4;
#pragma unroll
    for (int i = 0; i < 4; ++i) {
        const int row = n0 + wm * 64 + i * 16 + quad * 4;
#pragma unroll
        for (int j = 0; j < 2; ++j) {
            const int col = m0 + wn * 32 + j * 16 + (lane & 15);
            const float bv = bias ? bias[col] : 0.f;
#pragma unroll
            for (int r = 0; r < 4; ++r) {
                float v = acc[i][j][r] + bv;
                if (ACT == 1) v = dswishf_(v);
                if (HAS_RES) v += res[(size_t)(row + r) * M + col];
                v = clampd_(v);
                if (O32) out32[(size_t)(row + r) * M + col] = v;
                if (O16) out16[(size_t)(row + r) * M + col] = f2bf_(v);
            }
        }
    }
}

// ---------------------------------------------------------------------------
// R12: K=2048 variant with a 4-deep sub-tile ring ("BK=64" as two sequential
// BK=32 sub-tiles; identical linear per-sub-tile LDS layout so the proven
// linear ds_write pattern is unchanged). One barrier per 64-K step: barrier
// count halves (64 -> 32) and 4 global loads issue back-to-back (deeper MLP)
// for the 1-block/CU ffm2/ffn2 dispatches that can't get more TLP. LDS 64KB
// (grid 256 = 1 block/CU anyway). Correctness: reads of bufs ph^2 precede
// the same barrier that precedes their overwrite (pair-wise dbuf argument).
// ---------------------------------------------------------------------------
template <int ACT, bool HAS_RES, bool O32, bool O16>
__global__ __launch_bounds__(512) void gemm_k64(
    const u16* __restrict__ A, const u16* __restrict__ W,
    const float* __restrict__ bias, const float* __restrict__ res,
    float* __restrict__ out32, u16* __restrict__ out16, int N, int K, int M)
{
    __shared__ __align__(16) u16 As[4][128 * 32];
    __shared__ __align__(16) u16 Bs[4][128 * 32];
    const int tid  = threadIdx.x;
    const int wv   = tid >> 6;
    const int lane = tid & 63;
    const int wm   = wv >> 2, wn = wv & 3;
    const int m0 = blockIdx.x * 128;
    const int n0 = blockIdx.y * 128;

    const int sc_ = tid & 3;
    const int sr_ = tid >> 2;
    const u16* gA = A + (size_t)(n0 + sr_) * K + sc_ * 8;
    const u16* gB = W + (size_t)(m0 + sr_) * K + sc_ * 8;
    const int ls = sr_ * 32 + sc_ * 8;

    f32x4 acc[4][2];
#pragma unroll
    for (int i = 0; i < 4; ++i)
#pragma unroll
        for (int j = 0; j < 2; ++j) acc[i][j] = (f32x4)0.f;

    const int frow = (lane & 15);
    const int fk   = (lane >> 4) * 8;

    uint4 ra0 = *(const uint4*)(gA);
    uint4 ra1 = *(const uint4*)(gA + 32);
    uint4 rb0 = *(const uint4*)(gB);
    uint4 rb1 = *(const uint4*)(gB + 32);
    *(uint4*)&As[0][ls] = ra0; *(uint4*)&As[1][ls] = ra1;
    *(uint4*)&Bs[0][ls] = rb0; *(uint4*)&Bs[1][ls] = rb1;
    __syncthreads();

    int ph = 0;   // base buffer of current pair (0 or 2)
    for (int k0 = 0; k0 < K; k0 += 64) {
        const bool last = (k0 + 64 >= K);
        if (!last) {
            ra0 = *(const uint4*)(gA + k0 + 64);
            ra1 = *(const uint4*)(gA + k0 + 96);
            rb0 = *(const uint4*)(gB + k0 + 64);
            rb1 = *(const uint4*)(gB + k0 + 96);
        }
#pragma unroll
        for (int kk = 0; kk < 2; ++kk) {
            bf16x8 af[4], bf[2];
#pragma unroll
            for (int i = 0; i < 4; ++i)
                af[i] = *(const bf16x8*)&As[ph + kk][(wm * 64 + i * 16 + frow) * 32 + fk];
#pragma unroll
            for (int j = 0; j < 2; ++j)
                bf[j] = *(const bf16x8*)&Bs[ph + kk][(wn * 32 + j * 16 + frow) * 32 + fk];
#pragma unroll
            for (int i = 0; i < 4; ++i)
#pragma unroll
                for (int j = 0; j < 2; ++j)
                    acc[i][j] = __builtin_amdgcn_mfma_f32_16x16x32_bf16(af[i], bf[j], acc[i][j], 0, 0, 0);
        }
        if (!last) {
            const int nb = ph ^ 2;
            *(uint4*)&As[nb][ls] = ra0; *(uint4*)&As[nb + 1][ls] = ra1;
            *(uint4*)&Bs[nb][ls] = rb0; *(uint4*)&Bs[nb + 1][ls] = rb1;
            __syncthreads();
            ph = nb;
        }
    }

    const int quad = lane >> 4;
#pragma unroll
    for (int i = 0; i < 4; ++i) {
        const int row = n0 + wm * 64 + i * 16 + quad * 4;
#pragma unroll
        for (int j = 0; j < 2; ++j) {
            const int col = m0 + wn * 32 + j * 16 + (lane & 15);
            const float bv = bias ? bias[col] : 0.f;
#pragma unroll
            for (int r = 0; r < 4; ++r) {
                float v = acc[i][j][r] + bv;
                if (ACT == 1) v = dswishf_(v);
                if (HAS_RES) v += res[(size_t)(row + r) * M + col];
                v = clampd_(v);
                if (O32) out32[(size_t)(row + r) * M + col] = v;
                if (O16) out16[(size_t)(row + r) * M + col] = f2bf_(v);
            }
        }
    }
}

// ---------------------------------------------------------------------------
// Merged qkv + pos projection GEMM (both K=512, same dbuf body; R10).
// Grid (12, 72): y<64 -> qkv block; y>=64 -> pos block (x>=4 early-exits).
// EPI qkv: writes qu/qv/k/v bf16 in [b*8+h][t][d], q*0.125 + u/v bias.
//   (R7 lesson: V must NOT be written transposed here.)
// EPI pos: writes p_b[h][j][d] bf16.
// ---------------------------------------------------------------------------
__global__ __launch_bounds__(512) void gemm_qkvpos(
    const u16* __restrict__ Aq, const u16* __restrict__ Wq,
    const u16* __restrict__ Ap, const u16* __restrict__ Wp,
    const float* __restrict__ bias, const float* __restrict__ ub, const float* __restrict__ vb,
    u16* __restrict__ o_qu, u16* __restrict__ o_qv, u16* __restrict__ o_k,
    u16* __restrict__ o_v, u16* __restrict__ o_p)
{
    __shared__ __align__(16) u16 As[2][128 * 32];
    __shared__ __align__(16) u16 Bs[2][128 * 32];
    const bool isPos = (blockIdx.y >= 64);
    if (isPos && blockIdx.x >= 4) return;
    const u16* A = isPos ? Ap : Aq;
    const u16* W = isPos ? Wp : Wq;
    const int K = 512;
    const int tid  = threadIdx.x;
    const int wv   = tid >> 6;
    const int lane = tid & 63;
    const int wm   = wv >> 2, wn = wv & 3;
    const int m0 = blockIdx.x * 128;
    const int n0 = (isPos ? ((int)blockIdx.y - 64) : (int)blockIdx.y) * 128;

    const int sc_ = tid & 3;
    const int sr_ = tid >> 2;
    const u16* gA = A + (size_t)(n0 + sr_) * K + sc_ * 8;
    const u16* gB = W + (size_t)(m0 + sr_) * K + sc_ * 8;
    const int ls = sr_ * 32 + sc_ * 8;

    f32x4 acc[4][2];
#pragma unroll
    for (int i = 0; i < 4; ++i)
#pragma unroll
        for (int j = 0; j < 2; ++j) acc[i][j] = (f32x4)0.f;

    const int frow = (lane & 15);
    const int fk   = (lane >> 4) * 8;

    uint4 ra = *(const uint4*)(gA);
    uint4 rb = *(const uint4*)(gB);
    *(uint4*)&As[0][ls] = ra;
    *(uint4*)&Bs[0][ls] = rb;
    __syncthreads();

    int buf = 0;
    for (int k0 = 0; k0 < K; k0 += 32) {
        const bool last = (k0 + 32 >= K);
        if (!last) {
            ra = *(const uint4*)(gA + k0 + 32);
            rb = *(const uint4*)(gB + k0 + 32);
        }
        bf16x8 af[4], bf[2];
#pragma unroll
        for (int i = 0; i < 4; ++i)
            af[i] = *(const bf16x8*)&As[buf][(wm * 64 + i * 16 + frow) * 32 + fk];
#pragma unroll
        for (int j = 0; j < 2; ++j)
            bf[j] = *(const bf16x8*)&Bs[buf][(wn * 32 + j * 16 + frow) * 32 + fk];
#pragma unroll
        for (int i = 0; i < 4; ++i)
#pragma unroll
            for (int j = 0; j < 2; ++j)
                acc[i][j] = __builtin_amdgcn_mfma_f32_16x16x32_bf16(af[i], bf[j], acc[i][j], 0, 0, 0);
        if (!last) {
            const int nb = buf ^ 1;
            *(uint4*)&As[nb][ls] = ra;
            *(uint4*)&Bs[nb][ls] = rb;
            __syncthreads();
            buf = nb;
        }
    }

    const int quad = lane >> 4;
#pragma unroll
    for (int i = 0; i < 4; ++i) {
        const int rowb = n0 + wm * 64 + i * 16 + quad * 4;
#pragma unroll
        for (int j = 0; j < 2; ++j) {
            const int col = m0 + wn * 32 + j * 16 + (lane & 15);
            if (!isPos) {
                const float bv = bias[col];
                const int c = col & 511, h = c >> 6, d = c & 63;
#pragma unroll
                for (int r = 0; r < 4; ++r) {
                    const int row = rowb + r;
                    const float v = clampd_(acc[i][j][r] + bv);
                    const int t = row >> 4, b = row & 15;
                    const size_t dst = ((size_t)(b * 8 + h) * 512 + t) * 64 + d;
                    if (col < 512) {
                        o_qu[dst] = f2bf_(v * 0.125f + ub[c]);
                        o_qv[dst] = f2bf_(v * 0.125f + vb[c]);
                    } else if (col < 1024) {
                        o_k[dst] = f2bf_(v);
                    } else {
                        o_v[dst] = f2bf_(v);
                    }
                }
            } else {
                const int h = col >> 6, d = col & 63;
#pragma unroll
                for (int r = 0; r < 4; ++r)
                    o_p[(size_t)h * 65536 + (size_t)(rowb + r) * 64 + d] = f2bf_(acc[i][j][r]);
            }
        }
    }
}

// ---------------------------------------------------------------------------
// pw1 GEMM with fused GLU (R6-proven). Writes a*sigmoid(g) bf16 to glu_o.
// ---------------------------------------------------------------------------
__global__ __launch_bounds__(512) void gemm_glu_k(
    const u16* __restrict__ A, const u16* __restrict__ W,
    const float* __restrict__ bias, u16* __restrict__ out)
{
    __shared__ __align__(16) u16 As[2][128 * 32];
    __shared__ __align__(16) u16 Ba[2][128 * 32];
    __shared__ __align__(16) u16 Bg[2][128 * 32];
    const int tid  = threadIdx.x;
    const int wv   = tid >> 6;
    const int lane = tid & 63;
    const int wm   = wv >> 2, wn = wv & 3;
    const int m0 = blockIdx.x * 128;
    const int n0 = blockIdx.y * 128;
    const int K = 512;

    const int sc_ = tid & 3;
    const int sr_ = tid >> 2;
    const u16* gA  = A + (size_t)(n0 + sr_) * K + sc_ * 8;
    const u16* gBa = W + (size_t)(m0 + sr_) * K + sc_ * 8;
    const u16* gBg = W + (size_t)(m0 + 512 + sr_) * K + sc_ * 8;
    const int ls = sr_ * 32 + sc_ * 8;

    f32x4 aa[4][2], ag[4][2];
#pragma unroll
    for (int i = 0; i < 4; ++i)
#pragma unroll
        for (int j = 0; j < 2; ++j) { aa[i][j] = (f32x4)0.f; ag[i][j] = (f32x4)0.f; }

    const int frow = (lane & 15);
    const int fk   = (lane >> 4) * 8;

    uint4 ra  = *(const uint4*)(gA);
    uint4 rba = *(const uint4*)(gBa);
    uint4 rbg = *(const uint4*)(gBg);
    *(uint4*)&As[0][ls] = ra;
    *(uint4*)&Ba[0][ls] = rba;
    *(uint4*)&Bg[0][ls] = rbg;
    __syncthreads();

    int buf = 0;
    for (int k0 = 0; k0 < K; k0 += 32) {
        const bool last = (k0 + 32 >= K);
        if (!last) {
            ra  = *(const uint4*)(gA + k0 + 32);
            rba = *(const uint4*)(gBa + k0 + 32);
            rbg = *(const uint4*)(gBg + k0 + 32);
        }
        bf16x8 af[4], bfa[2], bfg[2];
#pragma unroll
        for (int i = 0; i < 4; ++i)
            af[i] = *(const bf16x8*)&As[buf][(wm * 64 + i * 16 + frow) * 32 + fk];
#pragma unroll
        for (int j = 0; j < 2; ++j) {
            bfa[j] = *(const bf16x8*)&Ba[buf][(wn * 32 + j * 16 + frow) * 32 + fk];
            bfg[j] = *(const bf16x8*)&Bg[buf][(wn * 32 + j * 16 + frow) * 32 + fk];
        }
#pragma unroll
        for (int i = 0; i < 4; ++i)
#pragma unroll
            for (int j = 0; j < 2; ++j) {
                aa[i][j] = __builtin_amdgcn_mfma_f32_16x16x32_bf16(af[i], bfa[j], aa[i][j], 0, 0, 0);
                ag[i][j] = __builtin_amdgcn_mfma_f32_16x16x32_bf16(af[i], bfg[j], ag[i][j], 0, 0, 0);
            }
        if (!last) {
            const int nb = buf ^ 1;
            *(uint4*)&As[nb][ls] = ra;
            *(uint4*)&Ba[nb][ls] = rba;
            *(uint4*)&Bg[nb][ls] = rbg;
            __syncthreads();
            buf = nb;
        }
    }

    const int quad = lane >> 4;
#pragma unroll
    for (int i = 0; i < 4; ++i) {
        const int row = n0 + wm * 64 + i * 16 + quad * 4;
#pragma unroll
        for (int j = 0; j < 2; ++j) {
            const int col = m0 + wn * 32 + j * 16 + (lane & 15);
            const float ba = bias[col];
            const float bg = bias[col + 512];
#pragma unroll
            for (int r = 0; r < 4; ++r) {
                const float a = clampd_(aa[i][j][r] + ba);
                const float g = clampd_(ag[i][j][r] + bg);
                out[(size_t)(row + r) * 512 + col] = f2bf_(a * sigmoidf_(g));
            }
        }
    }
}

// ---------------------------------------------------------------------------
// f32 -> bf16 converters / prep (merged single launch, R6-proven)
// ---------------------------------------------------------------------------
__device__ __forceinline__ void store_bf4_(u16* out, float4 v) {
    const unsigned lo = (unsigned)f2bf_(v.x) | ((unsigned)f2bf_(v.y) << 16);
    const unsigned hi = (unsigned)f2bf_(v.z) | ((unsigned)f2bf_(v.w) << 16);
    *(uint2*)out = make_uint2(lo, hi);
}

struct WPtrs { const float* p[9]; };
__global__ __launch_bounds__(256) void prep_k(
    WPtrs wp, const float* __restrict__ src, const float* __restrict__ pos,
    const float* __restrict__ cdw,
    u16* __restrict__ wb, u16* __restrict__ src_b, u16* __restrict__ pos_b,
    float* __restrict__ wTd)
{
    const int e = (blockIdx.x * 256 + threadIdx.x) * 4;
    if (e < 6291456) {
        static const int off[10] = {0, 1048576, 2097152, 3145728, 4194304,
                                    4980736, 5242880, 5505024, 6029312, 6291456};
        int r = 0;
#pragma unroll
        for (int k = 1; k < 9; ++k) r += (e >= off[k]);
        store_bf4_(wb + e, *(const float4*)(wp.p[r] + (e - off[r])));
    } else if (e < 6291456 + 4194304) {
        const int e2 = e - 6291456;
        store_bf4_(src_b + e2, *(const float4*)(src + e2));
    } else if (e < 6291456 + 4194304 + 524288) {
        const int e2 = e - (6291456 + 4194304);
        float4 v = make_float4(0.f, 0.f, 0.f, 0.f);
        if (e2 < 1023 * 512) v = *(const float4*)(pos + e2);
        store_bf4_(pos_b + e2, v);
    } else {
        const int e2 = e - (6291456 + 4194304 + 524288);
        if (e2 < 15872) {
#pragma unroll
            for (int q = 0; q < 4; ++q) {
                const int i2 = e2 + q;
                const int j = i2 >> 9, c = i2 & 511;
                wTd[i2] = cdw[c * 31 + j];
            }
        }
    }
}

// v_b[gbh][s][d] -> vt_b[gbh][d][s]  (64x64 LDS tile transpose; R7 lesson:
// this is cheaper than scattering the transpose into the GEMM epilogue)
__global__ __launch_bounds__(256) void vt_k(const u16* __restrict__ in, u16* __restrict__ out)
{
    __shared__ u16 tile[64][65];
    const int s0 = blockIdx.x * 64;
    const int gbh = blockIdx.y;
    const u16* src = in + (size_t)gbh * 512 * 64;
    u16* dst = out + (size_t)gbh * 64 * 512;
    const int tid = threadIdx.x;
#pragma unroll
    for (int q = 0; q < 2; ++q) {
        const int lin = tid * 2 + q;             // 0..511 uint4s
        const int srow = lin >> 3, c8 = (lin & 7) * 8;
        const uint4 v = *(const uint4*)(src + (size_t)(s0 + srow) * 64 + c8);
        const u16* vu = (const u16*)&v;
#pragma unroll
        for (int e = 0; e < 8; ++e) tile[srow][c8 + e] = vu[e];
    }
    __syncthreads();
#pragma unroll
    for (int q = 0; q < 2; ++q) {
        const int lin = tid * 2 + q;
        const int d = lin >> 3, sc8 = (lin & 7) * 8;
        u16 o[8];
#pragma unroll
        for (int e = 0; e < 8; ++e) o[e] = tile[sc8 + e][d];
        *(uint4*)(dst + (size_t)d * 512 + s0 + sc8) = *(uint4*)o;
    }
}

// ---------------------------------------------------------------------------
// Fused flash rel-pos attention (R6-proven body + R11 defer-max, the proven
// local optimum: 6 structural attacks regressed or were neutral).
// grid (t64-tiles=8, gbh=128), 4 waves/block, each wave owns 16 t-rows.
// Wave-private LDS slices, no barriers; padded strides (88/72 u16) keep LDS
// ops <= 2-way. l tracked via ones-column MFMA. Defer-max (T13, THR=8):
// skip O/Lacc rescale when all rows' tile max grew <= 8 (wave-uniform __any).
// ---------------------------------------------------------------------------
#define C2S 88   // padded C2 row stride (u16)
#define PS  72   // padded P row stride (u16)
__global__ __launch_bounds__(256, 4) void flash_attn(
    const u16* __restrict__ qu_b, const u16* __restrict__ qv_b,
    const u16* __restrict__ k_b, const u16* __restrict__ vt_b,
    const u16* __restrict__ p_b, u16* __restrict__ aob)
{
    __shared__ __align__(16) u16 C2ld[4][16 * C2S];
    __shared__ __align__(16) u16 Pld[4][16 * PS];
    const int tid = threadIdx.x;
    const int wv = tid >> 6;
    const int lane = tid & 63;
    const int quad = lane >> 4, ln = lane & 15;
    const int gbh = blockIdx.y;
    const int b = gbh >> 3, h = gbh & 7;
    const int t0 = blockIdx.x * 64 + wv * 16;     // wave's first t-row

    const u16* qu = qu_b + (size_t)gbh * 512 * 64;
    const u16* qv = qv_b + (size_t)gbh * 512 * 64;
    const u16* kb = k_b + (size_t)gbh * 512 * 64;
    const u16* vt = vt_b + (size_t)gbh * 64 * 512;
    const u16* pp = p_b + (size_t)h * 1024 * 64;

    // A-fragments (row = t0+ln, k = ks*32 + quad*8), constant across s-tiles
    bf16x8 aqu[2], aqv[2];
#pragma unroll
    for (int ks = 0; ks < 2; ++ks) {
        aqu[ks] = *(const bf16x8*)(qu + (size_t)(t0 + ln) * 64 + ks * 32 + quad * 8);
        aqv[ks] = *(const bf16x8*)(qv + (size_t)(t0 + ln) * 64 + ks * 32 + quad * 8);
    }

    const short ob = (short)0x3F80;               // bf16 1.0
    const bf16x8 vone = {ob, ob, ob, ob, ob, ob, ob, ob};

    f32x4 O[4];
#pragma unroll
    for (int nb = 0; nb < 4; ++nb) O[nb] = (f32x4)0.f;
    f32x4 Lacc = (f32x4)0.f;                      // per-row softmax denom
    float m[4];
#pragma unroll
    for (int r = 0; r < 4; ++r) m[r] = -1e30f;

    u16* c2w = &C2ld[wv][0];
    u16* pw  = &Pld[wv][0];

    for (int s0 = 0; s0 < 512; s0 += 64) {
        // ---- S = qu . k^T (16 x 64) ----
        f32x4 S[4];
#pragma unroll
        for (int nb = 0; nb < 4; ++nb) S[nb] = (f32x4)0.f;
        __builtin_amdgcn_s_setprio(1);
#pragma unroll
        for (int ks = 0; ks < 2; ++ks)
#pragma unroll
            for (int nb = 0; nb < 4; ++nb) {
                const bf16x8 bk = *(const bf16x8*)(kb + (size_t)(s0 + nb * 16 + ln) * 64 + ks * 32 + quad * 8);
                S[nb] = __builtin_amdgcn_mfma_f32_16x16x32_bf16(aqu[ks], bk, S[nb], 0, 0, 0);
            }
        __builtin_amdgcn_s_setprio(0);
        // ---- C2 window = qv . p[jlo..jlo+80)^T (16 x 80) ----
        const int jlo = 496 - t0 + s0;
        f32x4 C2[5];
#pragma unroll
        for (int nb = 0; nb < 5; ++nb) C2[nb] = (f32x4)0.f;
        __builtin_amdgcn_s_setprio(1);
#pragma unroll
        for (int ks = 0; ks < 2; ++ks)
#pragma unroll
            for (int nb = 0; nb < 5; ++nb) {
                const bf16x8 bp = *(const bf16x8*)(pp + (size_t)(jlo + nb * 16 + ln) * 64 + ks * 32 + quad * 8);
                C2[nb] = __builtin_amdgcn_mfma_f32_16x16x32_bf16(aqv[ks], bp, C2[nb], 0, 0, 0);
            }
        __builtin_amdgcn_s_setprio(0);
#pragma unroll
        for (int nb = 0; nb < 5; ++nb)
#pragma unroll
            for (int r = 0; r < 4; ++r)
                c2w[(quad * 4 + r) * C2S + nb * 16 + ln] = f2bf_(C2[nb][r]);

        // ---- S += shifted bd; clamp; row-max ----
        float sv[4][4];
        float rmax[4] = {-1e30f, -1e30f, -1e30f, -1e30f};
#pragma unroll
        for (int nb = 0; nb < 4; ++nb)
#pragma unroll
            for (int r = 0; r < 4; ++r) {
                const int tloc = quad * 4 + r;
                const int col = nb * 16 + ln + 15 - tloc;   // [0,78]
                const float bd = bf2f_(c2w[tloc * C2S + col]);
                const float s = clampd_(S[nb][r] + bd);
                sv[nb][r] = s;
                rmax[r] = fmaxf(rmax[r], s);
            }
#pragma unroll
        for (int off = 1; off < 16; off <<= 1)
#pragma unroll
            for (int r = 0; r < 4; ++r)
                rmax[r] = fmaxf(rmax[r], __shfl_xor(rmax[r], off, 64));

        // ---- online softmax update with defer-max (T13, THR=8) ----
        bool need = false;
#pragma unroll
        for (int r = 0; r < 4; ++r) need = need || (rmax[r] > m[r] + 8.f);
        if (__any((int)need)) {
            float alpha[4];
#pragma unroll
            for (int r = 0; r < 4; ++r) {
                const float mn = fmaxf(m[r], rmax[r]);
                alpha[r] = __expf(m[r] - mn);
                m[r] = mn;
            }
#pragma unroll
            for (int nb = 0; nb < 4; ++nb)
#pragma unroll
                for (int r = 0; r < 4; ++r) O[nb][r] *= alpha[r];
#pragma unroll
            for (int r = 0; r < 4; ++r) Lacc[r] *= alpha[r];
        }
#pragma unroll
        for (int nb = 0; nb < 4; ++nb)
#pragma unroll
            for (int r = 0; r < 4; ++r) {
                const float p = __expf(sv[nb][r] - m[r]);
                pw[(quad * 4 + r) * PS + nb * 16 + ln] = f2bf_(p);
            }

        // ---- O += P . V ; Lacc += P . 1  (P A-frags from LDS) ----
        __builtin_amdgcn_s_setprio(1);
#pragma unroll
        for (int ks = 0; ks < 2; ++ks) {
            const bf16x8 ap = *(const bf16x8*)&pw[ln * PS + ks * 32 + quad * 8];
#pragma unroll
            for (int nb = 0; nb < 4; ++nb) {
                const bf16x8 bv = *(const bf16x8*)(vt + (size_t)(nb * 16 + ln) * 512 + s0 + ks * 32 + quad * 8);
                O[nb] = __builtin_amdgcn_mfma_f32_16x16x32_bf16(ap, bv, O[nb], 0, 0, 0);
            }
            Lacc = __builtin_amdgcn_mfma_f32_16x16x32_bf16(ap, vone, Lacc, 0, 0, 0);
        }
        __builtin_amdgcn_s_setprio(0);
    }

    // ---- epilogue: normalize and write ao (t,b,c) ----
    float inv[4];
#pragma unroll
    for (int r = 0; r < 4; ++r) inv[r] = 1.f / Lacc[r];
#pragma unroll
    for (int nb = 0; nb < 4; ++nb)
#pragma unroll
        for (int r = 0; r < 4; ++r) {
            const int t = t0 + quad * 4 + r;
            const int d = nb * 16 + ln;
            aob[((size_t)t * B_SZ + b) * 512 + h * 64 + d] = f2bf_(O[nb][r] * inv[r]);
        }
}

// ---------------------------------------------------------------------------
// Conv-module pieces (bf16 chain)
// ---------------------------------------------------------------------------
__global__ __launch_bounds__(256) void dwconv_k(
    const u16* __restrict__ g, const float* __restrict__ wT,
    const float* __restrict__ bb, u16* __restrict__ out)
{
    const int idx = blockIdx.x * 256 + threadIdx.x;
    const int c = idx & 511;
    const int b = (idx >> 9) & 15;
    const int t0 = (idx >> 13) * 8;
    float wr[31];
#pragma unroll
    for (int j = 0; j < 31; ++j) wr[j] = wT[j * 512 + c];
    float win[38];
#pragma unroll
    for (int jj = 0; jj < 38; ++jj) {
        const int tt = t0 - 30 + jj;
        win[jj] = (tt >= 0) ? bf2f_(g[((size_t)tt * B_SZ + b) * 512 + c]) : 0.f;
    }
    const float bias = bb[c];
#pragma unroll
    for (int o = 0; o < 8; ++o) {
        float acc = bias;
#pragma unroll
        for (int j = 0; j < 31; ++j) acc += win[o + j] * wr[j];
        out[((size_t)(t0 + o) * B_SZ + b) * 512 + c] = f2bf_(dswishf_(acc));
    }
}

__global__ __launch_bounds__(256) void norm_k(float* __restrict__ x)
{
    const int row = blockIdx.x * 4 + (threadIdx.x >> 6);
    const int lane = threadIdx.x & 63;
    float* r = x + (size_t)row * 512;
    float v[8];
    float ss = 0.f;
#pragma unroll
    for (int j = 0; j < 8; ++j) { v[j] = r[lane + (j << 6)]; ss += v[j] * v[j]; }
#pragma unroll
    for (int o = 32; o > 0; o >>= 1) ss += __shfl_xor(ss, o, 64);
    const float scale = rsqrtf(ss * (1.f / 512.f) + EPS_BN);
#pragma unroll
    for (int j = 0; j < 8; ++j) r[lane + (j << 6)] = v[j] * scale;
}

// ---------------------------------------------------------------------------
extern "C" void kernel_launch(void* const* d_in, const int* in_sizes, int n_in,
                              void* d_out, int out_size, void* d_ws, size_t ws_size,
                              hipStream_t stream)
{
    const float* src   = (const float*)d_in[0];
    const float* pos   = (const float*)d_in[1];
    const float* fm_w1 = (const float*)d_in[2];
    const float* fm_b1 = (const float*)d_in[3];
    const float* fm_w2 = (const float*)d_in[4];
    const float* fm_b2 = (const float*)d_in[5];
    const float* f_w1  = (const float*)d_in[6];
    const float* f_b1  = (const float*)d_in[7];
    const float* f_w2  = (const float*)d_in[8];
    const float* f_b2  = (const float*)d_in[9];
    const float* ipw   = (const float*)d_in[10];
    const float* ipb   = (const float*)d_in[11];
    const float* opw   = (const float*)d_in[12];
    const float* opb   = (const float*)d_in[13];
    const float* lpw   = (const float*)d_in[14];
    const float* pbu   = (const float*)d_in[15];
    const float* pbv   = (const float*)d_in[16];
    const float* cpw1  = (const float*)d_in[17];
    const float* cpb1  = (const float*)d_in[18];
    const float* cdw   = (const float*)d_in[19];
    const float* cdb   = (const float*)d_in[20];
    const float* cpw2  = (const float*)d_in[21];
    const float* cpb2  = (const float*)d_in[22];

    float* x = (float*)d_out;              // running activation (8192 x 512) f32

    // ---- workspace layout ----
    char* base = (char*)d_ws;
    u16*   wb    = (u16*)base;   base += 6291456ull * 2;   // 9 weights bf16
    u16*   src_b = (u16*)base;   base += 4194304ull * 2;
    u16*   pos_b = (u16*)base;   base += 524288ull * 2;    // 1024x512 padded
    u16*   xb    = (u16*)base;   base += 4194304ull * 2;
    u16*   hb    = (u16*)base;   base += 16777216ull * 2;  // FFN hidden / dwconv out
    u16*   aob   = (u16*)base;   base += 4194304ull * 2;
    u16*   qu_b  = (u16*)base;   base += 4194304ull * 2;
    u16*   qv_b  = (u16*)base;   base += 4194304ull * 2;
    u16*   k_b   = (u16*)base;   base += 4194304ull * 2;
    u16*   v_b   = (u16*)base;   base += 4194304ull * 2;
    u16*   vt_b  = (u16*)base;   base += 4194304ull * 2;
    u16*   p_b   = (u16*)base;   base += 524288ull * 2;    // [8][1024][64]
    float* wTd   = (float*)base; base += 15872ull * 4;
    u16*   glu_o = (u16*)base;   base += 4194304ull * 2;   // conv glu out (8192x512)

    u16* fm_w1b = wb;
    u16* fm_w2b = wb + 1048576;
    u16* f_w1b  = wb + 2097152;
    u16* f_w2b  = wb + 3145728;
    u16* ipwb   = wb + 4194304;
    u16* opwb   = wb + 4980736;
    u16* lpwb   = wb + 5242880;
    u16* cpw1b  = wb + 5505024;
    u16* cpw2b  = wb + 6029312;

    const dim3 blk(256);
    const dim3 blkg(512);

    // 0) all f32 -> bf16 conversions + dw weight transpose, single launch
    WPtrs wp = {{fm_w1, fm_w2, f_w1, f_w2, ipw, opw, lpw, cpw1, cpw2}};
    prep_k<<<dim3(10768), blk, 0, stream>>>(wp, src, pos, cdw, wb, src_b, pos_b, wTd);

    // 1) macaron FFN: x = src + W2 @ dswish(W1 @ src)
    gemm_mfma<1, false, false, true><<<dim3(16, 64), blkg, 0, stream>>>(
        src_b, fm_w1b, fm_b1, nullptr, nullptr, hb, NROWS, 512, DFF_);
    gemm_k64<0, true, true, true><<<dim3(4, 64), blkg, 0, stream>>>(
        hb, fm_w2b, fm_b2, src, x, xb, NROWS, DFF_, 512);

    // 2) qkv + pos projections in ONE launch (pos fills CU slack); V transpose
    gemm_qkvpos<<<dim3(12, 72), blkg, 0, stream>>>(
        xb, ipwb, pos_b, lpwb, ipb, pbu, pbv, qu_b, qv_b, k_b, v_b, p_b);
    vt_k<<<dim3(8, 128), blk, 0, stream>>>(v_b, vt_b);

    // 3) fused flash rel-pos attention (single launch, full batch)
    flash_attn<<<dim3(8, 128), blk, 0, stream>>>(qu_b, qv_b, k_b, vt_b, p_b, aob);

    // 4) out projection (residual into x)
    gemm_mfma<0, true, true, true><<<dim3(4, 64), blkg, 0, stream>>>(
        aob, opwb, opb, x, x, xb, NROWS, 512, 512);

    // 5) conv module: pw1+GLU fused -> dwconv(+dswish) -> pw2 (residual)
    gemm_glu_k<<<dim3(4, 64), blkg, 0, stream>>>(xb, cpw1b, cpb1, glu_o);
    dwconv_k<<<dim3(2048), blk, 0, stream>>>(glu_o, wTd, cdb, hb);
    gemm_mfma<0, true, true, true><<<dim3(4, 64), blkg, 0, stream>>>(
        hb, cpw2b, cpb2, x, x, xb, NROWS, 512, 512);

    // 6) second FFN
    gemm_mfma<1, false, false, true><<<dim3(16, 64), blkg, 0, stream>>>(
        xb, f_w1b, f_b1, nullptr, nullptr, hb, NROWS, 512, DFF_);
    gemm_k64<0, true, true, false><<<dim3(4, 64), blkg, 0, stream>>>(
        hb, f_w2b, f_b2, x, x, nullptr, NROWS, DFF_, 512);

    // 7) BasicNorm
    norm_k<<<dim3(NROWS / 4), blk, 0, stream>>>(x);
}

// Round 13
// 466.277 us; speedup vs baseline: 1.0903x; 1.0110x over previous
//
#include <hip/hip_runtime.h>
#include <math.h>

// Problem constants (ConformerEncoderLayer, T=512 B=16 C=512 H=8 d=64 DFF=2048 K=31)
#define T_SEQ 512
#define B_SZ  16
#define C_DIM 512
#define NH    8
#define HD    64
#define DFF_  2048
#define NROWS (T_SEQ * B_SZ)   // 8192 rows of (t*B+b)
#define EPS_BN 1.2840254166877414f  // exp(0.25)

typedef unsigned short u16;
typedef __attribute__((ext_vector_type(8))) short bf16x8;
typedef __attribute__((ext_vector_type(4))) float f32x4;

__device__ __forceinline__ float sigmoidf_(float x) { return 1.f / (1.f + __expf(-x)); }
__device__ __forceinline__ float dswishf_(float x)  { return x * sigmoidf_(x - 1.f); }
__device__ __forceinline__ float clampd_(float x)   { return fminf(fmaxf(x, -1e4f), 1e4f); }
__device__ __forceinline__ u16 f2bf_(float x) {
    unsigned u = __float_as_uint(x);
    return (u16)((u + 0x7fffu + ((u >> 16) & 1u)) >> 16);
}
__device__ __forceinline__ float bf2f_(u16 u) {
    return __uint_as_float(((unsigned)u) << 16);
}

// ---------------------------------------------------------------------------
// bf16 MFMA GEMM, double-buffered LDS, reg-staged (R0-proven staging).
// R3-proven: 512-thread / 8-wave blocks on a 128x128 tile (wave = 64x32 out,
// acc[4][2]). R9 lesson: 64x64 tiles (more TLP, 2x panel traffic) REGRESS.
// Used for multi-block/CU dispatches (ffm1/ffn1) where 32KB LDS keeps
// several blocks resident. N,M mult of 128; K mult of 32.
// ---------------------------------------------------------------------------
template <int ACT, bool HAS_RES, bool O32, bool O16>
__global__ __launch_bounds__(512) void gemm_mfma(
    const u16* __restrict__ A, const u16* __restrict__ W,
    const float* __restrict__ bias, const float* __restrict__ res,
    float* __restrict__ out32, u16* __restrict__ out16, int N, int K, int M)
{
    __shared__ __align__(16) u16 As[2][128 * 32];
    __shared__ __align__(16) u16 Bs[2][128 * 32];
    const int tid  = threadIdx.x;
    const int wv   = tid >> 6;
    const int lane = tid & 63;
    const int wm   = wv >> 2, wn = wv & 3;   // 2 x 4 waves, 64x32 out each
    const int m0 = blockIdx.x * 128;
    const int n0 = blockIdx.y * 128;

    const int sc_ = tid & 3;
    const int sr_ = tid >> 2;                // 0..127
    const u16* gA = A + (size_t)(n0 + sr_) * K + sc_ * 8;
    const u16* gB = W + (size_t)(m0 + sr_) * K + sc_ * 8;
    const int ls = sr_ * 32 + sc_ * 8;

    f32x4 acc[4][2];
#pragma unroll
    for (int i = 0; i < 4; ++i)
#pragma unroll
        for (int j = 0; j < 2; ++j) acc[i][j] = (f32x4)0.f;

    const int frow = (lane & 15);
    const int fk   = (lane >> 4) * 8;

    uint4 ra = *(const uint4*)(gA);
    uint4 rb = *(const uint4*)(gB);
    *(uint4*)&As[0][ls] = ra;
    *(uint4*)&Bs[0][ls] = rb;
    __syncthreads();

    int buf = 0;
    for (int k0 = 0; k0 < K; k0 += 32) {
        const bool last = (k0 + 32 >= K);
        if (!last) {
            ra = *(const uint4*)(gA + k0 + 32);
            rb = *(const uint4*)(gB + k0 + 32);
        }
        bf16x8 af[4], bf[2];
#pragma unroll
        for (int i = 0; i < 4; ++i)
            af[i] = *(const bf16x8*)&As[buf][(wm * 64 + i * 16 + frow) * 32 + fk];
#pragma unroll
        for (int j = 0; j < 2; ++j)
            bf[j] = *(const bf16x8*)&Bs[buf][(wn * 32 + j * 16 + frow) * 32 + fk];
#pragma unroll
        for (int i = 0; i < 4; ++i)
#pragma unroll
            for (int j = 0; j < 2; ++j)
                acc[i][j] = __builtin_amdgcn_mfma_f32_16x16x32_bf16(af[i], bf[j], acc[i][j], 0, 0, 0);
        if (!last) {
            const int nb = buf ^ 1;
            *(uint4*)&As[nb][ls] = ra;
            *(uint4*)&Bs[nb][ls] = rb;
            __syncthreads();
            buf = nb;
        }
    }

    const int quad = lane >> 4;
#pragma unroll
    for (int i = 0; i < 4; ++i) {
        const int row = n0 + wm * 64 + i * 16 + quad * 4;
#pragma unroll
        for (int j = 0; j < 2; ++j) {
            const int col = m0 + wn * 32 + j * 16 + (lane & 15);
            const float bv = bias ? bias[col] : 0.f;
#pragma unroll
            for (int r = 0; r < 4; ++r) {
                float v = acc[i][j][r] + bv;
                if (ACT == 1) v = dswishf_(v);
                if (HAS_RES) v += res[(size_t)(row + r) * M + col];
                v = clampd_(v);
                if (O32) out32[(size_t)(row + r) * M + col] = v;
                if (O16) out16[(size_t)(row + r) * M + col] = f2bf_(v);
            }
        }
    }
}

// ---------------------------------------------------------------------------
// R12-proven: 4-deep sub-tile ring GEMM ("BK=64" as two sequential BK=32
// sub-tiles; linear per-sub-tile LDS layout). One barrier per 64-K step:
// barrier count halves and 4 global loads issue back-to-back. For the
// 1-block/CU dispatches (ffm2/ffn2/out-proj/cpw2) that can't get more TLP —
// R12 measured -8.7us on ffm2+ffn2. LDS 64KB (grid 256 = 1 block/CU anyway).
// K mult of 64. R13: also applied to out-proj and cpw2 (K=512).
// ---------------------------------------------------------------------------
template <int ACT, bool HAS_RES, bool O32, bool O16>
__global__ __launch_bounds__(512) void gemm_k64(
    const u16* __restrict__ A, const u16* __restrict__ W,
    const float* __restrict__ bias, const float* __restrict__ res,
    float* __restrict__ out32, u16* __restrict__ out16, int N, int K, int M)
{
    __shared__ __align__(16) u16 As[4][128 * 32];
    __shared__ __align__(16) u16 Bs[4][128 * 32];
    const int tid  = threadIdx.x;
    const int wv   = tid >> 6;
    const int lane = tid & 63;
    const int wm   = wv >> 2, wn = wv & 3;
    const int m0 = blockIdx.x * 128;
    const int n0 = blockIdx.y * 128;

    const int sc_ = tid & 3;
    const int sr_ = tid >> 2;
    const u16* gA = A + (size_t)(n0 + sr_) * K + sc_ * 8;
    const u16* gB = W + (size_t)(m0 + sr_) * K + sc_ * 8;
    const int ls = sr_ * 32 + sc_ * 8;

    f32x4 acc[4][2];
#pragma unroll
    for (int i = 0; i < 4; ++i)
#pragma unroll
        for (int j = 0; j < 2; ++j) acc[i][j] = (f32x4)0.f;

    const int frow = (lane & 15);
    const int fk   = (lane >> 4) * 8;

    uint4 ra0 = *(const uint4*)(gA);
    uint4 ra1 = *(const uint4*)(gA + 32);
    uint4 rb0 = *(const uint4*)(gB);
    uint4 rb1 = *(const uint4*)(gB + 32);
    *(uint4*)&As[0][ls] = ra0; *(uint4*)&As[1][ls] = ra1;
    *(uint4*)&Bs[0][ls] = rb0; *(uint4*)&Bs[1][ls] = rb1;
    __syncthreads();

    int ph = 0;   // base buffer of current pair (0 or 2)
    for (int k0 = 0; k0 < K; k0 += 64) {
        const bool last = (k0 + 64 >= K);
        if (!last) {
            ra0 = *(const uint4*)(gA + k0 + 64);
            ra1 = *(const uint4*)(gA + k0 + 96);
            rb0 = *(const uint4*)(gB + k0 + 64);
            rb1 = *(const uint4*)(gB + k0 + 96);
        }
#pragma unroll
        for (int kk = 0; kk < 2; ++kk) {
            bf16x8 af[4], bf[2];
#pragma unroll
            for (int i = 0; i < 4; ++i)
                af[i] = *(const bf16x8*)&As[ph + kk][(wm * 64 + i * 16 + frow) * 32 + fk];
#pragma unroll
            for (int j = 0; j < 2; ++j)
                bf[j] = *(const bf16x8*)&Bs[ph + kk][(wn * 32 + j * 16 + frow) * 32 + fk];
#pragma unroll
            for (int i = 0; i < 4; ++i)
#pragma unroll
                for (int j = 0; j < 2; ++j)
                    acc[i][j] = __builtin_amdgcn_mfma_f32_16x16x32_bf16(af[i], bf[j], acc[i][j], 0, 0, 0);
        }
        if (!last) {
            const int nb = ph ^ 2;
            *(uint4*)&As[nb][ls] = ra0; *(uint4*)&As[nb + 1][ls] = ra1;
            *(uint4*)&Bs[nb][ls] = rb0; *(uint4*)&Bs[nb + 1][ls] = rb1;
            __syncthreads();
            ph = nb;
        }
    }

    const int quad = lane >> 4;
#pragma unroll
    for (int i = 0; i < 4; ++i) {
        const int row = n0 + wm * 64 + i * 16 + quad * 4;
#pragma unroll
        for (int j = 0; j < 2; ++j) {
            const int col = m0 + wn * 32 + j * 16 + (lane & 15);
            const float bv = bias ? bias[col] : 0.f;
#pragma unroll
            for (int r = 0; r < 4; ++r) {
                float v = acc[i][j][r] + bv;
                if (ACT == 1) v = dswishf_(v);
                if (HAS_RES) v += res[(size_t)(row + r) * M + col];
                v = clampd_(v);
                if (O32) out32[(size_t)(row + r) * M + col] = v;
                if (O16) out16[(size_t)(row + r) * M + col] = f2bf_(v);
            }
        }
    }
}

// ---------------------------------------------------------------------------
// Merged qkv + pos projection GEMM (both K=512, same dbuf body; R10).
// Grid (12, 72): y<64 -> qkv block; y>=64 -> pos block (x>=4 early-exits).
// EPI qkv: writes qu/qv/k/v bf16 in [b*8+h][t][d], q*0.125 + u/v bias.
//   (R7 lesson: V must NOT be written transposed here.)
// EPI pos: writes p_b[h][j][d] bf16.
// ---------------------------------------------------------------------------
__global__ __launch_bounds__(512) void gemm_qkvpos(
    const u16* __restrict__ Aq, const u16* __restrict__ Wq,
    const u16* __restrict__ Ap, const u16* __restrict__ Wp,
    const float* __restrict__ bias, const float* __restrict__ ub, const float* __restrict__ vb,
    u16* __restrict__ o_qu, u16* __restrict__ o_qv, u16* __restrict__ o_k,
    u16* __restrict__ o_v, u16* __restrict__ o_p)
{
    __shared__ __align__(16) u16 As[2][128 * 32];
    __shared__ __align__(16) u16 Bs[2][128 * 32];
    const bool isPos = (blockIdx.y >= 64);
    if (isPos && blockIdx.x >= 4) return;
    const u16* A = isPos ? Ap : Aq;
    const u16* W = isPos ? Wp : Wq;
    const int K = 512;
    const int tid  = threadIdx.x;
    const int wv   = tid >> 6;
    const int lane = tid & 63;
    const int wm   = wv >> 2, wn = wv & 3;
    const int m0 = blockIdx.x * 128;
    const int n0 = (isPos ? ((int)blockIdx.y - 64) : (int)blockIdx.y) * 128;

    const int sc_ = tid & 3;
    const int sr_ = tid >> 2;
    const u16* gA = A + (size_t)(n0 + sr_) * K + sc_ * 8;
    const u16* gB = W + (size_t)(m0 + sr_) * K + sc_ * 8;
    const int ls = sr_ * 32 + sc_ * 8;

    f32x4 acc[4][2];
#pragma unroll
    for (int i = 0; i < 4; ++i)
#pragma unroll
        for (int j = 0; j < 2; ++j) acc[i][j] = (f32x4)0.f;

    const int frow = (lane & 15);
    const int fk   = (lane >> 4) * 8;

    uint4 ra = *(const uint4*)(gA);
    uint4 rb = *(const uint4*)(gB);
    *(uint4*)&As[0][ls] = ra;
    *(uint4*)&Bs[0][ls] = rb;
    __syncthreads();

    int buf = 0;
    for (int k0 = 0; k0 < K; k0 += 32) {
        const bool last = (k0 + 32 >= K);
        if (!last) {
            ra = *(const uint4*)(gA + k0 + 32);
            rb = *(const uint4*)(gB + k0 + 32);
        }
        bf16x8 af[4], bf[2];
#pragma unroll
        for (int i = 0; i < 4; ++i)
            af[i] = *(const bf16x8*)&As[buf][(wm * 64 + i * 16 + frow) * 32 + fk];
#pragma unroll
        for (int j = 0; j < 2; ++j)
            bf[j] = *(const bf16x8*)&Bs[buf][(wn * 32 + j * 16 + frow) * 32 + fk];
#pragma unroll
        for (int i = 0; i < 4; ++i)
#pragma unroll
            for (int j = 0; j < 2; ++j)
                acc[i][j] = __builtin_amdgcn_mfma_f32_16x16x32_bf16(af[i], bf[j], acc[i][j], 0, 0, 0);
        if (!last) {
            const int nb = buf ^ 1;
            *(uint4*)&As[nb][ls] = ra;
            *(uint4*)&Bs[nb][ls] = rb;
            __syncthreads();
            buf = nb;
        }
    }

    const int quad = lane >> 4;
#pragma unroll
    for (int i = 0; i < 4; ++i) {
        const int rowb = n0 + wm * 64 + i * 16 + quad * 4;
#pragma unroll
        for (int j = 0; j < 2; ++j) {
            const int col = m0 + wn * 32 + j * 16 + (lane & 15);
            if (!isPos) {
                const float bv = bias[col];
                const int c = col & 511, h = c >> 6, d = c & 63;
#pragma unroll
                for (int r = 0; r < 4; ++r) {
                    const int row = rowb + r;
                    const float v = clampd_(acc[i][j][r] + bv);
                    const int t = row >> 4, b = row & 15;
                    const size_t dst = ((size_t)(b * 8 + h) * 512 + t) * 64 + d;
                    if (col < 512) {
                        o_qu[dst] = f2bf_(v * 0.125f + ub[c]);
                        o_qv[dst] = f2bf_(v * 0.125f + vb[c]);
                    } else if (col < 1024) {
                        o_k[dst] = f2bf_(v);
                    } else {
                        o_v[dst] = f2bf_(v);
                    }
                }
            } else {
                const int h = col >> 6, d = col & 63;
#pragma unroll
                for (int r = 0; r < 4; ++r)
                    o_p[(size_t)h * 65536 + (size_t)(rowb + r) * 64 + d] = f2bf_(acc[i][j][r]);
            }
        }
    }
}

// ---------------------------------------------------------------------------
// pw1 GEMM with fused GLU (R6-proven). Writes a*sigmoid(g) bf16 to glu_o.
// (3 operand buffers -> K64 ring would need 192KB LDS > 160; stays BK=32.)
// ---------------------------------------------------------------------------
__global__ __launch_bounds__(512) void gemm_glu_k(
    const u16* __restrict__ A, const u16* __restrict__ W,
    const float* __restrict__ bias, u16* __restrict__ out)
{
    __shared__ __align__(16) u16 As[2][128 * 32];
    __shared__ __align__(16) u16 Ba[2][128 * 32];
    __shared__ __align__(16) u16 Bg[2][128 * 32];
    const int tid  = threadIdx.x;
    const int wv   = tid >> 6;
    const int lane = tid & 63;
    const int wm   = wv >> 2, wn = wv & 3;
    const int m0 = blockIdx.x * 128;
    const int n0 = blockIdx.y * 128;
    const int K = 512;

    const int sc_ = tid & 3;
    const int sr_ = tid >> 2;
    const u16* gA  = A + (size_t)(n0 + sr_) * K + sc_ * 8;
    const u16* gBa = W + (size_t)(m0 + sr_) * K + sc_ * 8;
    const u16* gBg = W + (size_t)(m0 + 512 + sr_) * K + sc_ * 8;
    const int ls = sr_ * 32 + sc_ * 8;

    f32x4 aa[4][2], ag[4][2];
#pragma unroll
    for (int i = 0; i < 4; ++i)
#pragma unroll
        for (int j = 0; j < 2; ++j) { aa[i][j] = (f32x4)0.f; ag[i][j] = (f32x4)0.f; }

    const int frow = (lane & 15);
    const int fk   = (lane >> 4) * 8;

    uint4 ra  = *(const uint4*)(gA);
    uint4 rba = *(const uint4*)(gBa);
    uint4 rbg = *(const uint4*)(gBg);
    *(uint4*)&As[0][ls] = ra;
    *(uint4*)&Ba[0][ls] = rba;
    *(uint4*)&Bg[0][ls] = rbg;
    __syncthreads();

    int buf = 0;
    for (int k0 = 0; k0 < K; k0 += 32) {
        const bool last = (k0 + 32 >= K);
        if (!last) {
            ra  = *(const uint4*)(gA + k0 + 32);
            rba = *(const uint4*)(gBa + k0 + 32);
            rbg = *(const uint4*)(gBg + k0 + 32);
        }
        bf16x8 af[4], bfa[2], bfg[2];
#pragma unroll
        for (int i = 0; i < 4; ++i)
            af[i] = *(const bf16x8*)&As[buf][(wm * 64 + i * 16 + frow) * 32 + fk];
#pragma unroll
        for (int j = 0; j < 2; ++j) {
            bfa[j] = *(const bf16x8*)&Ba[buf][(wn * 32 + j * 16 + frow) * 32 + fk];
            bfg[j] = *(const bf16x8*)&Bg[buf][(wn * 32 + j * 16 + frow) * 32 + fk];
        }
#pragma unroll
        for (int i = 0; i < 4; ++i)
#pragma unroll
            for (int j = 0; j < 2; ++j) {
                aa[i][j] = __builtin_amdgcn_mfma_f32_16x16x32_bf16(af[i], bfa[j], aa[i][j], 0, 0, 0);
                ag[i][j] = __builtin_amdgcn_mfma_f32_16x16x32_bf16(af[i], bfg[j], ag[i][j], 0, 0, 0);
            }
        if (!last) {
            const int nb = buf ^ 1;
            *(uint4*)&As[nb][ls] = ra;
            *(uint4*)&Ba[nb][ls] = rba;
            *(uint4*)&Bg[nb][ls] = rbg;
            __syncthreads();
            buf = nb;
        }
    }

    const int quad = lane >> 4;
#pragma unroll
    for (int i = 0; i < 4; ++i) {
        const int row = n0 + wm * 64 + i * 16 + quad * 4;
#pragma unroll
        for (int j = 0; j < 2; ++j) {
            const int col = m0 + wn * 32 + j * 16 + (lane & 15);
            const float ba = bias[col];
            const float bg = bias[col + 512];
#pragma unroll
            for (int r = 0; r < 4; ++r) {
                const float a = clampd_(aa[i][j][r] + ba);
                const float g = clampd_(ag[i][j][r] + bg);
                out[(size_t)(row + r) * 512 + col] = f2bf_(a * sigmoidf_(g));
            }
        }
    }
}

// ---------------------------------------------------------------------------
// f32 -> bf16 converters / prep (merged single launch, R6-proven)
// ---------------------------------------------------------------------------
__device__ __forceinline__ void store_bf4_(u16* out, float4 v) {
    const unsigned lo = (unsigned)f2bf_(v.x) | ((unsigned)f2bf_(v.y) << 16);
    const unsigned hi = (unsigned)f2bf_(v.z) | ((unsigned)f2bf_(v.w) << 16);
    *(uint2*)out = make_uint2(lo, hi);
}

struct WPtrs { const float* p[9]; };
__global__ __launch_bounds__(256) void prep_k(
    WPtrs wp, const float* __restrict__ src, const float* __restrict__ pos,
    const float* __restrict__ cdw,
    u16* __restrict__ wb, u16* __restrict__ src_b, u16* __restrict__ pos_b,
    float* __restrict__ wTd)
{
    const int e = (blockIdx.x * 256 + threadIdx.x) * 4;
    if (e < 6291456) {
        static const int off[10] = {0, 1048576, 2097152, 3145728, 4194304,
                                    4980736, 5242880, 5505024, 6029312, 6291456};
        int r = 0;
#pragma unroll
        for (int k = 1; k < 9; ++k) r += (e >= off[k]);
        store_bf4_(wb + e, *(const float4*)(wp.p[r] + (e - off[r])));
    } else if (e < 6291456 + 4194304) {
        const int e2 = e - 6291456;
        store_bf4_(src_b + e2, *(const float4*)(src + e2));
    } else if (e < 6291456 + 4194304 + 524288) {
        const int e2 = e - (6291456 + 4194304);
        float4 v = make_float4(0.f, 0.f, 0.f, 0.f);
        if (e2 < 1023 * 512) v = *(const float4*)(pos + e2);
        store_bf4_(pos_b + e2, v);
    } else {
        const int e2 = e - (6291456 + 4194304 + 524288);
        if (e2 < 15872) {
#pragma unroll
            for (int q = 0; q < 4; ++q) {
                const int i2 = e2 + q;
                const int j = i2 >> 9, c = i2 & 511;
                wTd[i2] = cdw[c * 31 + j];
            }
        }
    }
}

// v_b[gbh][s][d] -> vt_b[gbh][d][s]  (64x64 LDS tile transpose; R7 lesson:
// this is cheaper than scattering the transpose into the GEMM epilogue)
__global__ __launch_bounds__(256) void vt_k(const u16* __restrict__ in, u16* __restrict__ out)
{
    __shared__ u16 tile[64][65];
    const int s0 = blockIdx.x * 64;
    const int gbh = blockIdx.y;
    const u16* src = in + (size_t)gbh * 512 * 64;
    u16* dst = out + (size_t)gbh * 64 * 512;
    const int tid = threadIdx.x;
#pragma unroll
    for (int q = 0; q < 2; ++q) {
        const int lin = tid * 2 + q;             // 0..511 uint4s
        const int srow = lin >> 3, c8 = (lin & 7) * 8;
        const uint4 v = *(const uint4*)(src + (size_t)(s0 + srow) * 64 + c8);
        const u16* vu = (const u16*)&v;
#pragma unroll
        for (int e = 0; e < 8; ++e) tile[srow][c8 + e] = vu[e];
    }
    __syncthreads();
#pragma unroll
    for (int q = 0; q < 2; ++q) {
        const int lin = tid * 2 + q;
        const int d = lin >> 3, sc8 = (lin & 7) * 8;
        u16 o[8];
#pragma unroll
        for (int e = 0; e < 8; ++e) o[e] = tile[sc8 + e][d];
        *(uint4*)(dst + (size_t)d * 512 + s0 + sc8) = *(uint4*)o;
    }
}

// ---------------------------------------------------------------------------
// Fused flash rel-pos attention (R6-proven body + R11 defer-max, the proven
// local optimum: 6 structural attacks regressed or were neutral).
// grid (t64-tiles=8, gbh=128), 4 waves/block, each wave owns 16 t-rows.
// Wave-private LDS slices, no barriers; padded strides (88/72 u16) keep LDS
// ops <= 2-way. l tracked via ones-column MFMA. Defer-max (T13, THR=8):
// skip O/Lacc rescale when all rows' tile max grew <= 8 (wave-uniform __any).
// ---------------------------------------------------------------------------
#define C2S 88   // padded C2 row stride (u16)
#define PS  72   // padded P row stride (u16)
__global__ __launch_bounds__(256, 4) void flash_attn(
    const u16* __restrict__ qu_b, const u16* __restrict__ qv_b,
    const u16* __restrict__ k_b, const u16* __restrict__ vt_b,
    const u16* __restrict__ p_b, u16* __restrict__ aob)
{
    __shared__ __align__(16) u16 C2ld[4][16 * C2S];
    __shared__ __align__(16) u16 Pld[4][16 * PS];
    const int tid = threadIdx.x;
    const int wv = tid >> 6;
    const int lane = tid & 63;
    const int quad = lane >> 4, ln = lane & 15;
    const int gbh = blockIdx.y;
    const int b = gbh >> 3, h = gbh & 7;
    const int t0 = blockIdx.x * 64 + wv * 16;     // wave's first t-row

    const u16* qu = qu_b + (size_t)gbh * 512 * 64;
    const u16* qv = qv_b + (size_t)gbh * 512 * 64;
    const u16* kb = k_b + (size_t)gbh * 512 * 64;
    const u16* vt = vt_b + (size_t)gbh * 64 * 512;
    const u16* pp = p_b + (size_t)h * 1024 * 64;

    // A-fragments (row = t0+ln, k = ks*32 + quad*8), constant across s-tiles
    bf16x8 aqu[2], aqv[2];
#pragma unroll
    for (int ks = 0; ks < 2; ++ks) {
        aqu[ks] = *(const bf16x8*)(qu + (size_t)(t0 + ln) * 64 + ks * 32 + quad * 8);
        aqv[ks] = *(const bf16x8*)(qv + (size_t)(t0 + ln) * 64 + ks * 32 + quad * 8);
    }

    const short ob = (short)0x3F80;               // bf16 1.0
    const bf16x8 vone = {ob, ob, ob, ob, ob, ob, ob, ob};

    f32x4 O[4];
#pragma unroll
    for (int nb = 0; nb < 4; ++nb) O[nb] = (f32x4)0.f;
    f32x4 Lacc = (f32x4)0.f;                      // per-row softmax denom
    float m[4];
#pragma unroll
    for (int r = 0; r < 4; ++r) m[r] = -1e30f;

    u16* c2w = &C2ld[wv][0];
    u16* pw  = &Pld[wv][0];

    for (int s0 = 0; s0 < 512; s0 += 64) {
        // ---- S = qu . k^T (16 x 64) ----
        f32x4 S[4];
#pragma unroll
        for (int nb = 0; nb < 4; ++nb) S[nb] = (f32x4)0.f;
        __builtin_amdgcn_s_setprio(1);
#pragma unroll
        for (int ks = 0; ks < 2; ++ks)
#pragma unroll
            for (int nb = 0; nb < 4; ++nb) {
                const bf16x8 bk = *(const bf16x8*)(kb + (size_t)(s0 + nb * 16 + ln) * 64 + ks * 32 + quad * 8);
                S[nb] = __builtin_amdgcn_mfma_f32_16x16x32_bf16(aqu[ks], bk, S[nb], 0, 0, 0);
            }
        __builtin_amdgcn_s_setprio(0);
        // ---- C2 window = qv . p[jlo..jlo+80)^T (16 x 80) ----
        const int jlo = 496 - t0 + s0;
        f32x4 C2[5];
#pragma unroll
        for (int nb = 0; nb < 5; ++nb) C2[nb] = (f32x4)0.f;
        __builtin_amdgcn_s_setprio(1);
#pragma unroll
        for (int ks = 0; ks < 2; ++ks)
#pragma unroll
            for (int nb = 0; nb < 5; ++nb) {
                const bf16x8 bp = *(const bf16x8*)(pp + (size_t)(jlo + nb * 16 + ln) * 64 + ks * 32 + quad * 8);
                C2[nb] = __builtin_amdgcn_mfma_f32_16x16x32_bf16(aqv[ks], bp, C2[nb], 0, 0, 0);
            }
        __builtin_amdgcn_s_setprio(0);
#pragma unroll
        for (int nb = 0; nb < 5; ++nb)
#pragma unroll
            for (int r = 0; r < 4; ++r)
                c2w[(quad * 4 + r) * C2S + nb * 16 + ln] = f2bf_(C2[nb][r]);

        // ---- S += shifted bd; clamp; row-max ----
        float sv[4][4];
        float rmax[4] = {-1e30f, -1e30f, -1e30f, -1e30f};
#pragma unroll
        for (int nb = 0; nb < 4; ++nb)
#pragma unroll
            for (int r = 0; r < 4; ++r) {
                const int tloc = quad * 4 + r;
                const int col = nb * 16 + ln + 15 - tloc;   // [0,78]
                const float bd = bf2f_(c2w[tloc * C2S + col]);
                const float s = clampd_(S[nb][r] + bd);
                sv[nb][r] = s;
                rmax[r] = fmaxf(rmax[r], s);
            }
#pragma unroll
        for (int off = 1; off < 16; off <<= 1)
#pragma unroll
            for (int r = 0; r < 4; ++r)
                rmax[r] = fmaxf(rmax[r], __shfl_xor(rmax[r], off, 64));

        // ---- online softmax update with defer-max (T13, THR=8) ----
        bool need = false;
#pragma unroll
        for (int r = 0; r < 4; ++r) need = need || (rmax[r] > m[r] + 8.f);
        if (__any((int)need)) {
            float alpha[4];
#pragma unroll
            for (int r = 0; r < 4; ++r) {
                const float mn = fmaxf(m[r], rmax[r]);
                alpha[r] = __expf(m[r] - mn);
                m[r] = mn;
            }
#pragma unroll
            for (int nb = 0; nb < 4; ++nb)
#pragma unroll
                for (int r = 0; r < 4; ++r) O[nb][r] *= alpha[r];
#pragma unroll
            for (int r = 0; r < 4; ++r) Lacc[r] *= alpha[r];
        }
#pragma unroll
        for (int nb = 0; nb < 4; ++nb)
#pragma unroll
            for (int r = 0; r < 4; ++r) {
                const float p = __expf(sv[nb][r] - m[r]);
                pw[(quad * 4 + r) * PS + nb * 16 + ln] = f2bf_(p);
            }

        // ---- O += P . V ; Lacc += P . 1  (P A-frags from LDS) ----
        __builtin_amdgcn_s_setprio(1);
#pragma unroll
        for (int ks = 0; ks < 2; ++ks) {
            const bf16x8 ap = *(const bf16x8*)&pw[ln * PS + ks * 32 + quad * 8];
#pragma unroll
            for (int nb = 0; nb < 4; ++nb) {
                const bf16x8 bv = *(const bf16x8*)(vt + (size_t)(nb * 16 + ln) * 512 + s0 + ks * 32 + quad * 8);
                O[nb] = __builtin_amdgcn_mfma_f32_16x16x32_bf16(ap, bv, O[nb], 0, 0, 0);
            }
            Lacc = __builtin_amdgcn_mfma_f32_16x16x32_bf16(ap, vone, Lacc, 0, 0, 0);
        }
        __builtin_amdgcn_s_setprio(0);
    }

    // ---- epilogue: normalize and write ao (t,b,c) ----
    float inv[4];
#pragma unroll
    for (int r = 0; r < 4; ++r) inv[r] = 1.f / Lacc[r];
#pragma unroll
    for (int nb = 0; nb < 4; ++nb)
#pragma unroll
        for (int r = 0; r < 4; ++r) {
            const int t = t0 + quad * 4 + r;
            const int d = nb * 16 + ln;
            aob[((size_t)t * B_SZ + b) * 512 + h * 64 + d] = f2bf_(O[nb][r] * inv[r]);
        }
}

// ---------------------------------------------------------------------------
// Conv-module pieces (bf16 chain)
// ---------------------------------------------------------------------------
__global__ __launch_bounds__(256) void dwconv_k(
    const u16* __restrict__ g, const float* __restrict__ wT,
    const float* __restrict__ bb, u16* __restrict__ out)
{
    const int idx = blockIdx.x * 256 + threadIdx.x;
    const int c = idx & 511;
    const int b = (idx >> 9) & 15;
    const int t0 = (idx >> 13) * 8;
    float wr[31];
#pragma unroll
    for (int j = 0; j < 31; ++j) wr[j] = wT[j * 512 + c];
    float win[38];
#pragma unroll
    for (int jj = 0; jj < 38; ++jj) {
        const int tt = t0 - 30 + jj;
        win[jj] = (tt >= 0) ? bf2f_(g[((size_t)tt * B_SZ + b) * 512 + c]) : 0.f;
    }
    const float bias = bb[c];
#pragma unroll
    for (int o = 0; o < 8; ++o) {
        float acc = bias;
#pragma unroll
        for (int j = 0; j < 31; ++j) acc += win[o + j] * wr[j];
        out[((size_t)(t0 + o) * B_SZ + b) * 512 + c] = f2bf_(dswishf_(acc));
    }
}

__global__ __launch_bounds__(256) void norm_k(float* __restrict__ x)
{
    const int row = blockIdx.x * 4 + (threadIdx.x >> 6);
    const int lane = threadIdx.x & 63;
    float* r = x + (size_t)row * 512;
    float v[8];
    float ss = 0.f;
#pragma unroll
    for (int j = 0; j < 8; ++j) { v[j] = r[lane + (j << 6)]; ss += v[j] * v[j]; }
#pragma unroll
    for (int o = 32; o > 0; o >>= 1) ss += __shfl_xor(ss, o, 64);
    const float scale = rsqrtf(ss * (1.f / 512.f) + EPS_BN);
#pragma unroll
    for (int j = 0; j < 8; ++j) r[lane + (j << 6)] = v[j] * scale;
}

// ---------------------------------------------------------------------------
extern "C" void kernel_launch(void* const* d_in, const int* in_sizes, int n_in,
                              void* d_out, int out_size, void* d_ws, size_t ws_size,
                              hipStream_t stream)
{
    const float* src   = (const float*)d_in[0];
    const float* pos   = (const float*)d_in[1];
    const float* fm_w1 = (const float*)d_in[2];
    const float* fm_b1 = (const float*)d_in[3];
    const float* fm_w2 = (const float*)d_in[4];
    const float* fm_b2 = (const float*)d_in[5];
    const float* f_w1  = (const float*)d_in[6];
    const float* f_b1  = (const float*)d_in[7];
    const float* f_w2  = (const float*)d_in[8];
    const float* f_b2  = (const float*)d_in[9];
    const float* ipw   = (const float*)d_in[10];
    const float* ipb   = (const float*)d_in[11];
    const float* opw   = (const float*)d_in[12];
    const float* opb   = (const float*)d_in[13];
    const float* lpw   = (const float*)d_in[14];
    const float* pbu   = (const float*)d_in[15];
    const float* pbv   = (const float*)d_in[16];
    const float* cpw1  = (const float*)d_in[17];
    const float* cpb1  = (const float*)d_in[18];
    const float* cdw   = (const float*)d_in[19];
    const float* cdb   = (const float*)d_in[20];
    const float* cpw2  = (const float*)d_in[21];
    const float* cpb2  = (const float*)d_in[22];

    float* x = (float*)d_out;              // running activation (8192 x 512) f32

    // ---- workspace layout ----
    char* base = (char*)d_ws;
    u16*   wb    = (u16*)base;   base += 6291456ull * 2;   // 9 weights bf16
    u16*   src_b = (u16*)base;   base += 4194304ull * 2;
    u16*   pos_b = (u16*)base;   base += 524288ull * 2;    // 1024x512 padded
    u16*   xb    = (u16*)base;   base += 4194304ull * 2;
    u16*   hb    = (u16*)base;   base += 16777216ull * 2;  // FFN hidden / dwconv out
    u16*   aob   = (u16*)base;   base += 4194304ull * 2;
    u16*   qu_b  = (u16*)base;   base += 4194304ull * 2;
    u16*   qv_b  = (u16*)base;   base += 4194304ull * 2;
    u16*   k_b   = (u16*)base;   base += 4194304ull * 2;
    u16*   v_b   = (u16*)base;   base += 4194304ull * 2;
    u16*   vt_b  = (u16*)base;   base += 4194304ull * 2;
    u16*   p_b   = (u16*)base;   base += 524288ull * 2;    // [8][1024][64]
    float* wTd   = (float*)base; base += 15872ull * 4;
    u16*   glu_o = (u16*)base;   base += 4194304ull * 2;   // conv glu out (8192x512)

    u16* fm_w1b = wb;
    u16* fm_w2b = wb + 1048576;
    u16* f_w1b  = wb + 2097152;
    u16* f_w2b  = wb + 3145728;
    u16* ipwb   = wb + 4194304;
    u16* opwb   = wb + 4980736;
    u16* lpwb   = wb + 5242880;
    u16* cpw1b  = wb + 5505024;
    u16* cpw2b  = wb + 6029312;

    const dim3 blk(256);
    const dim3 blkg(512);

    // 0) all f32 -> bf16 conversions + dw weight transpose, single launch
    WPtrs wp = {{fm_w1, fm_w2, f_w1, f_w2, ipw, opw, lpw, cpw1, cpw2}};
    prep_k<<<dim3(10768), blk, 0, stream>>>(wp, src, pos, cdw, wb, src_b, pos_b, wTd);

    // 1) macaron FFN: x = src + W2 @ dswish(W1 @ src)
    gemm_mfma<1, false, false, true><<<dim3(16, 64), blkg, 0, stream>>>(
        src_b, fm_w1b, fm_b1, nullptr, nullptr, hb, NROWS, 512, DFF_);
    gemm_k64<0, true, true, true><<<dim3(4, 64), blkg, 0, stream>>>(
        hb, fm_w2b, fm_b2, src, x, xb, NROWS, DFF_, 512);

    // 2) qkv + pos projections in ONE launch (pos fills CU slack); V transpose
    gemm_qkvpos<<<dim3(12, 72), blkg, 0, stream>>>(
        xb, ipwb, pos_b, lpwb, ipb, pbu, pbv, qu_b, qv_b, k_b, v_b, p_b);
    vt_k<<<dim3(8, 128), blk, 0, stream>>>(v_b, vt_b);

    // 3) fused flash rel-pos attention (single launch, full batch)
    flash_attn<<<dim3(8, 128), blk, 0, stream>>>(qu_b, qv_b, k_b, vt_b, p_b, aob);

    // 4) out projection (residual into x) — K64 ring (R13: 1-block/CU dispatch)
    gemm_k64<0, true, true, true><<<dim3(4, 64), blkg, 0, stream>>>(
        aob, opwb, opb, x, x, xb, NROWS, 512, 512);

    // 5) conv module: pw1+GLU fused -> dwconv(+dswish) -> pw2 (residual, K64)
    gemm_glu_k<<<dim3(4, 64), blkg, 0, stream>>>(xb, cpw1b, cpb1, glu_o);
    dwconv_k<<<dim3(2048), blk, 0, stream>>>(glu_o, wTd, cdb, hb);
    gemm_k64<0, true, true, true><<<dim3(4, 64), blkg, 0, stream>>>(
        hb, cpw2b, cpb2, x, x, xb, NROWS, 512, 512);

    // 6) second FFN
    gemm_mfma<1, false, false, true><<<dim3(16, 64), blkg, 0, stream>>>(
        xb, f_w1b, f_b1, nullptr, nullptr, hb, NROWS, 512, DFF_);
    gemm_k64<0, true, true, false><<<dim3(4, 64), blkg, 0, stream>>>(
        hb, f_w2b, f_b2, x, x, nullptr, NROWS, DFF_, 512);

    // 7) BasicNorm
    norm_k<<<dim3(NROWS / 4), blk, 0, stream>>>(x);
}

// Round 14
// 457.785 us; speedup vs baseline: 1.1105x; 1.0186x over previous
//
#include <hip/hip_runtime.h>
#include <math.h>

// Problem constants (ConformerEncoderLayer, T=512 B=16 C=512 H=8 d=64 DFF=2048 K=31)
#define T_SEQ 512
#define B_SZ  16
#define C_DIM 512
#define NH    8
#define HD    64
#define DFF_  2048
#define NROWS (T_SEQ * B_SZ)   // 8192 rows of (t*B+b)
#define EPS_BN 1.2840254166877414f  // exp(0.25)

typedef unsigned short u16;
typedef __attribute__((ext_vector_type(8))) short bf16x8;
typedef __attribute__((ext_vector_type(4))) float f32x4;

__device__ __forceinline__ float sigmoidf_(float x) { return 1.f / (1.f + __expf(-x)); }
__device__ __forceinline__ float dswishf_(float x)  { return x * sigmoidf_(x - 1.f); }
__device__ __forceinline__ float clampd_(float x)   { return fminf(fmaxf(x, -1e4f), 1e4f); }
__device__ __forceinline__ u16 f2bf_(float x) {
    unsigned u = __float_as_uint(x);
    return (u16)((u + 0x7fffu + ((u >> 16) & 1u)) >> 16);
}
__device__ __forceinline__ float bf2f_(u16 u) {
    return __uint_as_float(((unsigned)u) << 16);
}

// ---------------------------------------------------------------------------
// bf16 MFMA GEMM, double-buffered LDS, reg-staged (R0-proven staging).
// R3-proven: 512-thread / 8-wave blocks on a 128x128 tile (wave = 64x32 out,
// acc[4][2]). R9 lesson: 64x64 tiles (more TLP, 2x panel traffic) REGRESS.
// Used for multi-block/CU dispatches (ffm1/ffn1) where 32KB LDS keeps
// several blocks resident. N,M mult of 128; K mult of 32.
// ---------------------------------------------------------------------------
template <int ACT, bool HAS_RES, bool O32, bool O16>
__global__ __launch_bounds__(512) void gemm_mfma(
    const u16* __restrict__ A, const u16* __restrict__ W,
    const float* __restrict__ bias, const float* __restrict__ res,
    float* __restrict__ out32, u16* __restrict__ out16, int N, int K, int M)
{
    __shared__ __align__(16) u16 As[2][128 * 32];
    __shared__ __align__(16) u16 Bs[2][128 * 32];
    const int tid  = threadIdx.x;
    const int wv   = tid >> 6;
    const int lane = tid & 63;
    const int wm   = wv >> 2, wn = wv & 3;   // 2 x 4 waves, 64x32 out each
    const int m0 = blockIdx.x * 128;
    const int n0 = blockIdx.y * 128;

    const int sc_ = tid & 3;
    const int sr_ = tid >> 2;                // 0..127
    const u16* gA = A + (size_t)(n0 + sr_) * K + sc_ * 8;
    const u16* gB = W + (size_t)(m0 + sr_) * K + sc_ * 8;
    const int ls = sr_ * 32 + sc_ * 8;

    f32x4 acc[4][2];
#pragma unroll
    for (int i = 0; i < 4; ++i)
#pragma unroll
        for (int j = 0; j < 2; ++j) acc[i][j] = (f32x4)0.f;

    const int frow = (lane & 15);
    const int fk   = (lane >> 4) * 8;

    uint4 ra = *(const uint4*)(gA);
    uint4 rb = *(const uint4*)(gB);
    *(uint4*)&As[0][ls] = ra;
    *(uint4*)&Bs[0][ls] = rb;
    __syncthreads();

    int buf = 0;
    for (int k0 = 0; k0 < K; k0 += 32) {
        const bool last = (k0 + 32 >= K);
        if (!last) {
            ra = *(const uint4*)(gA + k0 + 32);
            rb = *(const uint4*)(gB + k0 + 32);
        }
        bf16x8 af[4], bf[2];
#pragma unroll
        for (int i = 0; i < 4; ++i)
            af[i] = *(const bf16x8*)&As[buf][(wm * 64 + i * 16 + frow) * 32 + fk];
#pragma unroll
        for (int j = 0; j < 2; ++j)
            bf[j] = *(const bf16x8*)&Bs[buf][(wn * 32 + j * 16 + frow) * 32 + fk];
#pragma unroll
        for (int i = 0; i < 4; ++i)
#pragma unroll
            for (int j = 0; j < 2; ++j)
                acc[i][j] = __builtin_amdgcn_mfma_f32_16x16x32_bf16(af[i], bf[j], acc[i][j], 0, 0, 0);
        if (!last) {
            const int nb = buf ^ 1;
            *(uint4*)&As[nb][ls] = ra;
            *(uint4*)&Bs[nb][ls] = rb;
            __syncthreads();
            buf = nb;
        }
    }

    const int quad = lane >> 4;
#pragma unroll
    for (int i = 0; i < 4; ++i) {
        const int row = n0 + wm * 64 + i * 16 + quad * 4;
#pragma unroll
        for (int j = 0; j < 2; ++j) {
            const int col = m0 + wn * 32 + j * 16 + (lane & 15);
            const float bv = bias ? bias[col] : 0.f;
#pragma unroll
            for (int r = 0; r < 4; ++r) {
                float v = acc[i][j][r] + bv;
                if (ACT == 1) v = dswishf_(v);
                if (HAS_RES) v += res[(size_t)(row + r) * M + col];
                v = clampd_(v);
                if (O32) out32[(size_t)(row + r) * M + col] = v;
                if (O16) out16[(size_t)(row + r) * M + col] = f2bf_(v);
            }
        }
    }
}

// ---------------------------------------------------------------------------
// R12-proven: 4-deep sub-tile ring GEMM ("BK=64" as two sequential BK=32
// sub-tiles; linear per-sub-tile LDS layout). One barrier per 64-K step:
// barrier count halves and 4 global loads issue back-to-back. For the
// 1-block/CU dispatches (ffm2/ffn2/out-proj/cpw2) that can't get more TLP —
// R12 measured -8.7us on ffm2+ffn2; R13 -5.1us on out-proj+cpw2. LDS 64KB
// (grid 256 = 1 block/CU anyway). K mult of 64.
// ---------------------------------------------------------------------------
template <int ACT, bool HAS_RES, bool O32, bool O16>
__global__ __launch_bounds__(512) void gemm_k64(
    const u16* __restrict__ A, const u16* __restrict__ W,
    const float* __restrict__ bias, const float* __restrict__ res,
    float* __restrict__ out32, u16* __restrict__ out16, int N, int K, int M)
{
    __shared__ __align__(16) u16 As[4][128 * 32];
    __shared__ __align__(16) u16 Bs[4][128 * 32];
    const int tid  = threadIdx.x;
    const int wv   = tid >> 6;
    const int lane = tid & 63;
    const int wm   = wv >> 2, wn = wv & 3;
    const int m0 = blockIdx.x * 128;
    const int n0 = blockIdx.y * 128;

    const int sc_ = tid & 3;
    const int sr_ = tid >> 2;
    const u16* gA = A + (size_t)(n0 + sr_) * K + sc_ * 8;
    const u16* gB = W + (size_t)(m0 + sr_) * K + sc_ * 8;
    const int ls = sr_ * 32 + sc_ * 8;

    f32x4 acc[4][2];
#pragma unroll
    for (int i = 0; i < 4; ++i)
#pragma unroll
        for (int j = 0; j < 2; ++j) acc[i][j] = (f32x4)0.f;

    const int frow = (lane & 15);
    const int fk   = (lane >> 4) * 8;

    uint4 ra0 = *(const uint4*)(gA);
    uint4 ra1 = *(const uint4*)(gA + 32);
    uint4 rb0 = *(const uint4*)(gB);
    uint4 rb1 = *(const uint4*)(gB + 32);
    *(uint4*)&As[0][ls] = ra0; *(uint4*)&As[1][ls] = ra1;
    *(uint4*)&Bs[0][ls] = rb0; *(uint4*)&Bs[1][ls] = rb1;
    __syncthreads();

    int ph = 0;   // base buffer of current pair (0 or 2)
    for (int k0 = 0; k0 < K; k0 += 64) {
        const bool last = (k0 + 64 >= K);
        if (!last) {
            ra0 = *(const uint4*)(gA + k0 + 64);
            ra1 = *(const uint4*)(gA + k0 + 96);
            rb0 = *(const uint4*)(gB + k0 + 64);
            rb1 = *(const uint4*)(gB + k0 + 96);
        }
#pragma unroll
        for (int kk = 0; kk < 2; ++kk) {
            bf16x8 af[4], bf[2];
#pragma unroll
            for (int i = 0; i < 4; ++i)
                af[i] = *(const bf16x8*)&As[ph + kk][(wm * 64 + i * 16 + frow) * 32 + fk];
#pragma unroll
            for (int j = 0; j < 2; ++j)
                bf[j] = *(const bf16x8*)&Bs[ph + kk][(wn * 32 + j * 16 + frow) * 32 + fk];
#pragma unroll
            for (int i = 0; i < 4; ++i)
#pragma unroll
                for (int j = 0; j < 2; ++j)
                    acc[i][j] = __builtin_amdgcn_mfma_f32_16x16x32_bf16(af[i], bf[j], acc[i][j], 0, 0, 0);
        }
        if (!last) {
            const int nb = ph ^ 2;
            *(uint4*)&As[nb][ls] = ra0; *(uint4*)&As[nb + 1][ls] = ra1;
            *(uint4*)&Bs[nb][ls] = rb0; *(uint4*)&Bs[nb + 1][ls] = rb1;
            __syncthreads();
            ph = nb;
        }
    }

    const int quad = lane >> 4;
#pragma unroll
    for (int i = 0; i < 4; ++i) {
        const int row = n0 + wm * 64 + i * 16 + quad * 4;
#pragma unroll
        for (int j = 0; j < 2; ++j) {
            const int col = m0 + wn * 32 + j * 16 + (lane & 15);
            const float bv = bias ? bias[col] : 0.f;
#pragma unroll
            for (int r = 0; r < 4; ++r) {
                float v = acc[i][j][r] + bv;
                if (ACT == 1) v = dswishf_(v);
                if (HAS_RES) v += res[(size_t)(row + r) * M + col];
                v = clampd_(v);
                if (O32) out32[(size_t)(row + r) * M + col] = v;
                if (O16) out16[(size_t)(row + r) * M + col] = f2bf_(v);
            }
        }
    }
}

// ---------------------------------------------------------------------------
// Merged qkv + pos projection GEMM (both K=512, same dbuf body; R10).
// Grid (12, 72): y<64 -> qkv block; y>=64 -> pos block (x>=4 early-exits).
// EPI qkv: writes qu/qv/k/v bf16 in [b*8+h][t][d], q*0.125 + u/v bias.
//   (R7 lesson: V must NOT be written transposed here.)
// EPI pos: writes p_b[h][j][d] bf16.
// ---------------------------------------------------------------------------
__global__ __launch_bounds__(512) void gemm_qkvpos(
    const u16* __restrict__ Aq, const u16* __restrict__ Wq,
    const u16* __restrict__ Ap, const u16* __restrict__ Wp,
    const float* __restrict__ bias, const float* __restrict__ ub, const float* __restrict__ vb,
    u16* __restrict__ o_qu, u16* __restrict__ o_qv, u16* __restrict__ o_k,
    u16* __restrict__ o_v, u16* __restrict__ o_p)
{
    __shared__ __align__(16) u16 As[2][128 * 32];
    __shared__ __align__(16) u16 Bs[2][128 * 32];
    const bool isPos = (blockIdx.y >= 64);
    if (isPos && blockIdx.x >= 4) return;
    const u16* A = isPos ? Ap : Aq;
    const u16* W = isPos ? Wp : Wq;
    const int K = 512;
    const int tid  = threadIdx.x;
    const int wv   = tid >> 6;
    const int lane = tid & 63;
    const int wm   = wv >> 2, wn = wv & 3;
    const int m0 = blockIdx.x * 128;
    const int n0 = (isPos ? ((int)blockIdx.y - 64) : (int)blockIdx.y) * 128;

    const int sc_ = tid & 3;
    const int sr_ = tid >> 2;
    const u16* gA = A + (size_t)(n0 + sr_) * K + sc_ * 8;
    const u16* gB = W + (size_t)(m0 + sr_) * K + sc_ * 8;
    const int ls = sr_ * 32 + sc_ * 8;

    f32x4 acc[4][2];
#pragma unroll
    for (int i = 0; i < 4; ++i)
#pragma unroll
        for (int j = 0; j < 2; ++j) acc[i][j] = (f32x4)0.f;

    const int frow = (lane & 15);
    const int fk   = (lane >> 4) * 8;

    uint4 ra = *(const uint4*)(gA);
    uint4 rb = *(const uint4*)(gB);
    *(uint4*)&As[0][ls] = ra;
    *(uint4*)&Bs[0][ls] = rb;
    __syncthreads();

    int buf = 0;
    for (int k0 = 0; k0 < K; k0 += 32) {
        const bool last = (k0 + 32 >= K);
        if (!last) {
            ra = *(const uint4*)(gA + k0 + 32);
            rb = *(const uint4*)(gB + k0 + 32);
        }
        bf16x8 af[4], bf[2];
#pragma unroll
        for (int i = 0; i < 4; ++i)
            af[i] = *(const bf16x8*)&As[buf][(wm * 64 + i * 16 + frow) * 32 + fk];
#pragma unroll
        for (int j = 0; j < 2; ++j)
            bf[j] = *(const bf16x8*)&Bs[buf][(wn * 32 + j * 16 + frow) * 32 + fk];
#pragma unroll
        for (int i = 0; i < 4; ++i)
#pragma unroll
            for (int j = 0; j < 2; ++j)
                acc[i][j] = __builtin_amdgcn_mfma_f32_16x16x32_bf16(af[i], bf[j], acc[i][j], 0, 0, 0);
        if (!last) {
            const int nb = buf ^ 1;
            *(uint4*)&As[nb][ls] = ra;
            *(uint4*)&Bs[nb][ls] = rb;
            __syncthreads();
            buf = nb;
        }
    }

    const int quad = lane >> 4;
#pragma unroll
    for (int i = 0; i < 4; ++i) {
        const int rowb = n0 + wm * 64 + i * 16 + quad * 4;
#pragma unroll
        for (int j = 0; j < 2; ++j) {
            const int col = m0 + wn * 32 + j * 16 + (lane & 15);
            if (!isPos) {
                const float bv = bias[col];
                const int c = col & 511, h = c >> 6, d = c & 63;
#pragma unroll
                for (int r = 0; r < 4; ++r) {
                    const int row = rowb + r;
                    const float v = clampd_(acc[i][j][r] + bv);
                    const int t = row >> 4, b = row & 15;
                    const size_t dst = ((size_t)(b * 8 + h) * 512 + t) * 64 + d;
                    if (col < 512) {
                        o_qu[dst] = f2bf_(v * 0.125f + ub[c]);
                        o_qv[dst] = f2bf_(v * 0.125f + vb[c]);
                    } else if (col < 1024) {
                        o_k[dst] = f2bf_(v);
                    } else {
                        o_v[dst] = f2bf_(v);
                    }
                }
            } else {
                const int h = col >> 6, d = col & 63;
#pragma unroll
                for (int r = 0; r < 4; ++r)
                    o_p[(size_t)h * 65536 + (size_t)(rowb + r) * 64 + d] = f2bf_(acc[i][j][r]);
            }
        }
    }
}

// ---------------------------------------------------------------------------
// pw1 GEMM with fused GLU. R14: K64 4-deep ring (R12 mechanism; the R12 note
// "needs 192KB" was an arithmetic error — 3 operands x 4 x 8KB = 96KB fits).
// Grid (4,64) = 1 block/CU, barriers 16 -> 8, 6 loads issue back-to-back.
// Writes a*sigmoid(g) bf16 to glu_o.
// ---------------------------------------------------------------------------
__global__ __launch_bounds__(512) void gemm_glu_k(
    const u16* __restrict__ A, const u16* __restrict__ W,
    const float* __restrict__ bias, u16* __restrict__ out)
{
    __shared__ __align__(16) u16 As[4][128 * 32];
    __shared__ __align__(16) u16 Ba[4][128 * 32];
    __shared__ __align__(16) u16 Bg[4][128 * 32];
    const int tid  = threadIdx.x;
    const int wv   = tid >> 6;
    const int lane = tid & 63;
    const int wm   = wv >> 2, wn = wv & 3;
    const int m0 = blockIdx.x * 128;
    const int n0 = blockIdx.y * 128;
    const int K = 512;

    const int sc_ = tid & 3;
    const int sr_ = tid >> 2;
    const u16* gA  = A + (size_t)(n0 + sr_) * K + sc_ * 8;
    const u16* gBa = W + (size_t)(m0 + sr_) * K + sc_ * 8;
    const u16* gBg = W + (size_t)(m0 + 512 + sr_) * K + sc_ * 8;
    const int ls = sr_ * 32 + sc_ * 8;

    f32x4 aa[4][2], ag[4][2];
#pragma unroll
    for (int i = 0; i < 4; ++i)
#pragma unroll
        for (int j = 0; j < 2; ++j) { aa[i][j] = (f32x4)0.f; ag[i][j] = (f32x4)0.f; }

    const int frow = (lane & 15);
    const int fk   = (lane >> 4) * 8;

    uint4 ra0  = *(const uint4*)(gA);
    uint4 ra1  = *(const uint4*)(gA + 32);
    uint4 rba0 = *(const uint4*)(gBa);
    uint4 rba1 = *(const uint4*)(gBa + 32);
    uint4 rbg0 = *(const uint4*)(gBg);
    uint4 rbg1 = *(const uint4*)(gBg + 32);
    *(uint4*)&As[0][ls] = ra0;  *(uint4*)&As[1][ls] = ra1;
    *(uint4*)&Ba[0][ls] = rba0; *(uint4*)&Ba[1][ls] = rba1;
    *(uint4*)&Bg[0][ls] = rbg0; *(uint4*)&Bg[1][ls] = rbg1;
    __syncthreads();

    int ph = 0;
    for (int k0 = 0; k0 < K; k0 += 64) {
        const bool last = (k0 + 64 >= K);
        if (!last) {
            ra0  = *(const uint4*)(gA + k0 + 64);
            ra1  = *(const uint4*)(gA + k0 + 96);
            rba0 = *(const uint4*)(gBa + k0 + 64);
            rba1 = *(const uint4*)(gBa + k0 + 96);
            rbg0 = *(const uint4*)(gBg + k0 + 64);
            rbg1 = *(const uint4*)(gBg + k0 + 96);
        }
#pragma unroll
        for (int kk = 0; kk < 2; ++kk) {
            bf16x8 af[4], bfa[2], bfg[2];
#pragma unroll
            for (int i = 0; i < 4; ++i)
                af[i] = *(const bf16x8*)&As[ph + kk][(wm * 64 + i * 16 + frow) * 32 + fk];
#pragma unroll
            for (int j = 0; j < 2; ++j) {
                bfa[j] = *(const bf16x8*)&Ba[ph + kk][(wn * 32 + j * 16 + frow) * 32 + fk];
                bfg[j] = *(const bf16x8*)&Bg[ph + kk][(wn * 32 + j * 16 + frow) * 32 + fk];
            }
#pragma unroll
            for (int i = 0; i < 4; ++i)
#pragma unroll
                for (int j = 0; j < 2; ++j) {
                    aa[i][j] = __builtin_amdgcn_mfma_f32_16x16x32_bf16(af[i], bfa[j], aa[i][j], 0, 0, 0);
                    ag[i][j] = __builtin_amdgcn_mfma_f32_16x16x32_bf16(af[i], bfg[j], ag[i][j], 0, 0, 0);
                }
        }
        if (!last) {
            const int nb = ph ^ 2;
            *(uint4*)&As[nb][ls] = ra0;  *(uint4*)&As[nb + 1][ls] = ra1;
            *(uint4*)&Ba[nb][ls] = rba0; *(uint4*)&Ba[nb + 1][ls] = rba1;
            *(uint4*)&Bg[nb][ls] = rbg0; *(uint4*)&Bg[nb + 1][ls] = rbg1;
            __syncthreads();
            ph = nb;
        }
    }

    const int quad = lane >> 4;
#pragma unroll
    for (int i = 0; i < 4; ++i) {
        const int row = n0 + wm * 64 + i * 16 + quad * 4;
#pragma unroll
        for (int j = 0; j < 2; ++j) {
            const int col = m0 + wn * 32 + j * 16 + (lane & 15);
            const float ba = bias[col];
            const float bg = bias[col + 512];
#pragma unroll
            for (int r = 0; r < 4; ++r) {
                const float a = clampd_(aa[i][j][r] + ba);
                const float g = clampd_(ag[i][j][r] + bg);
                out[(size_t)(row + r) * 512 + col] = f2bf_(a * sigmoidf_(g));
            }
        }
    }
}

// ---------------------------------------------------------------------------
// f32 -> bf16 converters / prep (merged single launch, R6-proven)
// ---------------------------------------------------------------------------
__device__ __forceinline__ void store_bf4_(u16* out, float4 v) {
    const unsigned lo = (unsigned)f2bf_(v.x) | ((unsigned)f2bf_(v.y) << 16);
    const unsigned hi = (unsigned)f2bf_(v.z) | ((unsigned)f2bf_(v.w) << 16);
    *(uint2*)out = make_uint2(lo, hi);
}

struct WPtrs { const float* p[9]; };
__global__ __launch_bounds__(256) void prep_k(
    WPtrs wp, const float* __restrict__ src, const float* __restrict__ pos,
    const float* __restrict__ cdw,
    u16* __restrict__ wb, u16* __restrict__ src_b, u16* __restrict__ pos_b,
    float* __restrict__ wTd)
{
    const int e = (blockIdx.x * 256 + threadIdx.x) * 4;
    if (e < 6291456) {
        static const int off[10] = {0, 1048576, 2097152, 3145728, 4194304,
                                    4980736, 5242880, 5505024, 6029312, 6291456};
        int r = 0;
#pragma unroll
        for (int k = 1; k < 9; ++k) r += (e >= off[k]);
        store_bf4_(wb + e, *(const float4*)(wp.p[r] + (e - off[r])));
    } else if (e < 6291456 + 4194304) {
        const int e2 = e - 6291456;
        store_bf4_(src_b + e2, *(const float4*)(src + e2));
    } else if (e < 6291456 + 4194304 + 524288) {
        const int e2 = e - (6291456 + 4194304);
        float4 v = make_float4(0.f, 0.f, 0.f, 0.f);
        if (e2 < 1023 * 512) v = *(const float4*)(pos + e2);
        store_bf4_(pos_b + e2, v);
    } else {
        const int e2 = e - (6291456 + 4194304 + 524288);
        if (e2 < 15872) {
#pragma unroll
            for (int q = 0; q < 4; ++q) {
                const int i2 = e2 + q;
                const int j = i2 >> 9, c = i2 & 511;
                wTd[i2] = cdw[c * 31 + j];
            }
        }
    }
}

// v_b[gbh][s][d] -> vt_b[gbh][d][s]  (64x64 LDS tile transpose; R7 lesson:
// this is cheaper than scattering the transpose into the GEMM epilogue)
__global__ __launch_bounds__(256) void vt_k(const u16* __restrict__ in, u16* __restrict__ out)
{
    __shared__ u16 tile[64][65];
    const int s0 = blockIdx.x * 64;
    const int gbh = blockIdx.y;
    const u16* src = in + (size_t)gbh * 512 * 64;
    u16* dst = out + (size_t)gbh * 64 * 512;
    const int tid = threadIdx.x;
#pragma unroll
    for (int q = 0; q < 2; ++q) {
        const int lin = tid * 2 + q;             // 0..511 uint4s
        const int srow = lin >> 3, c8 = (lin & 7) * 8;
        const uint4 v = *(const uint4*)(src + (size_t)(s0 + srow) * 64 + c8);
        const u16* vu = (const u16*)&v;
#pragma unroll
        for (int e = 0; e < 8; ++e) tile[srow][c8 + e] = vu[e];
    }
    __syncthreads();
#pragma unroll
    for (int q = 0; q < 2; ++q) {
        const int lin = tid * 2 + q;
        const int d = lin >> 3, sc8 = (lin & 7) * 8;
        u16 o[8];
#pragma unroll
        for (int e = 0; e < 8; ++e) o[e] = tile[sc8 + e][d];
        *(uint4*)(dst + (size_t)d * 512 + s0 + sc8) = *(uint4*)o;
    }
}

// ---------------------------------------------------------------------------
// Fused flash rel-pos attention (R6-proven body + R11 defer-max, the proven
// local optimum: 6 structural attacks regressed or were neutral).
// grid (t64-tiles=8, gbh=128), 4 waves/block, each wave owns 16 t-rows.
// Wave-private LDS slices, no barriers; padded strides (88/72 u16) keep LDS
// ops <= 2-way. l tracked via ones-column MFMA. Defer-max (T13, THR=8):
// skip O/Lacc rescale when all rows' tile max grew <= 8 (wave-uniform __any).
// ---------------------------------------------------------------------------
#define C2S 88   // padded C2 row stride (u16)
#define PS  72   // padded P row stride (u16)
__global__ __launch_bounds__(256, 4) void flash_attn(
    const u16* __restrict__ qu_b, const u16* __restrict__ qv_b,
    const u16* __restrict__ k_b, const u16* __restrict__ vt_b,
    const u16* __restrict__ p_b, u16* __restrict__ aob)
{
    __shared__ __align__(16) u16 C2ld[4][16 * C2S];
    __shared__ __align__(16) u16 Pld[4][16 * PS];
    const int tid = threadIdx.x;
    const int wv = tid >> 6;
    const int lane = tid & 63;
    const int quad = lane >> 4, ln = lane & 15;
    const int gbh = blockIdx.y;
    const int b = gbh >> 3, h = gbh & 7;
    const int t0 = blockIdx.x * 64 + wv * 16;     // wave's first t-row

    const u16* qu = qu_b + (size_t)gbh * 512 * 64;
    const u16* qv = qv_b + (size_t)gbh * 512 * 64;
    const u16* kb = k_b + (size_t)gbh * 512 * 64;
    const u16* vt = vt_b + (size_t)gbh * 64 * 512;
    const u16* pp = p_b + (size_t)h * 1024 * 64;

    // A-fragments (row = t0+ln, k = ks*32 + quad*8), constant across s-tiles
    bf16x8 aqu[2], aqv[2];
#pragma unroll
    for (int ks = 0; ks < 2; ++ks) {
        aqu[ks] = *(const bf16x8*)(qu + (size_t)(t0 + ln) * 64 + ks * 32 + quad * 8);
        aqv[ks] = *(const bf16x8*)(qv + (size_t)(t0 + ln) * 64 + ks * 32 + quad * 8);
    }

    const short ob = (short)0x3F80;               // bf16 1.0
    const bf16x8 vone = {ob, ob, ob, ob, ob, ob, ob, ob};

    f32x4 O[4];
#pragma unroll
    for (int nb = 0; nb < 4; ++nb) O[nb] = (f32x4)0.f;
    f32x4 Lacc = (f32x4)0.f;                      // per-row softmax denom
    float m[4];
#pragma unroll
    for (int r = 0; r < 4; ++r) m[r] = -1e30f;

    u16* c2w = &C2ld[wv][0];
    u16* pw  = &Pld[wv][0];

    for (int s0 = 0; s0 < 512; s0 += 64) {
        // ---- S = qu . k^T (16 x 64) ----
        f32x4 S[4];
#pragma unroll
        for (int nb = 0; nb < 4; ++nb) S[nb] = (f32x4)0.f;
        __builtin_amdgcn_s_setprio(1);
#pragma unroll
        for (int ks = 0; ks < 2; ++ks)
#pragma unroll
            for (int nb = 0; nb < 4; ++nb) {
                const bf16x8 bk = *(const bf16x8*)(kb + (size_t)(s0 + nb * 16 + ln) * 64 + ks * 32 + quad * 8);
                S[nb] = __builtin_amdgcn_mfma_f32_16x16x32_bf16(aqu[ks], bk, S[nb], 0, 0, 0);
            }
        __builtin_amdgcn_s_setprio(0);
        // ---- C2 window = qv . p[jlo..jlo+80)^T (16 x 80) ----
        const int jlo = 496 - t0 + s0;
        f32x4 C2[5];
#pragma unroll
        for (int nb = 0; nb < 5; ++nb) C2[nb] = (f32x4)0.f;
        __builtin_amdgcn_s_setprio(1);
#pragma unroll
        for (int ks = 0; ks < 2; ++ks)
#pragma unroll
            for (int nb = 0; nb < 5; ++nb) {
                const bf16x8 bp = *(const bf16x8*)(pp + (size_t)(jlo + nb * 16 + ln) * 64 + ks * 32 + quad * 8);
                C2[nb] = __builtin_amdgcn_mfma_f32_16x16x32_bf16(aqv[ks], bp, C2[nb], 0, 0, 0);
            }
        __builtin_amdgcn_s_setprio(0);
#pragma unroll
        for (int nb = 0; nb < 5; ++nb)
#pragma unroll
            for (int r = 0; r < 4; ++r)
                c2w[(quad * 4 + r) * C2S + nb * 16 + ln] = f2bf_(C2[nb][r]);

        // ---- S += shifted bd; clamp; row-max ----
        float sv[4][4];
        float rmax[4] = {-1e30f, -1e30f, -1e30f, -1e30f};
#pragma unroll
        for (int nb = 0; nb < 4; ++nb)
#pragma unroll
            for (int r = 0; r < 4; ++r) {
                const int tloc = quad * 4 + r;
                const int col = nb * 16 + ln + 15 - tloc;   // [0,78]
                const float bd = bf2f_(c2w[tloc * C2S + col]);
                const float s = clampd_(S[nb][r] + bd);
                sv[nb][r] = s;
                rmax[r] = fmaxf(rmax[r], s);
            }
#pragma unroll
        for (int off = 1; off < 16; off <<= 1)
#pragma unroll
            for (int r = 0; r < 4; ++r)
                rmax[r] = fmaxf(rmax[r], __shfl_xor(rmax[r], off, 64));

        // ---- online softmax update with defer-max (T13, THR=8) ----
        bool need = false;
#pragma unroll
        for (int r = 0; r < 4; ++r) need = need || (rmax[r] > m[r] + 8.f);
        if (__any((int)need)) {
            float alpha[4];
#pragma unroll
            for (int r = 0; r < 4; ++r) {
                const float mn = fmaxf(m[r], rmax[r]);
                alpha[r] = __expf(m[r] - mn);
                m[r] = mn;
            }
#pragma unroll
            for (int nb = 0; nb < 4; ++nb)
#pragma unroll
                for (int r = 0; r < 4; ++r) O[nb][r] *= alpha[r];
#pragma unroll
            for (int r = 0; r < 4; ++r) Lacc[r] *= alpha[r];
        }
#pragma unroll
        for (int nb = 0; nb < 4; ++nb)
#pragma unroll
            for (int r = 0; r < 4; ++r) {
                const float p = __expf(sv[nb][r] - m[r]);
                pw[(quad * 4 + r) * PS + nb * 16 + ln] = f2bf_(p);
            }

        // ---- O += P . V ; Lacc += P . 1  (P A-frags from LDS) ----
        __builtin_amdgcn_s_setprio(1);
#pragma unroll
        for (int ks = 0; ks < 2; ++ks) {
            const bf16x8 ap = *(const bf16x8*)&pw[ln * PS + ks * 32 + quad * 8];
#pragma unroll
            for (int nb = 0; nb < 4; ++nb) {
                const bf16x8 bv = *(const bf16x8*)(vt + (size_t)(nb * 16 + ln) * 512 + s0 + ks * 32 + quad * 8);
                O[nb] = __builtin_amdgcn_mfma_f32_16x16x32_bf16(ap, bv, O[nb], 0, 0, 0);
            }
            Lacc = __builtin_amdgcn_mfma_f32_16x16x32_bf16(ap, vone, Lacc, 0, 0, 0);
        }
        __builtin_amdgcn_s_setprio(0);
    }

    // ---- epilogue: normalize and write ao (t,b,c) ----
    float inv[4];
#pragma unroll
    for (int r = 0; r < 4; ++r) inv[r] = 1.f / Lacc[r];
#pragma unroll
    for (int nb = 0; nb < 4; ++nb)
#pragma unroll
        for (int r = 0; r < 4; ++r) {
            const int t = t0 + quad * 4 + r;
            const int d = nb * 16 + ln;
            aob[((size_t)t * B_SZ + b) * 512 + h * 64 + d] = f2bf_(O[nb][r] * inv[r]);
        }
}

// ---------------------------------------------------------------------------
// Conv-module pieces (bf16 chain)
// ---------------------------------------------------------------------------
__global__ __launch_bounds__(256) void dwconv_k(
    const u16* __restrict__ g, const float* __restrict__ wT,
    const float* __restrict__ bb, u16* __restrict__ out)
{
    const int idx = blockIdx.x * 256 + threadIdx.x;
    const int c = idx & 511;
    const int b = (idx >> 9) & 15;
    const int t0 = (idx >> 13) * 8;
    float wr[31];
#pragma unroll
    for (int j = 0; j < 31; ++j) wr[j] = wT[j * 512 + c];
    float win[38];
#pragma unroll
    for (int jj = 0; jj < 38; ++jj) {
        const int tt = t0 - 30 + jj;
        win[jj] = (tt >= 0) ? bf2f_(g[((size_t)tt * B_SZ + b) * 512 + c]) : 0.f;
    }
    const float bias = bb[c];
#pragma unroll
    for (int o = 0; o < 8; ++o) {
        float acc = bias;
#pragma unroll
        for (int j = 0; j < 31; ++j) acc += win[o + j] * wr[j];
        out[((size_t)(t0 + o) * B_SZ + b) * 512 + c] = f2bf_(dswishf_(acc));
    }
}

__global__ __launch_bounds__(256) void norm_k(float* __restrict__ x)
{
    const int row = blockIdx.x * 4 + (threadIdx.x >> 6);
    const int lane = threadIdx.x & 63;
    float* r = x + (size_t)row * 512;
    float v[8];
    float ss = 0.f;
#pragma unroll
    for (int j = 0; j < 8; ++j) { v[j] = r[lane + (j << 6)]; ss += v[j] * v[j]; }
#pragma unroll
    for (int o = 32; o > 0; o >>= 1) ss += __shfl_xor(ss, o, 64);
    const float scale = rsqrtf(ss * (1.f / 512.f) + EPS_BN);
#pragma unroll
    for (int j = 0; j < 8; ++j) r[lane + (j << 6)] = v[j] * scale;
}

// ---------------------------------------------------------------------------
extern "C" void kernel_launch(void* const* d_in, const int* in_sizes, int n_in,
                              void* d_out, int out_size, void* d_ws, size_t ws_size,
                              hipStream_t stream)
{
    const float* src   = (const float*)d_in[0];
    const float* pos   = (const float*)d_in[1];
    const float* fm_w1 = (const float*)d_in[2];
    const float* fm_b1 = (const float*)d_in[3];
    const float* fm_w2 = (const float*)d_in[4];
    const float* fm_b2 = (const float*)d_in[5];
    const float* f_w1  = (const float*)d_in[6];
    const float* f_b1  = (const float*)d_in[7];
    const float* f_w2  = (const float*)d_in[8];
    const float* f_b2  = (const float*)d_in[9];
    const float* ipw   = (const float*)d_in[10];
    const float* ipb   = (const float*)d_in[11];
    const float* opw   = (const float*)d_in[12];
    const float* opb   = (const float*)d_in[13];
    const float* lpw   = (const float*)d_in[14];
    const float* pbu   = (const float*)d_in[15];
    const float* pbv   = (const float*)d_in[16];
    const float* cpw1  = (const float*)d_in[17];
    const float* cpb1  = (const float*)d_in[18];
    const float* cdw   = (const float*)d_in[19];
    const float* cdb   = (const float*)d_in[20];
    const float* cpw2  = (const float*)d_in[21];
    const float* cpb2  = (const float*)d_in[22];

    float* x = (float*)d_out;              // running activation (8192 x 512) f32

    // ---- workspace layout ----
    char* base = (char*)d_ws;
    u16*   wb    = (u16*)base;   base += 6291456ull * 2;   // 9 weights bf16
    u16*   src_b = (u16*)base;   base += 4194304ull * 2;
    u16*   pos_b = (u16*)base;   base += 524288ull * 2;    // 1024x512 padded
    u16*   xb    = (u16*)base;   base += 4194304ull * 2;
    u16*   hb    = (u16*)base;   base += 16777216ull * 2;  // FFN hidden / dwconv out
    u16*   aob   = (u16*)base;   base += 4194304ull * 2;
    u16*   qu_b  = (u16*)base;   base += 4194304ull * 2;
    u16*   qv_b  = (u16*)base;   base += 4194304ull * 2;
    u16*   k_b   = (u16*)base;   base += 4194304ull * 2;
    u16*   v_b   = (u16*)base;   base += 4194304ull * 2;
    u16*   vt_b  = (u16*)base;   base += 4194304ull * 2;
    u16*   p_b   = (u16*)base;   base += 524288ull * 2;    // [8][1024][64]
    float* wTd   = (float*)base; base += 15872ull * 4;
    u16*   glu_o = (u16*)base;   base += 4194304ull * 2;   // conv glu out (8192x512)

    u16* fm_w1b = wb;
    u16* fm_w2b = wb + 1048576;
    u16* f_w1b  = wb + 2097152;
    u16* f_w2b  = wb + 3145728;
    u16* ipwb   = wb + 4194304;
    u16* opwb   = wb + 4980736;
    u16* lpwb   = wb + 5242880;
    u16* cpw1b  = wb + 5505024;
    u16* cpw2b  = wb + 6029312;

    const dim3 blk(256);
    const dim3 blkg(512);

    // 0) all f32 -> bf16 conversions + dw weight transpose, single launch
    WPtrs wp = {{fm_w1, fm_w2, f_w1, f_w2, ipw, opw, lpw, cpw1, cpw2}};
    prep_k<<<dim3(10768), blk, 0, stream>>>(wp, src, pos, cdw, wb, src_b, pos_b, wTd);

    // 1) macaron FFN: x = src + W2 @ dswish(W1 @ src)
    gemm_mfma<1, false, false, true><<<dim3(16, 64), blkg, 0, stream>>>(
        src_b, fm_w1b, fm_b1, nullptr, nullptr, hb, NROWS, 512, DFF_);
    gemm_k64<0, true, true, true><<<dim3(4, 64), blkg, 0, stream>>>(
        hb, fm_w2b, fm_b2, src, x, xb, NROWS, DFF_, 512);

    // 2) qkv + pos projections in ONE launch (pos fills CU slack); V transpose
    gemm_qkvpos<<<dim3(12, 72), blkg, 0, stream>>>(
        xb, ipwb, pos_b, lpwb, ipb, pbu, pbv, qu_b, qv_b, k_b, v_b, p_b);
    vt_k<<<dim3(8, 128), blk, 0, stream>>>(v_b, vt_b);

    // 3) fused flash rel-pos attention (single launch, full batch)
    flash_attn<<<dim3(8, 128), blk, 0, stream>>>(qu_b, qv_b, k_b, vt_b, p_b, aob);

    // 4) out projection (residual into x) — K64 ring (1-block/CU dispatch)
    gemm_k64<0, true, true, true><<<dim3(4, 64), blkg, 0, stream>>>(
        aob, opwb, opb, x, x, xb, NROWS, 512, 512);

    // 5) conv module: pw1+GLU fused (K64 ring) -> dwconv(+dswish) -> pw2 (K64)
    gemm_glu_k<<<dim3(4, 64), blkg, 0, stream>>>(xb, cpw1b, cpb1, glu_o);
    dwconv_k<<<dim3(2048), blk, 0, stream>>>(glu_o, wTd, cdb, hb);
    gemm_k64<0, true, true, true><<<dim3(4, 64), blkg, 0, stream>>>(
        hb, cpw2b, cpb2, x, x, xb, NROWS, 512, 512);

    // 6) second FFN
    gemm_mfma<1, false, false, true><<<dim3(16, 64), blkg, 0, stream>>>(
        xb, f_w1b, f_b1, nullptr, nullptr, hb, NROWS, 512, DFF_);
    gemm_k64<0, true, true, false><<<dim3(4, 64), blkg, 0, stream>>>(
        hb, f_w2b, f_b2, x, x, nullptr, NROWS, DFF_, 512);

    // 7) BasicNorm
    norm_k<<<dim3(NROWS / 4), blk, 0, stream>>>(x);
}